// Round 5
// baseline (278.680 us; speedup 1.0000x reference)
//
#include <hip/hip_runtime.h>
#include <math.h>

#define B_N 2048
#define F_N 512
#define H_N 256
#define E_N 64

typedef __attribute__((ext_vector_type(8))) short short8;
typedef __attribute__((ext_vector_type(4))) float f32x4;
typedef __attribute__((ext_vector_type(4))) unsigned short ushort4v;

static __device__ __forceinline__ unsigned short bf16_rne(float x) {
  unsigned u = __float_as_uint(x);
  unsigned r = (u + 0x7FFFu + ((u >> 16) & 1u)) >> 16;
  return (unsigned short)r;
}
static __device__ __forceinline__ float bf16_to_f(unsigned short h) {
  return __uint_as_float(((unsigned)h) << 16);
}

// ---------------- K0: prep (transposes, expert norms, coef, zero counts) ----
__global__ __launch_bounds__(256) void k0_prep(
    const float* __restrict__ proj_w, const float* __restrict__ expert_emb,
    const float* __restrict__ expert_features, const float* __restrict__ trust,
    const float* __restrict__ dt, float* __restrict__ pwT,
    float* __restrict__ embT, float* __restrict__ enT,
    float* __restrict__ coef, int* __restrict__ cnt) {
  int bid = blockIdx.x, tid = threadIdx.x;
  if (bid < 512) {
    int idx = bid * 256 + tid;
    int f = idx >> 8, h = idx & 255;
    pwT[idx] = proj_w[h * 512 + f];
    if (bid == 0 && tid < E_N) cnt[tid] = 0;
  } else {
    int e = bid - 512;  // 0..63
    float v0 = expert_features[e * 512 + tid];
    float v1 = expert_features[e * 512 + tid + 256];
    float ss = v0 * v0 + v1 * v1;
    #pragma unroll
    for (int off = 32; off; off >>= 1) ss += __shfl_xor(ss, off);
    __shared__ float parts[4];
    if ((tid & 63) == 0) parts[tid >> 6] = ss;
    __syncthreads();
    float tot = parts[0] + parts[1] + parts[2] + parts[3];
    float inv = 1.0f / fmaxf(sqrtf(tot), 1e-8f);
    enT[tid * 64 + e] = v0 * inv;
    enT[(tid + 256) * 64 + e] = v1 * inv;
    embT[tid * 64 + e] = expert_emb[e * 256 + tid];
    if (tid == 0) {
      float st = fmaxf(0.1f, expf(-0.005f * dt[e]));
      coef[e] = trust[e] * st;
    }
  }
}

// ---------------- K0g: Gpack[f][e] = (pwT[f]·embT[:,e], enT[f][e]); gbias ---
__global__ __launch_bounds__(64) void k0g(
    const float* __restrict__ pwT, const float* __restrict__ proj_b,
    const float* __restrict__ embT, const float* __restrict__ enT,
    float* __restrict__ Gpack, float* __restrict__ gbias) {
  __shared__ float row[256];
  int f = blockIdx.x;
  int e = threadIdx.x;  // 0..63
  const float* src = (f < 512) ? (pwT + f * 256) : proj_b;
  *(float4*)&row[e * 4] = *(const float4*)&src[e * 4];
  __syncthreads();
  float g = 0.0f;
  #pragma unroll 8
  for (int h = 0; h < 256; ++h) g = fmaf(row[h], embT[h * 64 + e], g);
  if (f < 512) {
    Gpack[(f * 64 + e) * 2 + 0] = g;
    Gpack[(f * 64 + e) * 2 + 1] = enT[f * 64 + e];
  } else {
    gbias[e] = g;
  }
}

// ---------------- conv: features -> bf16 hi/lo -----------------------------
__global__ __launch_bounds__(256) void k_convF(const float* __restrict__ f,
    unsigned short* __restrict__ Fh, unsigned short* __restrict__ Fl) {
  int i = (blockIdx.x * 256 + threadIdx.x) * 4;
  float4 v = *(const float4*)(f + i);
  float xs[4] = {v.x, v.y, v.z, v.w};
  ushort4v h, l;
  #pragma unroll
  for (int j = 0; j < 4; ++j) {
    unsigned short hh = bf16_rne(xs[j]);
    h[j] = hh;
    l[j] = bf16_rne(xs[j] - bf16_to_f(hh));
  }
  *(ushort4v*)(Fh + i) = h;
  *(ushort4v*)(Fl + i) = l;
}

// ---------------- conv: fst_w -> transposed bf16 hi/lo [e][col][k] ----------
// v2: coalesced 1KB/wave fp32 row reads -> LDS [64][260] -> per-thread col
// conversion -> 128B-contiguous writes per col.
__global__ __launch_bounds__(256) void k_convW(const float* __restrict__ fst_w,
    unsigned short* __restrict__ WhT, unsigned short* __restrict__ WlT) {
  __shared__ float tile[64][260];  // pad 4: 2-way-free phase-2 reads
  int bid = blockIdx.x;            // 1024 = 64e x 8kb x 2cb
  int e = bid >> 4;
  int kb = (bid >> 1) & 7;
  int cb = bid & 1;
  int tid = threadIdx.x;

  // phase 1: each wave reads whole 1KB rows (64 lanes x float4)
  const float* src = fst_w + ((size_t)e << 18) + (size_t)(kb * 64) * 512 +
                     cb * 256;
  int kr = tid >> 6;        // wave id
  int c4 = (tid & 63) * 4;
  #pragma unroll
  for (int r = 0; r < 16; ++r) {
    int k = r * 4 + kr;
    *(float4*)&tile[k][c4] = *(const float4*)&src[(size_t)k * 512 + c4];
  }
  __syncthreads();

  // phase 2: thread = one col; 64 k's -> 128B contiguous h + l
  int c = tid;
  size_t dbase = ((size_t)e << 18) + (size_t)(cb * 256 + c) * 512 + kb * 64;
  #pragma unroll
  for (int g = 0; g < 8; ++g) {
    short8 vh, vl;
    #pragma unroll
    for (int i = 0; i < 8; ++i) {
      float x = tile[g * 8 + i][c];
      unsigned short hh = bf16_rne(x);
      vh[i] = (short)hh;
      vl[i] = (short)bf16_rne(x - bf16_to_f(hh));
    }
    *(short8*)(WhT + dbase + g * 8) = vh;
    *(short8*)(WlT + dbase + g * 8) = vl;
  }
}

// ---------------- K1: score + top-8 + softmax + scatter (8 tok/block) -------
__global__ __launch_bounds__(256) void k1_score(
    const float* __restrict__ features, const float* __restrict__ Gpack,
    const float* __restrict__ gbias, const float* __restrict__ coef,
    int* __restrict__ cnt, int* __restrict__ tk_idx, float* __restrict__ tk_w,
    int* __restrict__ tlist, float* __restrict__ wlist) {
  __shared__ float Ft[8][512];  // 16 KB
  int tid = threadIdx.x;
  int b0 = blockIdx.x * 8;

  #pragma unroll
  for (int q = 0; q < 4; ++q) {
    int idx = q * 256 + tid;
    int t = idx >> 7;
    int fo = (idx & 127) * 4;
    *(float4*)&Ft[t][fo] =
        *(const float4*)&features[(size_t)(b0 + t) * 512 + fo];
  }
  __syncthreads();

  int wave = tid >> 6, e = tid & 63;
  float cf = coef[e];
  float gb = gbias[e];
  int t0 = wave * 2, t1 = t0 + 1;

  float l0 = 0.f, s0 = 0.f, l1 = 0.f, s1 = 0.f;
  #pragma unroll 8
  for (int f = 0; f < 512; ++f) {
    float2 gp = *(const float2*)&Gpack[(f * 64 + e) * 2];
    float f0 = Ft[t0][f];
    float f1 = Ft[t1][f];
    l0 = fmaf(f0, gp.x, l0);
    s0 = fmaf(f0, gp.y, s0);
    l1 = fmaf(f1, gp.x, l1);
    s1 = fmaf(f1, gp.y, s1);
  }
  float n0 = 0.f, n1 = 0.f;
  #pragma unroll
  for (int j = 0; j < 8; ++j) {
    float v0 = Ft[t0][e + 64 * j];
    float v1 = Ft[t1][e + 64 * j];
    n0 = fmaf(v0, v0, n0);
    n1 = fmaf(v1, v1, n1);
  }
  #pragma unroll
  for (int off = 32; off; off >>= 1) {
    n0 += __shfl_xor(n0, off);
    n1 += __shfl_xor(n1, off);
  }

  #pragma unroll
  for (int tt = 0; tt < 2; ++tt) {
    float l = tt ? l1 : l0;
    float s = tt ? s1 : s0;
    float nn = tt ? n1 : n0;
    int b = b0 + wave * 2 + tt;
    float inv_n = 1.0f / fmaxf(sqrtf(nn), 1e-8f);
    float gate = 1.0f / (1.0f + expf(-(l + gb) * 0.0625f));
    float sim = fmaxf(s * inv_n, 0.0f);
    float score = gate * sim * cf;

    float cur = score;
    float bv[8];
    int bi[8];
    #pragma unroll
    for (int r = 0; r < 8; ++r) {
      float mv = cur;
      int mi = e;
      #pragma unroll
      for (int off = 1; off < 64; off <<= 1) {
        float ov = __shfl_xor(mv, off);
        int oi = __shfl_xor(mi, off);
        if (ov > mv || (ov == mv && oi < mi)) { mv = ov; mi = oi; }
      }
      bv[r] = mv;
      bi[r] = mi;
      if (e == mi) cur = -1.0f;
    }
    float m0 = bv[0];
    float ex[8];
    float sum = 0.0f;
    #pragma unroll
    for (int r = 0; r < 8; ++r) { ex[r] = expf(bv[r] - m0); sum += ex[r]; }
    float isum = 1.0f / sum;

    if (e < 8) {
      int ir = 0; float er = 0.0f;
      switch (e) {
        case 0: ir = bi[0]; er = ex[0]; break;
        case 1: ir = bi[1]; er = ex[1]; break;
        case 2: ir = bi[2]; er = ex[2]; break;
        case 3: ir = bi[3]; er = ex[3]; break;
        case 4: ir = bi[4]; er = ex[4]; break;
        case 5: ir = bi[5]; er = ex[5]; break;
        case 6: ir = bi[6]; er = ex[6]; break;
        case 7: ir = bi[7]; er = ex[7]; break;
      }
      float wr = er * isum;
      int pos = atomicAdd(&cnt[ir], 1);
      tlist[ir * B_N + pos] = b;
      wlist[ir * B_N + pos] = wr;
      tk_idx[b * 8 + e] = ir;
      tk_w[b * 8 + e] = wr;
    }
  }
}

// ---------------- K2: out[b,:] = sum_k w_k * fst_b[e_k,:]  ------------------
__global__ __launch_bounds__(256) void k2_bias(
    const int* __restrict__ tk_idx, const float* __restrict__ tk_w,
    const float* __restrict__ fst_b, float* __restrict__ out) {
  int b = blockIdx.x, tid = threadIdx.x;
  int ir[8];
  float wr[8];
  #pragma unroll
  for (int r = 0; r < 8; ++r) {
    ir[r] = tk_idx[b * 8 + r];
    wr[r] = tk_w[b * 8 + r];
  }
  #pragma unroll
  for (int q = 0; q < 2; ++q) {
    int f = tid + q * 256;
    float a = 0.0f;
    #pragma unroll
    for (int r = 0; r < 8; ++r) a = fmaf(wr[r], fst_b[ir[r] * 512 + f], a);
    out[(size_t)b * 512 + f] = a;
  }
}

// ---------------- K3 (MFMA): gathered per-expert FST, bf16 3-term split -----
// v2: DOUBLE-BUFFERED LDS, STAGE(s+1) issued BEFORE compute(s), single
// barrier per K-step -> load latency/BW hidden under MFMA+ds_read.
// Block: 64 tokens x 128 cols x K=512 (8 steps of 64). 4 waves, M64xN32 each.
__global__ __launch_bounds__(256, 1) void k3_mfma(
    const unsigned short* __restrict__ Fh, const unsigned short* __restrict__ Fl,
    const unsigned short* __restrict__ WhT, const unsigned short* __restrict__ WlT,
    const int* __restrict__ cnt, const int* __restrict__ tlist,
    const float* __restrict__ wlist, float* __restrict__ out) {
  __shared__ unsigned short Bh[2][128 * 64];  // 32 KB
  __shared__ unsigned short Bl[2][128 * 64];  // 32 KB
  __shared__ unsigned short Ah[2][64 * 64];   // 16 KB
  __shared__ unsigned short Al[2][64 * 64];   // 16 KB
  __shared__ int tl[64];
  __shared__ float wl[64];

  int tid = threadIdx.x;
  int e = blockIdx.x & 63;          // expert-minor spread
  int rest = blockIdx.x >> 6;
  int chunk = rest & 3;             // 4 col chunks of 128
  int tile = rest >> 2;             // 0..31 token tiles
  int c0 = chunk * 128;
  int c_e = cnt[e];
  int t0 = tile * 64;
  if (t0 >= c_e) return;

  if (tid < 64) {
    int t = t0 + tid;
    tl[tid] = tlist[e * B_N + (t < c_e ? t : t0)];
    wl[tid] = (t < c_e) ? wlist[e * B_N + t] : 0.0f;
  }
  __syncthreads();

  int wave = tid >> 6, lane = tid & 63;
  const unsigned short* WhT_e = WhT + ((size_t)e << 18);
  const unsigned short* WlT_e = WlT + ((size_t)e << 18);

  // staging source offsets (shorts), pre-swizzled: LDS row-major, k-slot p
  // holds logical k-group g = p ^ (row&7)  (proven 0-conflict in r4)
  size_t bsrc[4];
  int bdst[4];
  #pragma unroll
  for (int i = 0; i < 4; ++i) {
    int cw = wave * 32 + i * 8;
    int cl = cw + (lane >> 3);
    int g = (lane & 7) ^ (cl & 7);
    bsrc[i] = (size_t)(c0 + cl) * 512 + g * 8;
    bdst[i] = cw * 64;
  }
  size_t asrc[2];
  int adst[2];
  #pragma unroll
  for (int j = 0; j < 2; ++j) {
    int tw = wave * 16 + j * 8;
    int tkl = tw + (lane >> 3);
    int g = (lane & 7) ^ (tkl & 7);
    asrc[j] = (size_t)tl[tkl] * 512 + g * 8;
    adst[j] = tw * 64;
  }

  f32x4 acc[4][2];
  #pragma unroll
  for (int mt = 0; mt < 4; ++mt)
    #pragma unroll
    for (int ct = 0; ct < 2; ++ct) acc[mt][ct] = (f32x4){0.f, 0.f, 0.f, 0.f};

  int kg = lane >> 4;
  int mrow = lane & 15;

  #define STAGE(K0S, BUF)                                                     \
    do {                                                                      \
      _Pragma("unroll")                                                       \
      for (int i = 0; i < 4; ++i) {                                           \
        __builtin_amdgcn_global_load_lds(                                     \
            (const __attribute__((address_space(1))) void*)(WhT_e + bsrc[i] + (K0S)), \
            (__attribute__((address_space(3))) void*)(&Bh[BUF][0] + bdst[i]), 16, 0, 0);\
        __builtin_amdgcn_global_load_lds(                                     \
            (const __attribute__((address_space(1))) void*)(WlT_e + bsrc[i] + (K0S)), \
            (__attribute__((address_space(3))) void*)(&Bl[BUF][0] + bdst[i]), 16, 0, 0);\
      }                                                                       \
      _Pragma("unroll")                                                       \
      for (int j = 0; j < 2; ++j) {                                           \
        __builtin_amdgcn_global_load_lds(                                     \
            (const __attribute__((address_space(1))) void*)(Fh + asrc[j] + (K0S)), \
            (__attribute__((address_space(3))) void*)(&Ah[BUF][0] + adst[j]), 16, 0, 0);\
        __builtin_amdgcn_global_load_lds(                                     \
            (const __attribute__((address_space(1))) void*)(Fl + asrc[j] + (K0S)), \
            (__attribute__((address_space(3))) void*)(&Al[BUF][0] + adst[j]), 16, 0, 0);\
      }                                                                       \
    } while (0)

  STAGE(0, 0);
  __syncthreads();  // prologue drain

  int buf = 0;
  for (int s = 0; s < 8; ++s) {
    if (s < 7) STAGE((s + 1) * 64, buf ^ 1);  // issue next-step loads FIRST
    // compute on current buffer (hides in-flight loads)
    #pragma unroll
    for (int kh = 0; kh < 2; ++kh) {
      int gq = kh * 4 + kg;
      short8 afh[4], afl[4], bfh[2], bfl[2];
      #pragma unroll
      for (int mt = 0; mt < 4; ++mt) {
        int tr = mt * 16 + mrow;
        int off = tr * 64 + ((gq ^ (tr & 7)) * 8);
        afh[mt] = *(const short8*)(&Ah[buf][0] + off);
        afl[mt] = *(const short8*)(&Al[buf][0] + off);
      }
      #pragma unroll
      for (int ct = 0; ct < 2; ++ct) {
        int cl = wave * 32 + ct * 16 + mrow;
        int off = cl * 64 + ((gq ^ (cl & 7)) * 8);
        bfh[ct] = *(const short8*)(&Bh[buf][0] + off);
        bfl[ct] = *(const short8*)(&Bl[buf][0] + off);
      }
      #pragma unroll
      for (int mt = 0; mt < 4; ++mt)
        #pragma unroll
        for (int ct = 0; ct < 2; ++ct) {
          acc[mt][ct] = __builtin_amdgcn_mfma_f32_16x16x32_bf16(
              afh[mt], bfh[ct], acc[mt][ct], 0, 0, 0);
          acc[mt][ct] = __builtin_amdgcn_mfma_f32_16x16x32_bf16(
              afh[mt], bfl[ct], acc[mt][ct], 0, 0, 0);
          acc[mt][ct] = __builtin_amdgcn_mfma_f32_16x16x32_bf16(
              afl[mt], bfh[ct], acc[mt][ct], 0, 0, 0);
        }
    }
    __syncthreads();  // single per-step drain: next buf ready, cur buf free
    buf ^= 1;
  }
  #undef STAGE

  // epilogue: C/D layout col=lane&15, row=(lane>>4)*4+r
  int rbase = (lane >> 4) * 4;
  #pragma unroll
  for (int mt = 0; mt < 4; ++mt) {
    #pragma unroll
    for (int r = 0; r < 4; ++r) {
      int tloc = mt * 16 + rbase + r;
      float w = wl[tloc];
      if (w != 0.0f) {
        size_t orow = (size_t)tl[tloc] * 512 + c0 + wave * 32 + mrow;
        atomicAdd(out + orow, w * acc[mt][0][r]);
        atomicAdd(out + orow + 16, w * acc[mt][1][r]);
      }
    }
  }
}

// ---------------- K3 fallback (fp32 VALU) -----------------------------------
#define TM 64
#define TN 256
#define KC 16
__global__ __launch_bounds__(256, 2) void k3_fst(
    const float* __restrict__ features, const float* __restrict__ fst_w,
    const int* __restrict__ cnt, const int* __restrict__ tlist,
    const float* __restrict__ wlist, float* __restrict__ out) {
  __shared__ float Ws[2][KC][TN];
  __shared__ float Ft[2][KC][TM];
  __shared__ int tl[TM];
  __shared__ float wl[TM];

  int tid = threadIdx.x;
  int e = blockIdx.x & 63;
  int rest = blockIdx.x >> 6;
  int tile = rest >> 1;
  int ch = rest & 1;
  int c0 = ch * TN;
  int c_e = cnt[e];
  int t0 = tile * TM;
  if (t0 >= c_e) return;

  if (tid < TM) {
    int t = t0 + tid;
    if (t < c_e) {
      tl[tid] = tlist[e * B_N + t];
      wl[tid] = wlist[e * B_N + t];
    } else {
      tl[tid] = tlist[e * B_N + t0];
      wl[tid] = 0.0f;
    }
  }
  __syncthreads();

  const float* fw_e = fst_w + (size_t)e * (512 * 512);
  int wave = tid >> 6, lane = tid & 63;
  int tg = wave * 2 + (lane >> 5);
  int cg = lane & 31;
  int ft_t = tid >> 2;
  int ft_fq = tid & 3;
  const float* ft_src_row = features + (size_t)tl[ft_t] * 512;

  auto stageWs = [&](int kc, int buf) {
    int f0 = kc * KC;
    #pragma unroll
    for (int r = 0; r < 4; ++r) {
      int f = wave * 4 + r;
      const float* src = fw_e + (size_t)(f0 + f) * 512 + c0 + lane * 4;
      __builtin_amdgcn_global_load_lds(
          (const __attribute__((address_space(1))) void*)src,
          (__attribute__((address_space(3))) void*)&Ws[buf][f][0], 16, 0, 0);
    }
  };
  auto loadFt = [&](int kc) -> float4 {
    return *(const float4*)&ft_src_row[kc * KC + ft_fq * 4];
  };
  auto writeFt = [&](float4 v, int buf) {
    Ft[buf][ft_fq * 4 + 0][ft_t] = v.x;
    Ft[buf][ft_fq * 4 + 1][ft_t] = v.y;
    Ft[buf][ft_fq * 4 + 2][ft_t] = v.z;
    Ft[buf][ft_fq * 4 + 3][ft_t] = v.w;
  };

  float acc[8][8];
  #pragma unroll
  for (int j = 0; j < 8; ++j)
    #pragma unroll
    for (int i = 0; i < 8; ++i) acc[j][i] = 0.0f;

  auto compute = [&](int buf) {
    #pragma unroll 4
    for (int f = 0; f < KC; ++f) {
      float4 a0 = *(const float4*)&Ft[buf][f][tg * 8];
      float4 a1 = *(const float4*)&Ft[buf][f][tg * 8 + 4];
      float4 w0 = *(const float4*)&Ws[buf][f][cg * 4];
      float4 w1 = *(const float4*)&Ws[buf][f][cg * 4 + 128];
      float av[8] = {a0.x, a0.y, a0.z, a0.w, a1.x, a1.y, a1.z, a1.w};
      float wv[8] = {w0.x, w0.y, w0.z, w0.w, w1.x, w1.y, w1.z, w1.w};
      #pragma unroll
      for (int j = 0; j < 8; ++j)
        #pragma unroll
        for (int i = 0; i < 8; ++i)
          acc[j][i] = fmaf(av[j], wv[i], acc[j][i]);
    }
  };

  stageWs(0, 0);
  float4 rf = loadFt(0);
  writeFt(rf, 0);
  __syncthreads();

  for (int kc = 0; kc < 32; ++kc) {
    int cb = kc & 1, nb = cb ^ 1;
    float4 rn = make_float4(0.f, 0.f, 0.f, 0.f);
    if (kc < 31) {
      stageWs(kc + 1, nb);
      rn = loadFt(kc + 1);
    }
    compute(cb);
    if (kc < 31) writeFt(rn, nb);
    __syncthreads();
  }

  #pragma unroll
  for (int j = 0; j < 8; ++j) {
    int lt = tg * 8 + j;
    float w = wl[lt];
    if (w != 0.0f) {
      size_t orow = (size_t)tl[lt] * 512 + c0 + cg * 4;
      #pragma unroll
      for (int i = 0; i < 4; ++i) atomicAdd(&out[orow + i], w * acc[j][i]);
      #pragma unroll
      for (int i = 0; i < 4; ++i)
        atomicAdd(&out[orow + 128 + i], w * acc[j][i + 4]);
    }
  }
}

// ---------------- launch ----------------------------------------------------
extern "C" void kernel_launch(void* const* d_in, const int* in_sizes, int n_in,
                              void* d_out, int out_size, void* d_ws,
                              size_t ws_size, hipStream_t stream) {
  const float* features = (const float*)d_in[0];
  const float* proj_w = (const float*)d_in[1];
  const float* proj_b = (const float*)d_in[2];
  const float* expert_emb = (const float*)d_in[3];
  const float* expert_features = (const float*)d_in[4];
  const float* trust = (const float*)d_in[5];
  const float* dt = (const float*)d_in[6];
  const float* fst_w = (const float*)d_in[7];
  const float* fst_b = (const float*)d_in[8];
  float* out = (float*)d_out;

  float* ws = (float*)d_ws;
  float* pwT = ws;                           // 512*256
  float* embT = pwT + 131072;                // 256*64
  float* enT = embT + 16384;                 // 512*64
  float* coef = enT + 32768;                 // 64
  int* cnt = (int*)(coef + 64);              // 64
  int* tk_idx = cnt + 64;                    // 2048*8
  float* tk_w = (float*)(tk_idx + 16384);    // 2048*8
  int* tlist = (int*)(tk_w + 16384);         // 64*2048
  float* wlist = (float*)(tlist + 131072);   // 64*2048
  float* Gpack = wlist + 131072;             // 512*64*2
  float* gbias = Gpack + 65536;              // 64
  unsigned short* Fh = (unsigned short*)(gbias + 64);       // 2048*512
  unsigned short* Fl = Fh + (1 << 20);
  unsigned short* WhT = Fl + (1 << 20);                     // 64*512*512
  unsigned short* WlT = WhT + (1 << 24);
  size_t need = (size_t)((char*)(WlT + (1 << 24)) - (char*)d_ws);
  bool big = ws_size >= need;

  hipLaunchKernelGGL(k0_prep, dim3(576), dim3(256), 0, stream, proj_w,
                     expert_emb, expert_features, trust, dt, pwT, embT, enT,
                     coef, cnt);
  hipLaunchKernelGGL(k0g, dim3(513), dim3(64), 0, stream, pwT, proj_b, embT,
                     enT, Gpack, gbias);
  if (big) {
    hipLaunchKernelGGL(k_convF, dim3(1024), dim3(256), 0, stream, features, Fh,
                       Fl);
    hipLaunchKernelGGL(k_convW, dim3(1024), dim3(256), 0, stream, fst_w, WhT,
                       WlT);
  }
  hipLaunchKernelGGL(k1_score, dim3(256), dim3(256), 0, stream, features,
                     Gpack, gbias, coef, cnt, tk_idx, tk_w, tlist, wlist);
  hipLaunchKernelGGL(k2_bias, dim3(2048), dim3(256), 0, stream, tk_idx, tk_w,
                     fst_b, out);
  if (big) {
    hipLaunchKernelGGL(k3_mfma, dim3(8192), dim3(256), 0, stream, Fh, Fl, WhT,
                       WlT, cnt, tlist, wlist, out);
  } else {
    hipLaunchKernelGGL(k3_fst, dim3(4096), dim3(256), 0, stream, features,
                       fst_w, cnt, tlist, wlist, out);
  }
}

// Round 6
// 211.534 us; speedup vs baseline: 1.3174x; 1.3174x over previous
//
#include <hip/hip_runtime.h>
#include <hip/hip_fp16.h>
#include <math.h>

#define B_N 2048
#define F_N 512
#define H_N 256
#define E_N 64

typedef __attribute__((ext_vector_type(8))) _Float16 half8;
typedef __attribute__((ext_vector_type(4))) float f32x4;

// ---------------- K0: prep (transposes, expert norms, coef, zero counts) ----
__global__ __launch_bounds__(256) void k0_prep(
    const float* __restrict__ proj_w, const float* __restrict__ expert_emb,
    const float* __restrict__ expert_features, const float* __restrict__ trust,
    const float* __restrict__ dt, float* __restrict__ pwT,
    float* __restrict__ embT, float* __restrict__ enT,
    float* __restrict__ coef, int* __restrict__ cnt) {
  int bid = blockIdx.x, tid = threadIdx.x;
  if (bid < 512) {
    int idx = bid * 256 + tid;
    int f = idx >> 8, h = idx & 255;
    pwT[idx] = proj_w[h * 512 + f];
    if (bid == 0 && tid < E_N) cnt[tid] = 0;
  } else {
    int e = bid - 512;  // 0..63
    float v0 = expert_features[e * 512 + tid];
    float v1 = expert_features[e * 512 + tid + 256];
    float ss = v0 * v0 + v1 * v1;
    #pragma unroll
    for (int off = 32; off; off >>= 1) ss += __shfl_xor(ss, off);
    __shared__ float parts[4];
    if ((tid & 63) == 0) parts[tid >> 6] = ss;
    __syncthreads();
    float tot = parts[0] + parts[1] + parts[2] + parts[3];
    float inv = 1.0f / fmaxf(sqrtf(tot), 1e-8f);
    enT[tid * 64 + e] = v0 * inv;
    enT[(tid + 256) * 64 + e] = v1 * inv;
    embT[tid * 64 + e] = expert_emb[e * 256 + tid];
    if (tid == 0) {
      float st = fmaxf(0.1f, expf(-0.005f * dt[e]));
      coef[e] = trust[e] * st;
    }
  }
}

// ---------------- K0g: Gpack[f][e] = (pwT[f]·embT[:,e], enT[f][e]); gbias ---
__global__ __launch_bounds__(64) void k0g(
    const float* __restrict__ pwT, const float* __restrict__ proj_b,
    const float* __restrict__ embT, const float* __restrict__ enT,
    float* __restrict__ Gpack, float* __restrict__ gbias) {
  __shared__ float row[256];
  int f = blockIdx.x;
  int e = threadIdx.x;  // 0..63
  const float* src = (f < 512) ? (pwT + f * 256) : proj_b;
  *(float4*)&row[e * 4] = *(const float4*)&src[e * 4];
  __syncthreads();
  float g = 0.0f;
  #pragma unroll 8
  for (int h = 0; h < 256; ++h) g = fmaf(row[h], embT[h * 64 + e], g);
  if (f < 512) {
    Gpack[(f * 64 + e) * 2 + 0] = g;
    Gpack[(f * 64 + e) * 2 + 1] = enT[f * 64 + e];
  } else {
    gbias[e] = g;
  }
}

// ---------------- conv: features -> fp16 ------------------------------------
__global__ __launch_bounds__(256) void k_convF(const float* __restrict__ f,
                                               _Float16* __restrict__ Fh) {
  int i = (blockIdx.x * 256 + threadIdx.x) * 8;
  float4 v0 = *(const float4*)(f + i);
  float4 v1 = *(const float4*)(f + i + 4);
  half8 h;
  h[0] = (_Float16)v0.x; h[1] = (_Float16)v0.y;
  h[2] = (_Float16)v0.z; h[3] = (_Float16)v0.w;
  h[4] = (_Float16)v1.x; h[5] = (_Float16)v1.y;
  h[6] = (_Float16)v1.z; h[7] = (_Float16)v1.w;
  *(half8*)(Fh + i) = h;
}

// ---------------- conv: fst_w -> transposed fp16 [e][col][k] ----------------
// coalesced 1KB/wave fp32 row reads -> LDS [64][260] -> per-thread col
// conversion -> 128B-contiguous writes per col.
__global__ __launch_bounds__(256) void k_convW(const float* __restrict__ fst_w,
                                               _Float16* __restrict__ WhT) {
  __shared__ float tile[64][260];  // pad 4
  int bid = blockIdx.x;            // 1024 = 64e x 8kb x 2cb
  int e = bid >> 4;
  int kb = (bid >> 1) & 7;
  int cb = bid & 1;
  int tid = threadIdx.x;

  const float* src = fst_w + ((size_t)e << 18) + (size_t)(kb * 64) * 512 +
                     cb * 256;
  int kr = tid >> 6;        // wave id
  int c4 = (tid & 63) * 4;
  #pragma unroll
  for (int r = 0; r < 16; ++r) {
    int k = r * 4 + kr;
    *(float4*)&tile[k][c4] = *(const float4*)&src[(size_t)k * 512 + c4];
  }
  __syncthreads();

  int c = tid;
  size_t dbase = ((size_t)e << 18) + (size_t)(cb * 256 + c) * 512 + kb * 64;
  #pragma unroll
  for (int g = 0; g < 8; ++g) {
    half8 vh;
    #pragma unroll
    for (int i = 0; i < 8; ++i) vh[i] = (_Float16)tile[g * 8 + i][c];
    *(half8*)(WhT + dbase + g * 8) = vh;
  }
}

// ---------------- K1: score + top-8 + softmax + scatter (8 tok/block) -------
__global__ __launch_bounds__(256) void k1_score(
    const float* __restrict__ features, const float* __restrict__ Gpack,
    const float* __restrict__ gbias, const float* __restrict__ coef,
    int* __restrict__ cnt, int* __restrict__ tk_idx, float* __restrict__ tk_w,
    int* __restrict__ tlist, float* __restrict__ wlist) {
  __shared__ float Ft[8][512];  // 16 KB
  int tid = threadIdx.x;
  int b0 = blockIdx.x * 8;

  #pragma unroll
  for (int q = 0; q < 4; ++q) {
    int idx = q * 256 + tid;
    int t = idx >> 7;
    int fo = (idx & 127) * 4;
    *(float4*)&Ft[t][fo] =
        *(const float4*)&features[(size_t)(b0 + t) * 512 + fo];
  }
  __syncthreads();

  int wave = tid >> 6, e = tid & 63;
  float cf = coef[e];
  float gb = gbias[e];
  int t0 = wave * 2, t1 = t0 + 1;

  float l0 = 0.f, s0 = 0.f, l1 = 0.f, s1 = 0.f;
  #pragma unroll 8
  for (int f = 0; f < 512; ++f) {
    float2 gp = *(const float2*)&Gpack[(f * 64 + e) * 2];
    float f0 = Ft[t0][f];
    float f1 = Ft[t1][f];
    l0 = fmaf(f0, gp.x, l0);
    s0 = fmaf(f0, gp.y, s0);
    l1 = fmaf(f1, gp.x, l1);
    s1 = fmaf(f1, gp.y, s1);
  }
  float n0 = 0.f, n1 = 0.f;
  #pragma unroll
  for (int j = 0; j < 8; ++j) {
    float v0 = Ft[t0][e + 64 * j];
    float v1 = Ft[t1][e + 64 * j];
    n0 = fmaf(v0, v0, n0);
    n1 = fmaf(v1, v1, n1);
  }
  #pragma unroll
  for (int off = 32; off; off >>= 1) {
    n0 += __shfl_xor(n0, off);
    n1 += __shfl_xor(n1, off);
  }

  #pragma unroll
  for (int tt = 0; tt < 2; ++tt) {
    float l = tt ? l1 : l0;
    float s = tt ? s1 : s0;
    float nn = tt ? n1 : n0;
    int b = b0 + wave * 2 + tt;
    float inv_n = 1.0f / fmaxf(sqrtf(nn), 1e-8f);
    float gate = 1.0f / (1.0f + expf(-(l + gb) * 0.0625f));
    float sim = fmaxf(s * inv_n, 0.0f);
    float score = gate * sim * cf;

    float cur = score;
    float bv[8];
    int bi[8];
    #pragma unroll
    for (int r = 0; r < 8; ++r) {
      float mv = cur;
      int mi = e;
      #pragma unroll
      for (int off = 1; off < 64; off <<= 1) {
        float ov = __shfl_xor(mv, off);
        int oi = __shfl_xor(mi, off);
        if (ov > mv || (ov == mv && oi < mi)) { mv = ov; mi = oi; }
      }
      bv[r] = mv;
      bi[r] = mi;
      if (e == mi) cur = -1.0f;
    }
    float m0 = bv[0];
    float ex[8];
    float sum = 0.0f;
    #pragma unroll
    for (int r = 0; r < 8; ++r) { ex[r] = expf(bv[r] - m0); sum += ex[r]; }
    float isum = 1.0f / sum;

    if (e < 8) {
      int ir = 0; float er = 0.0f;
      switch (e) {
        case 0: ir = bi[0]; er = ex[0]; break;
        case 1: ir = bi[1]; er = ex[1]; break;
        case 2: ir = bi[2]; er = ex[2]; break;
        case 3: ir = bi[3]; er = ex[3]; break;
        case 4: ir = bi[4]; er = ex[4]; break;
        case 5: ir = bi[5]; er = ex[5]; break;
        case 6: ir = bi[6]; er = ex[6]; break;
        case 7: ir = bi[7]; er = ex[7]; break;
      }
      float wr = er * isum;
      int pos = atomicAdd(&cnt[ir], 1);
      tlist[ir * B_N + pos] = b;
      wlist[ir * B_N + pos] = wr;
      tk_idx[b * 8 + e] = ir;
      tk_w[b * 8 + e] = wr;
    }
  }
}

// ---------------- K2: out[b,:] = sum_k w_k * fst_b[e_k,:]  ------------------
__global__ __launch_bounds__(256) void k2_bias(
    const int* __restrict__ tk_idx, const float* __restrict__ tk_w,
    const float* __restrict__ fst_b, float* __restrict__ out) {
  int b = blockIdx.x, tid = threadIdx.x;
  int ir[8];
  float wr[8];
  #pragma unroll
  for (int r = 0; r < 8; ++r) {
    ir[r] = tk_idx[b * 8 + r];
    wr[r] = tk_w[b * 8 + r];
  }
  #pragma unroll
  for (int q = 0; q < 2; ++q) {
    int f = tid + q * 256;
    float a = 0.0f;
    #pragma unroll
    for (int r = 0; r < 8; ++r) a = fmaf(wr[r], fst_b[ir[r] * 512 + f], a);
    out[(size_t)b * 512 + f] = a;
  }
}

// ---------------- K3 (MFMA): gathered per-expert FST, fp16 single-term ------
// Block: 64 tokens x 128 cols x K=512 (8 steps of 64). 4 waves, M64xN32 each.
// Double-buffered LDS (48.5 KB -> 3 blocks/CU), stage(s+1) issued before
// compute(s), one barrier per step.
// Dispatch: bid = tile + 32*chunk + 128*e  -> consecutive active tiles of an
// expert land on consecutive CUs (r4/r5 had all tiles of (e,chunk) on ONE CU).
__global__ __launch_bounds__(256, 3) void k3_mfma(
    const _Float16* __restrict__ Fh, const _Float16* __restrict__ WhT,
    const int* __restrict__ cnt, const int* __restrict__ tlist,
    const float* __restrict__ wlist, float* __restrict__ out) {
  __shared__ _Float16 Bh[2][128 * 64];  // 32 KB
  __shared__ _Float16 Ah[2][64 * 64];   // 16 KB
  __shared__ int tl[64];
  __shared__ float wl[64];

  int tid = threadIdx.x;
  int bid = blockIdx.x;
  int tile = bid & 31;              // LOW bits: spreads tiles across CUs
  int chunk = (bid >> 5) & 3;
  int e = bid >> 7;
  int c0 = chunk * 128;
  int c_e = cnt[e];
  int t0 = tile * 64;
  if (t0 >= c_e) return;

  if (tid < 64) {
    int t = t0 + tid;
    tl[tid] = tlist[e * B_N + (t < c_e ? t : t0)];
    wl[tid] = (t < c_e) ? wlist[e * B_N + t] : 0.0f;
  }
  __syncthreads();

  int wave = tid >> 6, lane = tid & 63;
  const _Float16* WhT_e = WhT + ((size_t)e << 18);

  // staging source offsets (elements), pre-swizzled: LDS row-major, k-slot p
  // holds logical k-group g = p ^ (row&7)  (0-conflict, validated r4/r5)
  size_t bsrc[4];
  int bdst[4];
  #pragma unroll
  for (int i = 0; i < 4; ++i) {
    int cw = wave * 32 + i * 8;
    int cl = cw + (lane >> 3);
    int g = (lane & 7) ^ (cl & 7);
    bsrc[i] = (size_t)(c0 + cl) * 512 + g * 8;
    bdst[i] = cw * 64;
  }
  size_t asrc[2];
  int adst[2];
  #pragma unroll
  for (int j = 0; j < 2; ++j) {
    int tw = wave * 16 + j * 8;
    int tkl = tw + (lane >> 3);
    int g = (lane & 7) ^ (tkl & 7);
    asrc[j] = (size_t)tl[tkl] * 512 + g * 8;
    adst[j] = tw * 64;
  }

  f32x4 acc[4][2];
  #pragma unroll
  for (int mt = 0; mt < 4; ++mt)
    #pragma unroll
    for (int ct = 0; ct < 2; ++ct) acc[mt][ct] = (f32x4){0.f, 0.f, 0.f, 0.f};

  int kg = lane >> 4;
  int mrow = lane & 15;

  #define STAGE(K0S, BUF)                                                     \
    do {                                                                      \
      _Pragma("unroll")                                                       \
      for (int i = 0; i < 4; ++i) {                                           \
        __builtin_amdgcn_global_load_lds(                                     \
            (const __attribute__((address_space(1))) void*)(WhT_e + bsrc[i] + (K0S)), \
            (__attribute__((address_space(3))) void*)(&Bh[BUF][0] + bdst[i]), 16, 0, 0);\
      }                                                                       \
      _Pragma("unroll")                                                       \
      for (int j = 0; j < 2; ++j) {                                           \
        __builtin_amdgcn_global_load_lds(                                     \
            (const __attribute__((address_space(1))) void*)(Fh + asrc[j] + (K0S)), \
            (__attribute__((address_space(3))) void*)(&Ah[BUF][0] + adst[j]), 16, 0, 0);\
      }                                                                       \
    } while (0)

  STAGE(0, 0);
  __syncthreads();  // prologue drain

  int buf = 0;
  for (int s = 0; s < 8; ++s) {
    if (s < 7) STAGE((s + 1) * 64, buf ^ 1);  // issue next-step loads FIRST
    #pragma unroll
    for (int kh = 0; kh < 2; ++kh) {
      int gq = kh * 4 + kg;
      half8 af[4], bf[2];
      #pragma unroll
      for (int mt = 0; mt < 4; ++mt) {
        int tr = mt * 16 + mrow;
        af[mt] = *(const half8*)(&Ah[buf][0] + tr * 64 + ((gq ^ (tr & 7)) * 8));
      }
      #pragma unroll
      for (int ct = 0; ct < 2; ++ct) {
        int cl = wave * 32 + ct * 16 + mrow;
        bf[ct] = *(const half8*)(&Bh[buf][0] + cl * 64 + ((gq ^ (cl & 7)) * 8));
      }
      #pragma unroll
      for (int mt = 0; mt < 4; ++mt)
        #pragma unroll
        for (int ct = 0; ct < 2; ++ct)
          acc[mt][ct] = __builtin_amdgcn_mfma_f32_16x16x32_f16(
              af[mt], bf[ct], acc[mt][ct], 0, 0, 0);
    }
    __syncthreads();  // drains vmcnt: next buf staged, cur buf free
    buf ^= 1;
  }
  #undef STAGE

  // epilogue: C/D layout col=lane&15, row=(lane>>4)*4+r
  int rbase = (lane >> 4) * 4;
  #pragma unroll
  for (int mt = 0; mt < 4; ++mt) {
    #pragma unroll
    for (int r = 0; r < 4; ++r) {
      int tloc = mt * 16 + rbase + r;
      float w = wl[tloc];
      if (w != 0.0f) {
        size_t orow = (size_t)tl[tloc] * 512 + c0 + wave * 32 + mrow;
        atomicAdd(out + orow, w * acc[mt][0][r]);
        atomicAdd(out + orow + 16, w * acc[mt][1][r]);
      }
    }
  }
}

// ---------------- K3 fallback (fp32 VALU) -----------------------------------
#define TM 64
#define TN 256
#define KC 16
__global__ __launch_bounds__(256, 2) void k3_fst(
    const float* __restrict__ features, const float* __restrict__ fst_w,
    const int* __restrict__ cnt, const int* __restrict__ tlist,
    const float* __restrict__ wlist, float* __restrict__ out) {
  __shared__ float Ws[2][KC][TN];
  __shared__ float Ft[2][KC][TM];
  __shared__ int tl[TM];
  __shared__ float wl[TM];

  int tid = threadIdx.x;
  int e = blockIdx.x & 63;
  int rest = blockIdx.x >> 6;
  int tile = rest >> 1;
  int ch = rest & 1;
  int c0 = ch * TN;
  int c_e = cnt[e];
  int t0 = tile * TM;
  if (t0 >= c_e) return;

  if (tid < TM) {
    int t = t0 + tid;
    if (t < c_e) {
      tl[tid] = tlist[e * B_N + t];
      wl[tid] = wlist[e * B_N + t];
    } else {
      tl[tid] = tlist[e * B_N + t0];
      wl[tid] = 0.0f;
    }
  }
  __syncthreads();

  const float* fw_e = fst_w + (size_t)e * (512 * 512);
  int wave = tid >> 6, lane = tid & 63;
  int tg = wave * 2 + (lane >> 5);
  int cg = lane & 31;
  int ft_t = tid >> 2;
  int ft_fq = tid & 3;
  const float* ft_src_row = features + (size_t)tl[ft_t] * 512;

  auto stageWs = [&](int kc, int buf) {
    int f0 = kc * KC;
    #pragma unroll
    for (int r = 0; r < 4; ++r) {
      int f = wave * 4 + r;
      const float* src = fw_e + (size_t)(f0 + f) * 512 + c0 + lane * 4;
      __builtin_amdgcn_global_load_lds(
          (const __attribute__((address_space(1))) void*)src,
          (__attribute__((address_space(3))) void*)&Ws[buf][f][0], 16, 0, 0);
    }
  };
  auto loadFt = [&](int kc) -> float4 {
    return *(const float4*)&ft_src_row[kc * KC + ft_fq * 4];
  };
  auto writeFt = [&](float4 v, int buf) {
    Ft[buf][ft_fq * 4 + 0][ft_t] = v.x;
    Ft[buf][ft_fq * 4 + 1][ft_t] = v.y;
    Ft[buf][ft_fq * 4 + 2][ft_t] = v.z;
    Ft[buf][ft_fq * 4 + 3][ft_t] = v.w;
  };

  float acc[8][8];
  #pragma unroll
  for (int j = 0; j < 8; ++j)
    #pragma unroll
    for (int i = 0; i < 8; ++i) acc[j][i] = 0.0f;

  auto compute = [&](int buf) {
    #pragma unroll 4
    for (int f = 0; f < KC; ++f) {
      float4 a0 = *(const float4*)&Ft[buf][f][tg * 8];
      float4 a1 = *(const float4*)&Ft[buf][f][tg * 8 + 4];
      float4 w0 = *(const float4*)&Ws[buf][f][cg * 4];
      float4 w1 = *(const float4*)&Ws[buf][f][cg * 4 + 128];
      float av[8] = {a0.x, a0.y, a0.z, a0.w, a1.x, a1.y, a1.z, a1.w};
      float wv[8] = {w0.x, w0.y, w0.z, w0.w, w1.x, w1.y, w1.z, w1.w};
      #pragma unroll
      for (int j = 0; j < 8; ++j)
        #pragma unroll
        for (int i = 0; i < 8; ++i)
          acc[j][i] = fmaf(av[j], wv[i], acc[j][i]);
    }
  };

  stageWs(0, 0);
  float4 rf = loadFt(0);
  writeFt(rf, 0);
  __syncthreads();

  for (int kc = 0; kc < 32; ++kc) {
    int cb = kc & 1, nb = cb ^ 1;
    float4 rn = make_float4(0.f, 0.f, 0.f, 0.f);
    if (kc < 31) {
      stageWs(kc + 1, nb);
      rn = loadFt(kc + 1);
    }
    compute(cb);
    if (kc < 31) writeFt(rn, nb);
    __syncthreads();
  }

  #pragma unroll
  for (int j = 0; j < 8; ++j) {
    int lt = tg * 8 + j;
    float w = wl[lt];
    if (w != 0.0f) {
      size_t orow = (size_t)tl[lt] * 512 + c0 + cg * 4;
      #pragma unroll
      for (int i = 0; i < 4; ++i) atomicAdd(&out[orow + i], w * acc[j][i]);
      #pragma unroll
      for (int i = 0; i < 4; ++i)
        atomicAdd(&out[orow + 128 + i], w * acc[j][i + 4]);
    }
  }
}

// ---------------- launch ----------------------------------------------------
extern "C" void kernel_launch(void* const* d_in, const int* in_sizes, int n_in,
                              void* d_out, int out_size, void* d_ws,
                              size_t ws_size, hipStream_t stream) {
  const float* features = (const float*)d_in[0];
  const float* proj_w = (const float*)d_in[1];
  const float* proj_b = (const float*)d_in[2];
  const float* expert_emb = (const float*)d_in[3];
  const float* expert_features = (const float*)d_in[4];
  const float* trust = (const float*)d_in[5];
  const float* dt = (const float*)d_in[6];
  const float* fst_w = (const float*)d_in[7];
  const float* fst_b = (const float*)d_in[8];
  float* out = (float*)d_out;

  float* ws = (float*)d_ws;
  float* pwT = ws;                           // 512*256
  float* embT = pwT + 131072;                // 256*64
  float* enT = embT + 16384;                 // 512*64
  float* coef = enT + 32768;                 // 64
  int* cnt = (int*)(coef + 64);              // 64
  int* tk_idx = cnt + 64;                    // 2048*8
  float* tk_w = (float*)(tk_idx + 16384);    // 2048*8
  int* tlist = (int*)(tk_w + 16384);         // 64*2048
  float* wlist = (float*)(tlist + 131072);   // 64*2048
  float* Gpack = wlist + 131072;             // 512*64*2
  float* gbias = Gpack + 65536;              // 64
  _Float16* Fh = (_Float16*)(gbias + 64);    // 2048*512
  _Float16* WhT = Fh + (1 << 20);            // 64*512*512
  size_t need = (size_t)((char*)(WhT + (1 << 24)) - (char*)d_ws);
  bool big = ws_size >= need;

  hipLaunchKernelGGL(k0_prep, dim3(576), dim3(256), 0, stream, proj_w,
                     expert_emb, expert_features, trust, dt, pwT, embT, enT,
                     coef, cnt);
  hipLaunchKernelGGL(k0g, dim3(513), dim3(64), 0, stream, pwT, proj_b, embT,
                     enT, Gpack, gbias);
  if (big) {
    hipLaunchKernelGGL(k_convF, dim3(512), dim3(256), 0, stream, features, Fh);
    hipLaunchKernelGGL(k_convW, dim3(1024), dim3(256), 0, stream, fst_w, WhT);
  }
  hipLaunchKernelGGL(k1_score, dim3(256), dim3(256), 0, stream, features,
                     Gpack, gbias, coef, cnt, tk_idx, tk_w, tlist, wlist);
  hipLaunchKernelGGL(k2_bias, dim3(2048), dim3(256), 0, stream, tk_idx, tk_w,
                     fst_b, out);
  if (big) {
    hipLaunchKernelGGL(k3_mfma, dim3(8192), dim3(256), 0, stream, Fh, WhT, cnt,
                       tlist, wlist, out);
  } else {
    hipLaunchKernelGGL(k3_fst, dim3(4096), dim3(256), 0, stream, features,
                       fst_w, cnt, tlist, wlist, out);
  }
}

// Round 7
// 148.989 us; speedup vs baseline: 1.8705x; 1.4198x over previous
//
#include <hip/hip_runtime.h>
#include <hip/hip_fp16.h>
#include <math.h>

#define B_N 2048
#define F_N 512
#define H_N 256
#define E_N 64

typedef __attribute__((ext_vector_type(8))) _Float16 half8;
typedef __attribute__((ext_vector_type(4))) float f32x4;

// ---------------- K0: prep (transposes, expert norms, coef, zero counts) ----
__global__ __launch_bounds__(256) void k0_prep(
    const float* __restrict__ proj_w, const float* __restrict__ expert_emb,
    const float* __restrict__ expert_features, const float* __restrict__ trust,
    const float* __restrict__ dt, float* __restrict__ pwT,
    float* __restrict__ embT, float* __restrict__ enT,
    float* __restrict__ coef, int* __restrict__ cnt) {
  int bid = blockIdx.x, tid = threadIdx.x;
  if (bid < 512) {
    int idx = bid * 256 + tid;
    int f = idx >> 8, h = idx & 255;
    pwT[idx] = proj_w[h * 512 + f];
    if (bid == 0 && tid < E_N) cnt[tid] = 0;
  } else {
    int e = bid - 512;  // 0..63
    float v0 = expert_features[e * 512 + tid];
    float v1 = expert_features[e * 512 + tid + 256];
    float ss = v0 * v0 + v1 * v1;
    #pragma unroll
    for (int off = 32; off; off >>= 1) ss += __shfl_xor(ss, off);
    __shared__ float parts[4];
    if ((tid & 63) == 0) parts[tid >> 6] = ss;
    __syncthreads();
    float tot = parts[0] + parts[1] + parts[2] + parts[3];
    float inv = 1.0f / fmaxf(sqrtf(tot), 1e-8f);
    enT[tid * 64 + e] = v0 * inv;
    enT[(tid + 256) * 64 + e] = v1 * inv;
    embT[tid * 64 + e] = expert_emb[e * 256 + tid];
    if (tid == 0) {
      float st = fmaxf(0.1f, expf(-0.005f * dt[e]));
      coef[e] = trust[e] * st;
    }
  }
}

// ---------------- K0g: Gpack[f][e] = (pwT[f]·embT[:,e], enT[f][e]); gbias ---
__global__ __launch_bounds__(64) void k0g(
    const float* __restrict__ pwT, const float* __restrict__ proj_b,
    const float* __restrict__ embT, const float* __restrict__ enT,
    float* __restrict__ Gpack, float* __restrict__ gbias) {
  __shared__ float row[256];
  int f = blockIdx.x;
  int e = threadIdx.x;  // 0..63
  const float* src = (f < 512) ? (pwT + f * 256) : proj_b;
  *(float4*)&row[e * 4] = *(const float4*)&src[e * 4];
  __syncthreads();
  float g = 0.0f;
  #pragma unroll 8
  for (int h = 0; h < 256; ++h) g = fmaf(row[h], embT[h * 64 + e], g);
  if (f < 512) {
    Gpack[(f * 64 + e) * 2 + 0] = g;
    Gpack[(f * 64 + e) * 2 + 1] = enT[f * 64 + e];
  } else {
    gbias[e] = g;
  }
}

// ---------------- conv: features -> fp16 ------------------------------------
__global__ __launch_bounds__(256) void k_convF(const float* __restrict__ f,
                                               _Float16* __restrict__ Fh) {
  int i = (blockIdx.x * 256 + threadIdx.x) * 8;
  float4 v0 = *(const float4*)(f + i);
  float4 v1 = *(const float4*)(f + i + 4);
  half8 h;
  h[0] = (_Float16)v0.x; h[1] = (_Float16)v0.y;
  h[2] = (_Float16)v0.z; h[3] = (_Float16)v0.w;
  h[4] = (_Float16)v1.x; h[5] = (_Float16)v1.y;
  h[6] = (_Float16)v1.z; h[7] = (_Float16)v1.w;
  *(half8*)(Fh + i) = h;
}

// ---------------- conv: fst_w -> transposed fp16 [e][col][k] ----------------
// v3: coalesced fp32 row reads -> staggered LDS -> per-(col,k8) threads so
// WRITES are 8 cols x 128B contiguous chunks per wave instr (full lines).
// LDS addr = k*260 + ((k>>3)<<2) + c  -> phase-2 read conflicts = 2-way (free).
__global__ __launch_bounds__(256) void k_convW(const float* __restrict__ fst_w,
                                               _Float16* __restrict__ WhT) {
  __shared__ float tile[16704];    // 64*260 + stagger slack (65.3 KB)
  int bid = blockIdx.x;            // 1024 = 64e x 8kb x 2cb
  int e = bid >> 4;
  int kb = (bid >> 1) & 7;
  int cb = bid & 1;
  int tid = threadIdx.x;

  // phase 1: each wave reads whole 1KB rows (64 lanes x float4), writes
  // consecutive float4s (conflict-free; stagger keeps 16B alignment)
  const float* src = fst_w + ((size_t)e << 18) + (size_t)(kb * 64) * 512 +
                     cb * 256;
  int kr = tid >> 6;        // wave id
  int c4 = (tid & 63) * 4;
  #pragma unroll
  for (int r = 0; r < 16; ++r) {
    int k = r * 4 + kr;
    *(float4*)&tile[k * 260 + ((k >> 3) << 2) + c4] =
        *(const float4*)&src[(size_t)k * 512 + c4];
  }
  __syncthreads();

  // phase 2: thread -> (col co = tid>>3, k-group ko = (tid&7)*8); 8 g-iters
  // cover 256 cols. Per wave instr: 8 cols x 16B-consecutive-lanes = full
  // 64B lines. LDS banks = (4*(t&7) + (t>>3) + const)%32 -> 2-way (free).
  int co = tid >> 3;        // 0..31
  int ko = (tid & 7) * 8;   // 0,8,..,56
  #pragma unroll
  for (int g = 0; g < 8; ++g) {
    int c = g * 32 + co;
    half8 vh;
    #pragma unroll
    for (int i = 0; i < 8; ++i) {
      int k = ko + i;
      vh[i] = (_Float16)tile[k * 260 + ((k >> 3) << 2) + c];
    }
    size_t dbase =
        ((size_t)e << 18) + (size_t)(cb * 256 + c) * 512 + kb * 64 + ko;
    *(half8*)(WhT + dbase) = vh;
  }
}

// ---------------- K_sched: compact job list (e, tile) via wave prefix sum ---
__global__ __launch_bounds__(64) void k_sched(const int* __restrict__ cnt,
                                              int* __restrict__ jobs,
                                              int* __restrict__ njobs) {
  int e = threadIdx.x;  // 0..63, one wave
  int nt = (cnt[e] + 63) >> 6;
  int inc = nt;
  #pragma unroll
  for (int d = 1; d < 64; d <<= 1) {
    int v = __shfl_up(inc, d);
    if (e >= d) inc += v;
  }
  int base = inc - nt;  // exclusive prefix
  for (int t = 0; t < nt; ++t) jobs[base + t] = (e << 8) | t;
  if (e == 63) njobs[0] = inc;
}

// ---------------- K1: score + top-8 + softmax + scatter (8 tok/block) -------
__global__ __launch_bounds__(256) void k1_score(
    const float* __restrict__ features, const float* __restrict__ Gpack,
    const float* __restrict__ gbias, const float* __restrict__ coef,
    int* __restrict__ cnt, int* __restrict__ tk_idx, float* __restrict__ tk_w,
    int* __restrict__ tlist, float* __restrict__ wlist) {
  __shared__ float Ft[8][512];  // 16 KB
  int tid = threadIdx.x;
  int b0 = blockIdx.x * 8;

  #pragma unroll
  for (int q = 0; q < 4; ++q) {
    int idx = q * 256 + tid;
    int t = idx >> 7;
    int fo = (idx & 127) * 4;
    *(float4*)&Ft[t][fo] =
        *(const float4*)&features[(size_t)(b0 + t) * 512 + fo];
  }
  __syncthreads();

  int wave = tid >> 6, e = tid & 63;
  float cf = coef[e];
  float gb = gbias[e];
  int t0 = wave * 2, t1 = t0 + 1;

  float l0 = 0.f, s0 = 0.f, l1 = 0.f, s1 = 0.f;
  #pragma unroll 8
  for (int f = 0; f < 512; ++f) {
    float2 gp = *(const float2*)&Gpack[(f * 64 + e) * 2];
    float f0 = Ft[t0][f];
    float f1 = Ft[t1][f];
    l0 = fmaf(f0, gp.x, l0);
    s0 = fmaf(f0, gp.y, s0);
    l1 = fmaf(f1, gp.x, l1);
    s1 = fmaf(f1, gp.y, s1);
  }
  float n0 = 0.f, n1 = 0.f;
  #pragma unroll
  for (int j = 0; j < 8; ++j) {
    float v0 = Ft[t0][e + 64 * j];
    float v1 = Ft[t1][e + 64 * j];
    n0 = fmaf(v0, v0, n0);
    n1 = fmaf(v1, v1, n1);
  }
  #pragma unroll
  for (int off = 32; off; off >>= 1) {
    n0 += __shfl_xor(n0, off);
    n1 += __shfl_xor(n1, off);
  }

  #pragma unroll
  for (int tt = 0; tt < 2; ++tt) {
    float l = tt ? l1 : l0;
    float s = tt ? s1 : s0;
    float nn = tt ? n1 : n0;
    int b = b0 + wave * 2 + tt;
    float inv_n = 1.0f / fmaxf(sqrtf(nn), 1e-8f);
    float gate = 1.0f / (1.0f + expf(-(l + gb) * 0.0625f));
    float sim = fmaxf(s * inv_n, 0.0f);
    float score = gate * sim * cf;

    float cur = score;
    float bv[8];
    int bi[8];
    #pragma unroll
    for (int r = 0; r < 8; ++r) {
      float mv = cur;
      int mi = e;
      #pragma unroll
      for (int off = 1; off < 64; off <<= 1) {
        float ov = __shfl_xor(mv, off);
        int oi = __shfl_xor(mi, off);
        if (ov > mv || (ov == mv && oi < mi)) { mv = ov; mi = oi; }
      }
      bv[r] = mv;
      bi[r] = mi;
      if (e == mi) cur = -1.0f;
    }
    float m0 = bv[0];
    float ex[8];
    float sum = 0.0f;
    #pragma unroll
    for (int r = 0; r < 8; ++r) { ex[r] = expf(bv[r] - m0); sum += ex[r]; }
    float isum = 1.0f / sum;

    if (e < 8) {
      int ir = 0; float er = 0.0f;
      switch (e) {
        case 0: ir = bi[0]; er = ex[0]; break;
        case 1: ir = bi[1]; er = ex[1]; break;
        case 2: ir = bi[2]; er = ex[2]; break;
        case 3: ir = bi[3]; er = ex[3]; break;
        case 4: ir = bi[4]; er = ex[4]; break;
        case 5: ir = bi[5]; er = ex[5]; break;
        case 6: ir = bi[6]; er = ex[6]; break;
        case 7: ir = bi[7]; er = ex[7]; break;
      }
      float wr = er * isum;
      int pos = atomicAdd(&cnt[ir], 1);
      tlist[ir * B_N + pos] = b;
      wlist[ir * B_N + pos] = wr;
      tk_idx[b * 8 + e] = ir;
      tk_w[b * 8 + e] = wr;
    }
  }
}

// ---------------- K2: out[b,:] = sum_k w_k * fst_b[e_k,:]  ------------------
__global__ __launch_bounds__(256) void k2_bias(
    const int* __restrict__ tk_idx, const float* __restrict__ tk_w,
    const float* __restrict__ fst_b, float* __restrict__ out) {
  int b = blockIdx.x, tid = threadIdx.x;
  int ir[8];
  float wr[8];
  #pragma unroll
  for (int r = 0; r < 8; ++r) {
    ir[r] = tk_idx[b * 8 + r];
    wr[r] = tk_w[b * 8 + r];
  }
  #pragma unroll
  for (int q = 0; q < 2; ++q) {
    int f = tid + q * 256;
    float a = 0.0f;
    #pragma unroll
    for (int r = 0; r < 8; ++r) a = fmaf(wr[r], fst_b[ir[r] * 512 + f], a);
    out[(size_t)b * 512 + f] = a;
  }
}

// ---------------- K3 (MFMA): gathered per-expert FST, fp16, job-compacted ---
// Block: 64 tokens x 128 cols x K=512 (8 steps of 64). 4 waves, M64xN32 each.
// Grid 2048: bid = job*4 + chunk, job indexes the COMPACT list from k_sched ->
// active blocks are the first ~1280 consecutive bids -> even CU distribution,
// 3 co-resident blocks/CU hide the per-step vmcnt drain via TLP.
__global__ __launch_bounds__(256, 3) void k3_mfma(
    const _Float16* __restrict__ Fh, const _Float16* __restrict__ WhT,
    const int* __restrict__ cnt, const int* __restrict__ tlist,
    const float* __restrict__ wlist, const int* __restrict__ jobs,
    const int* __restrict__ njobs, float* __restrict__ out) {
  __shared__ _Float16 Bh[2][128 * 64];  // 32 KB
  __shared__ _Float16 Ah[2][64 * 64];   // 16 KB
  __shared__ int tl[64];
  __shared__ float wl[64];

  int tid = threadIdx.x;
  int job = blockIdx.x >> 2;
  int chunk = blockIdx.x & 3;
  if (job >= njobs[0]) return;
  int jb = jobs[job];
  int e = jb >> 8;
  int tile = jb & 255;
  int c0 = chunk * 128;
  int c_e = cnt[e];
  int t0 = tile * 64;

  if (tid < 64) {
    int t = t0 + tid;
    tl[tid] = tlist[e * B_N + (t < c_e ? t : t0)];
    wl[tid] = (t < c_e) ? wlist[e * B_N + t] : 0.0f;
  }
  __syncthreads();

  int wave = tid >> 6, lane = tid & 63;
  const _Float16* WhT_e = WhT + ((size_t)e << 18);

  // staging source offsets (elements), pre-swizzled: LDS row-major, k-slot p
  // holds logical k-group g = p ^ (row&7)  (0-conflict, validated r4-r6)
  size_t bsrc[4];
  int bdst[4];
  #pragma unroll
  for (int i = 0; i < 4; ++i) {
    int cw = wave * 32 + i * 8;
    int cl = cw + (lane >> 3);
    int g = (lane & 7) ^ (cl & 7);
    bsrc[i] = (size_t)(c0 + cl) * 512 + g * 8;
    bdst[i] = cw * 64;
  }
  size_t asrc[2];
  int adst[2];
  #pragma unroll
  for (int j = 0; j < 2; ++j) {
    int tw = wave * 16 + j * 8;
    int tkl = tw + (lane >> 3);
    int g = (lane & 7) ^ (tkl & 7);
    asrc[j] = (size_t)tl[tkl] * 512 + g * 8;
    adst[j] = tw * 64;
  }

  f32x4 acc[4][2];
  #pragma unroll
  for (int mt = 0; mt < 4; ++mt)
    #pragma unroll
    for (int ct = 0; ct < 2; ++ct) acc[mt][ct] = (f32x4){0.f, 0.f, 0.f, 0.f};

  int kg = lane >> 4;
  int mrow = lane & 15;

  #define STAGE(K0S, BUF)                                                     \
    do {                                                                      \
      _Pragma("unroll")                                                       \
      for (int i = 0; i < 4; ++i) {                                           \
        __builtin_amdgcn_global_load_lds(                                     \
            (const __attribute__((address_space(1))) void*)(WhT_e + bsrc[i] + (K0S)), \
            (__attribute__((address_space(3))) void*)(&Bh[BUF][0] + bdst[i]), 16, 0, 0);\
      }                                                                       \
      _Pragma("unroll")                                                       \
      for (int j = 0; j < 2; ++j) {                                           \
        __builtin_amdgcn_global_load_lds(                                     \
            (const __attribute__((address_space(1))) void*)(Fh + asrc[j] + (K0S)), \
            (__attribute__((address_space(3))) void*)(&Ah[BUF][0] + adst[j]), 16, 0, 0);\
      }                                                                       \
    } while (0)

  STAGE(0, 0);
  __syncthreads();  // prologue drain

  int buf = 0;
  for (int s = 0; s < 8; ++s) {
    if (s < 7) STAGE((s + 1) * 64, buf ^ 1);  // issue next-step loads FIRST
    #pragma unroll
    for (int kh = 0; kh < 2; ++kh) {
      int gq = kh * 4 + kg;
      half8 af[4], bf[2];
      #pragma unroll
      for (int mt = 0; mt < 4; ++mt) {
        int tr = mt * 16 + mrow;
        af[mt] = *(const half8*)(&Ah[buf][0] + tr * 64 + ((gq ^ (tr & 7)) * 8));
      }
      #pragma unroll
      for (int ct = 0; ct < 2; ++ct) {
        int cl = wave * 32 + ct * 16 + mrow;
        bf[ct] = *(const half8*)(&Bh[buf][0] + cl * 64 + ((gq ^ (cl & 7)) * 8));
      }
      #pragma unroll
      for (int mt = 0; mt < 4; ++mt)
        #pragma unroll
        for (int ct = 0; ct < 2; ++ct)
          acc[mt][ct] = __builtin_amdgcn_mfma_f32_16x16x32_f16(
              af[mt], bf[ct], acc[mt][ct], 0, 0, 0);
    }
    __syncthreads();  // drains vmcnt: next buf staged, cur buf free
    buf ^= 1;
  }
  #undef STAGE

  // epilogue: C/D layout col=lane&15, row=(lane>>4)*4+r
  int rbase = (lane >> 4) * 4;
  #pragma unroll
  for (int mt = 0; mt < 4; ++mt) {
    #pragma unroll
    for (int r = 0; r < 4; ++r) {
      int tloc = mt * 16 + rbase + r;
      float w = wl[tloc];
      if (w != 0.0f) {
        size_t orow = (size_t)tl[tloc] * 512 + c0 + wave * 32 + mrow;
        atomicAdd(out + orow, w * acc[mt][0][r]);
        atomicAdd(out + orow + 16, w * acc[mt][1][r]);
      }
    }
  }
}

// ---------------- K3 fallback (fp32 VALU) -----------------------------------
#define TM 64
#define TN 256
#define KC 16
__global__ __launch_bounds__(256, 2) void k3_fst(
    const float* __restrict__ features, const float* __restrict__ fst_w,
    const int* __restrict__ cnt, const int* __restrict__ tlist,
    const float* __restrict__ wlist, float* __restrict__ out) {
  __shared__ float Ws[2][KC][TN];
  __shared__ float Ft[2][KC][TM];
  __shared__ int tl[TM];
  __shared__ float wl[TM];

  int tid = threadIdx.x;
  int e = blockIdx.x & 63;
  int rest = blockIdx.x >> 6;
  int tile = rest >> 1;
  int ch = rest & 1;
  int c0 = ch * TN;
  int c_e = cnt[e];
  int t0 = tile * TM;
  if (t0 >= c_e) return;

  if (tid < TM) {
    int t = t0 + tid;
    if (t < c_e) {
      tl[tid] = tlist[e * B_N + t];
      wl[tid] = wlist[e * B_N + t];
    } else {
      tl[tid] = tlist[e * B_N + t0];
      wl[tid] = 0.0f;
    }
  }
  __syncthreads();

  const float* fw_e = fst_w + (size_t)e * (512 * 512);
  int wave = tid >> 6, lane = tid & 63;
  int tg = wave * 2 + (lane >> 5);
  int cg = lane & 31;
  int ft_t = tid >> 2;
  int ft_fq = tid & 3;
  const float* ft_src_row = features + (size_t)tl[ft_t] * 512;

  auto stageWs = [&](int kc, int buf) {
    int f0 = kc * KC;
    #pragma unroll
    for (int r = 0; r < 4; ++r) {
      int f = wave * 4 + r;
      const float* src = fw_e + (size_t)(f0 + f) * 512 + c0 + lane * 4;
      __builtin_amdgcn_global_load_lds(
          (const __attribute__((address_space(1))) void*)src,
          (__attribute__((address_space(3))) void*)&Ws[buf][f][0], 16, 0, 0);
    }
  };
  auto loadFt = [&](int kc) -> float4 {
    return *(const float4*)&ft_src_row[kc * KC + ft_fq * 4];
  };
  auto writeFt = [&](float4 v, int buf) {
    Ft[buf][ft_fq * 4 + 0][ft_t] = v.x;
    Ft[buf][ft_fq * 4 + 1][ft_t] = v.y;
    Ft[buf][ft_fq * 4 + 2][ft_t] = v.z;
    Ft[buf][ft_fq * 4 + 3][ft_t] = v.w;
  };

  float acc[8][8];
  #pragma unroll
  for (int j = 0; j < 8; ++j)
    #pragma unroll
    for (int i = 0; i < 8; ++i) acc[j][i] = 0.0f;

  auto compute = [&](int buf) {
    #pragma unroll 4
    for (int f = 0; f < KC; ++f) {
      float4 a0 = *(const float4*)&Ft[buf][f][tg * 8];
      float4 a1 = *(const float4*)&Ft[buf][f][tg * 8 + 4];
      float4 w0 = *(const float4*)&Ws[buf][f][cg * 4];
      float4 w1 = *(const float4*)&Ws[buf][f][cg * 4 + 128];
      float av[8] = {a0.x, a0.y, a0.z, a0.w, a1.x, a1.y, a1.z, a1.w};
      float wv[8] = {w0.x, w0.y, w0.z, w0.w, w1.x, w1.y, w1.z, w1.w};
      #pragma unroll
      for (int j = 0; j < 8; ++j)
        #pragma unroll
        for (int i = 0; i < 8; ++i)
          acc[j][i] = fmaf(av[j], wv[i], acc[j][i]);
    }
  };

  stageWs(0, 0);
  float4 rf = loadFt(0);
  writeFt(rf, 0);
  __syncthreads();

  for (int kc = 0; kc < 32; ++kc) {
    int cb = kc & 1, nb = cb ^ 1;
    float4 rn = make_float4(0.f, 0.f, 0.f, 0.f);
    if (kc < 31) {
      stageWs(kc + 1, nb);
      rn = loadFt(kc + 1);
    }
    compute(cb);
    if (kc < 31) writeFt(rn, nb);
    __syncthreads();
  }

  #pragma unroll
  for (int j = 0; j < 8; ++j) {
    int lt = tg * 8 + j;
    float w = wl[lt];
    if (w != 0.0f) {
      size_t orow = (size_t)tl[lt] * 512 + c0 + cg * 4;
      #pragma unroll
      for (int i = 0; i < 4; ++i) atomicAdd(&out[orow + i], w * acc[j][i]);
      #pragma unroll
      for (int i = 0; i < 4; ++i)
        atomicAdd(&out[orow + 128 + i], w * acc[j][i + 4]);
    }
  }
}

// ---------------- launch ----------------------------------------------------
extern "C" void kernel_launch(void* const* d_in, const int* in_sizes, int n_in,
                              void* d_out, int out_size, void* d_ws,
                              size_t ws_size, hipStream_t stream) {
  const float* features = (const float*)d_in[0];
  const float* proj_w = (const float*)d_in[1];
  const float* proj_b = (const float*)d_in[2];
  const float* expert_emb = (const float*)d_in[3];
  const float* expert_features = (const float*)d_in[4];
  const float* trust = (const float*)d_in[5];
  const float* dt = (const float*)d_in[6];
  const float* fst_w = (const float*)d_in[7];
  const float* fst_b = (const float*)d_in[8];
  float* out = (float*)d_out;

  float* ws = (float*)d_ws;
  float* pwT = ws;                           // 512*256
  float* embT = pwT + 131072;                // 256*64
  float* enT = embT + 16384;                 // 512*64
  float* coef = enT + 32768;                 // 64
  int* cnt = (int*)(coef + 64);              // 64
  int* tk_idx = cnt + 64;                    // 2048*8
  float* tk_w = (float*)(tk_idx + 16384);    // 2048*8
  int* tlist = (int*)(tk_w + 16384);         // 64*2048
  float* wlist = (float*)(tlist + 131072);   // 64*2048
  float* Gpack = wlist + 131072;             // 512*64*2
  float* gbias = Gpack + 65536;              // 64
  int* jobs = (int*)(gbias + 64);            // 2048
  int* njobs = jobs + 2048;                  // 64 (pad)
  _Float16* Fh = (_Float16*)(njobs + 64);    // 2048*512
  _Float16* WhT = Fh + (1 << 20);            // 64*512*512
  size_t need = (size_t)((char*)(WhT + (1 << 24)) - (char*)d_ws);
  bool big = ws_size >= need;

  hipLaunchKernelGGL(k0_prep, dim3(576), dim3(256), 0, stream, proj_w,
                     expert_emb, expert_features, trust, dt, pwT, embT, enT,
                     coef, cnt);
  hipLaunchKernelGGL(k0g, dim3(513), dim3(64), 0, stream, pwT, proj_b, embT,
                     enT, Gpack, gbias);
  if (big) {
    hipLaunchKernelGGL(k_convF, dim3(512), dim3(256), 0, stream, features, Fh);
    hipLaunchKernelGGL(k_convW, dim3(1024), dim3(256), 0, stream, fst_w, WhT);
  }
  hipLaunchKernelGGL(k1_score, dim3(256), dim3(256), 0, stream, features,
                     Gpack, gbias, coef, cnt, tk_idx, tk_w, tlist, wlist);
  hipLaunchKernelGGL(k2_bias, dim3(2048), dim3(256), 0, stream, tk_idx, tk_w,
                     fst_b, out);
  if (big) {
    hipLaunchKernelGGL(k_sched, dim3(1), dim3(64), 0, stream, cnt, jobs,
                       njobs);
    hipLaunchKernelGGL(k3_mfma, dim3(2048), dim3(256), 0, stream, Fh, WhT, cnt,
                       tlist, wlist, jobs, njobs, out);
  } else {
    hipLaunchKernelGGL(k3_fst, dim3(4096), dim3(256), 0, stream, features,
                       fst_w, cnt, tlist, wlist, out);
  }
}

// Round 8
// 146.987 us; speedup vs baseline: 1.8960x; 1.0136x over previous
//
#include <hip/hip_runtime.h>
#include <hip/hip_fp16.h>
#include <math.h>

#define B_N 2048
#define F_N 512
#define H_N 256
#define E_N 64

typedef __attribute__((ext_vector_type(8))) _Float16 half8;
typedef __attribute__((ext_vector_type(4))) float f32x4;

// ---------------- K0: prep (transposes, expert norms, coef, zero counts) ----
__global__ __launch_bounds__(256) void k0_prep(
    const float* __restrict__ proj_w, const float* __restrict__ expert_emb,
    const float* __restrict__ expert_features, const float* __restrict__ trust,
    const float* __restrict__ dt, float* __restrict__ pwT,
    float* __restrict__ embT, float* __restrict__ enT,
    float* __restrict__ coef, int* __restrict__ cnt) {
  int bid = blockIdx.x, tid = threadIdx.x;
  if (bid < 512) {
    int idx = bid * 256 + tid;
    int f = idx >> 8, h = idx & 255;
    pwT[idx] = proj_w[h * 512 + f];
    if (bid == 0 && tid < E_N) cnt[tid] = 0;
  } else {
    int e = bid - 512;  // 0..63
    float v0 = expert_features[e * 512 + tid];
    float v1 = expert_features[e * 512 + tid + 256];
    float ss = v0 * v0 + v1 * v1;
    #pragma unroll
    for (int off = 32; off; off >>= 1) ss += __shfl_xor(ss, off);
    __shared__ float parts[4];
    if ((tid & 63) == 0) parts[tid >> 6] = ss;
    __syncthreads();
    float tot = parts[0] + parts[1] + parts[2] + parts[3];
    float inv = 1.0f / fmaxf(sqrtf(tot), 1e-8f);
    enT[tid * 64 + e] = v0 * inv;
    enT[(tid + 256) * 64 + e] = v1 * inv;
    embT[tid * 64 + e] = expert_emb[e * 256 + tid];
    if (tid == 0) {
      float st = fmaxf(0.1f, expf(-0.005f * dt[e]));
      coef[e] = trust[e] * st;
    }
  }
}

// ---------------- K0g: Gpack[f][e] = (pwT[f]·embT[:,e], enT[f][e]); gbias ---
__global__ __launch_bounds__(64) void k0g(
    const float* __restrict__ pwT, const float* __restrict__ proj_b,
    const float* __restrict__ embT, const float* __restrict__ enT,
    float* __restrict__ Gpack, float* __restrict__ gbias) {
  __shared__ float row[256];
  int f = blockIdx.x;
  int e = threadIdx.x;  // 0..63
  const float* src = (f < 512) ? (pwT + f * 256) : proj_b;
  *(float4*)&row[e * 4] = *(const float4*)&src[e * 4];
  __syncthreads();
  float g = 0.0f;
  #pragma unroll 8
  for (int h = 0; h < 256; ++h) g = fmaf(row[h], embT[h * 64 + e], g);
  if (f < 512) {
    Gpack[(f * 64 + e) * 2 + 0] = g;
    Gpack[(f * 64 + e) * 2 + 1] = enT[f * 64 + e];
  } else {
    gbias[e] = g;
  }
}

// ---------------- conv: features -> fp16 ------------------------------------
__global__ __launch_bounds__(256) void k_convF(const float* __restrict__ f,
                                               _Float16* __restrict__ Fh) {
  int i = (blockIdx.x * 256 + threadIdx.x) * 8;
  float4 v0 = *(const float4*)(f + i);
  float4 v1 = *(const float4*)(f + i + 4);
  half8 h;
  h[0] = (_Float16)v0.x; h[1] = (_Float16)v0.y;
  h[2] = (_Float16)v0.z; h[3] = (_Float16)v0.w;
  h[4] = (_Float16)v1.x; h[5] = (_Float16)v1.y;
  h[6] = (_Float16)v1.z; h[7] = (_Float16)v1.w;
  *(half8*)(Fh + i) = h;
}

// ---------------- conv: fst_w -> transposed fp16 [e][col][k] ----------------
// coalesced fp32 row reads -> staggered LDS -> per-(col,k8) threads so
// WRITES are 8 cols x 128B contiguous chunks per wave instr (full lines).
__global__ __launch_bounds__(256) void k_convW(const float* __restrict__ fst_w,
                                               _Float16* __restrict__ WhT) {
  __shared__ float tile[16704];    // 64*260 + stagger slack
  int bid = blockIdx.x;            // 1024 = 64e x 8kb x 2cb
  int e = bid >> 4;
  int kb = (bid >> 1) & 7;
  int cb = bid & 1;
  int tid = threadIdx.x;

  const float* src = fst_w + ((size_t)e << 18) + (size_t)(kb * 64) * 512 +
                     cb * 256;
  int kr = tid >> 6;        // wave id
  int c4 = (tid & 63) * 4;
  #pragma unroll
  for (int r = 0; r < 16; ++r) {
    int k = r * 4 + kr;
    *(float4*)&tile[k * 260 + ((k >> 3) << 2) + c4] =
        *(const float4*)&src[(size_t)k * 512 + c4];
  }
  __syncthreads();

  int co = tid >> 3;        // 0..31
  int ko = (tid & 7) * 8;   // 0,8,..,56
  #pragma unroll
  for (int g = 0; g < 8; ++g) {
    int c = g * 32 + co;
    half8 vh;
    #pragma unroll
    for (int i = 0; i < 8; ++i) {
      int k = ko + i;
      vh[i] = (_Float16)tile[k * 260 + ((k >> 3) << 2) + c];
    }
    size_t dbase =
        ((size_t)e << 18) + (size_t)(cb * 256 + c) * 512 + kb * 64 + ko;
    *(half8*)(WhT + dbase) = vh;
  }
}

// ---------------- K_sched: compact job list (e, tile) via wave prefix sum ---
__global__ __launch_bounds__(64) void k_sched(const int* __restrict__ cnt,
                                              int* __restrict__ jobs,
                                              int* __restrict__ njobs) {
  int e = threadIdx.x;  // 0..63, one wave
  int nt = (cnt[e] + 63) >> 6;
  int inc = nt;
  #pragma unroll
  for (int d = 1; d < 64; d <<= 1) {
    int v = __shfl_up(inc, d);
    if (e >= d) inc += v;
  }
  int base = inc - nt;  // exclusive prefix
  for (int t = 0; t < nt; ++t) jobs[base + t] = (e << 8) | t;
  if (e == 63) njobs[0] = inc;
}

// ---------------- K1: score + top-8 + softmax + scatter ---------------------
// v3 (TLP fix): 1024 blocks x 2 tokens. 4 waves = (token w&1) x (f-half w>>1);
// each wave does a 256-f partial dot -> LDS partials -> waves 0/1 combine and
// run top-8. 4 blocks/CU co-resident -> 4 waves/SIMD hides L2 latency
// (r7: 256 blocks = 1 wave/SIMD = 300cyc/iter serial stall, 65us).
__global__ __launch_bounds__(256) void k1_score(
    const float* __restrict__ features, const float* __restrict__ Gpack,
    const float* __restrict__ gbias, const float* __restrict__ coef,
    int* __restrict__ cnt, int* __restrict__ tk_idx, float* __restrict__ tk_w,
    int* __restrict__ tlist, float* __restrict__ wlist) {
  __shared__ float Ft[2][512];   // 4 KB
  __shared__ float pl[4][64];
  __shared__ float ps[4][64];
  __shared__ float pn[4];
  int tid = threadIdx.x;
  int b0 = blockIdx.x * 2;

  // stage 2 feature rows (256 float4 slots, 1 per thread)
  {
    int t = tid >> 7;
    int fo = (tid & 127) * 4;
    *(float4*)&Ft[t][fo] =
        *(const float4*)&features[(size_t)(b0 + t) * 512 + fo];
  }
  __syncthreads();

  int wave = tid >> 6, e = tid & 63;
  int tok = wave & 1;
  int f0 = (wave >> 1) * 256;

  // partial dots over 256 f's, 2 sub-accumulators per dot (4 chains)
  float la = 0.f, lb = 0.f, sa = 0.f, sb = 0.f;
  #pragma unroll 4
  for (int f = f0; f < f0 + 256; f += 2) {
    float2 g0 = *(const float2*)&Gpack[(f * 64 + e) * 2];
    float2 g1 = *(const float2*)&Gpack[((f + 1) * 64 + e) * 2];
    float x0 = Ft[tok][f];
    float x1 = Ft[tok][f + 1];
    la = fmaf(x0, g0.x, la);
    sa = fmaf(x0, g0.y, sa);
    lb = fmaf(x1, g1.x, lb);
    sb = fmaf(x1, g1.y, sb);
  }
  // partial norm over this wave's f-range
  float nn = 0.f;
  #pragma unroll
  for (int j = 0; j < 4; ++j) {
    float v = Ft[tok][f0 + e + 64 * j];
    nn = fmaf(v, v, nn);
  }
  #pragma unroll
  for (int off = 32; off; off >>= 1) nn += __shfl_xor(nn, off);

  pl[wave][e] = la + lb;
  ps[wave][e] = sa + sb;
  if (e == 0) pn[wave] = nn;
  __syncthreads();

  if (wave < 2) {  // finalize token `wave`
    int b = b0 + wave;
    float l = pl[wave][e] + pl[wave + 2][e];
    float s = ps[wave][e] + ps[wave + 2][e];
    float ntot = pn[wave] + pn[wave + 2];
    float cf = coef[e];
    float gb = gbias[e];
    float inv_n = 1.0f / fmaxf(sqrtf(ntot), 1e-8f);
    float gate = 1.0f / (1.0f + expf(-(l + gb) * 0.0625f));
    float sim = fmaxf(s * inv_n, 0.0f);
    float score = gate * sim * cf;

    // top-8: butterfly max with (value desc, index asc) tie-break
    float cur = score;
    float bv[8];
    int bi[8];
    #pragma unroll
    for (int r = 0; r < 8; ++r) {
      float mv = cur;
      int mi = e;
      #pragma unroll
      for (int off = 1; off < 64; off <<= 1) {
        float ov = __shfl_xor(mv, off);
        int oi = __shfl_xor(mi, off);
        if (ov > mv || (ov == mv && oi < mi)) { mv = ov; mi = oi; }
      }
      bv[r] = mv;
      bi[r] = mi;
      if (e == mi) cur = -1.0f;  // scores >= 0
    }
    float m0 = bv[0];
    float ex[8];
    float sum = 0.0f;
    #pragma unroll
    for (int r = 0; r < 8; ++r) { ex[r] = expf(bv[r] - m0); sum += ex[r]; }
    float isum = 1.0f / sum;

    if (e < 8) {
      int ir = 0; float er = 0.0f;
      switch (e) {
        case 0: ir = bi[0]; er = ex[0]; break;
        case 1: ir = bi[1]; er = ex[1]; break;
        case 2: ir = bi[2]; er = ex[2]; break;
        case 3: ir = bi[3]; er = ex[3]; break;
        case 4: ir = bi[4]; er = ex[4]; break;
        case 5: ir = bi[5]; er = ex[5]; break;
        case 6: ir = bi[6]; er = ex[6]; break;
        case 7: ir = bi[7]; er = ex[7]; break;
      }
      float wr = er * isum;
      int pos = atomicAdd(&cnt[ir], 1);
      tlist[ir * B_N + pos] = b;
      wlist[ir * B_N + pos] = wr;
      tk_idx[b * 8 + e] = ir;
      tk_w[b * 8 + e] = wr;
    }
  }
}

// ---------------- K2: out[b,:] = sum_k w_k * fst_b[e_k,:]  ------------------
__global__ __launch_bounds__(256) void k2_bias(
    const int* __restrict__ tk_idx, const float* __restrict__ tk_w,
    const float* __restrict__ fst_b, float* __restrict__ out) {
  int b = blockIdx.x, tid = threadIdx.x;
  int ir[8];
  float wr[8];
  #pragma unroll
  for (int r = 0; r < 8; ++r) {
    ir[r] = tk_idx[b * 8 + r];
    wr[r] = tk_w[b * 8 + r];
  }
  #pragma unroll
  for (int q = 0; q < 2; ++q) {
    int f = tid + q * 256;
    float a = 0.0f;
    #pragma unroll
    for (int r = 0; r < 8; ++r) a = fmaf(wr[r], fst_b[ir[r] * 512 + f], a);
    out[(size_t)b * 512 + f] = a;
  }
}

// ---------------- K3 (MFMA): gathered per-expert FST, fp16, job-compacted ---
__global__ __launch_bounds__(256, 3) void k3_mfma(
    const _Float16* __restrict__ Fh, const _Float16* __restrict__ WhT,
    const int* __restrict__ cnt, const int* __restrict__ tlist,
    const float* __restrict__ wlist, const int* __restrict__ jobs,
    const int* __restrict__ njobs, float* __restrict__ out) {
  __shared__ _Float16 Bh[2][128 * 64];  // 32 KB
  __shared__ _Float16 Ah[2][64 * 64];   // 16 KB
  __shared__ int tl[64];
  __shared__ float wl[64];

  int tid = threadIdx.x;
  int job = blockIdx.x >> 2;
  int chunk = blockIdx.x & 3;
  if (job >= njobs[0]) return;
  int jb = jobs[job];
  int e = jb >> 8;
  int tile = jb & 255;
  int c0 = chunk * 128;
  int c_e = cnt[e];
  int t0 = tile * 64;

  if (tid < 64) {
    int t = t0 + tid;
    tl[tid] = tlist[e * B_N + (t < c_e ? t : t0)];
    wl[tid] = (t < c_e) ? wlist[e * B_N + t] : 0.0f;
  }
  __syncthreads();

  int wave = tid >> 6, lane = tid & 63;
  const _Float16* WhT_e = WhT + ((size_t)e << 18);

  size_t bsrc[4];
  int bdst[4];
  #pragma unroll
  for (int i = 0; i < 4; ++i) {
    int cw = wave * 32 + i * 8;
    int cl = cw + (lane >> 3);
    int g = (lane & 7) ^ (cl & 7);
    bsrc[i] = (size_t)(c0 + cl) * 512 + g * 8;
    bdst[i] = cw * 64;
  }
  size_t asrc[2];
  int adst[2];
  #pragma unroll
  for (int j = 0; j < 2; ++j) {
    int tw = wave * 16 + j * 8;
    int tkl = tw + (lane >> 3);
    int g = (lane & 7) ^ (tkl & 7);
    asrc[j] = (size_t)tl[tkl] * 512 + g * 8;
    adst[j] = tw * 64;
  }

  f32x4 acc[4][2];
  #pragma unroll
  for (int mt = 0; mt < 4; ++mt)
    #pragma unroll
    for (int ct = 0; ct < 2; ++ct) acc[mt][ct] = (f32x4){0.f, 0.f, 0.f, 0.f};

  int kg = lane >> 4;
  int mrow = lane & 15;

  #define STAGE(K0S, BUF)                                                     \
    do {                                                                      \
      _Pragma("unroll")                                                       \
      for (int i = 0; i < 4; ++i) {                                           \
        __builtin_amdgcn_global_load_lds(                                     \
            (const __attribute__((address_space(1))) void*)(WhT_e + bsrc[i] + (K0S)), \
            (__attribute__((address_space(3))) void*)(&Bh[BUF][0] + bdst[i]), 16, 0, 0);\
      }                                                                       \
      _Pragma("unroll")                                                       \
      for (int j = 0; j < 2; ++j) {                                           \
        __builtin_amdgcn_global_load_lds(                                     \
            (const __attribute__((address_space(1))) void*)(Fh + asrc[j] + (K0S)), \
            (__attribute__((address_space(3))) void*)(&Ah[BUF][0] + adst[j]), 16, 0, 0);\
      }                                                                       \
    } while (0)

  STAGE(0, 0);
  __syncthreads();  // prologue drain

  int buf = 0;
  for (int s = 0; s < 8; ++s) {
    if (s < 7) STAGE((s + 1) * 64, buf ^ 1);  // issue next-step loads FIRST
    #pragma unroll
    for (int kh = 0; kh < 2; ++kh) {
      int gq = kh * 4 + kg;
      half8 af[4], bf[2];
      #pragma unroll
      for (int mt = 0; mt < 4; ++mt) {
        int tr = mt * 16 + mrow;
        af[mt] = *(const half8*)(&Ah[buf][0] + tr * 64 + ((gq ^ (tr & 7)) * 8));
      }
      #pragma unroll
      for (int ct = 0; ct < 2; ++ct) {
        int cl = wave * 32 + ct * 16 + mrow;
        bf[ct] = *(const half8*)(&Bh[buf][0] + cl * 64 + ((gq ^ (cl & 7)) * 8));
      }
      #pragma unroll
      for (int mt = 0; mt < 4; ++mt)
        #pragma unroll
        for (int ct = 0; ct < 2; ++ct)
          acc[mt][ct] = __builtin_amdgcn_mfma_f32_16x16x32_f16(
              af[mt], bf[ct], acc[mt][ct], 0, 0, 0);
    }
    __syncthreads();  // drains vmcnt: next buf staged, cur buf free
    buf ^= 1;
  }
  #undef STAGE

  // epilogue: C/D layout col=lane&15, row=(lane>>4)*4+r
  int rbase = (lane >> 4) * 4;
  #pragma unroll
  for (int mt = 0; mt < 4; ++mt) {
    #pragma unroll
    for (int r = 0; r < 4; ++r) {
      int tloc = mt * 16 + rbase + r;
      float w = wl[tloc];
      if (w != 0.0f) {
        size_t orow = (size_t)tl[tloc] * 512 + c0 + wave * 32 + mrow;
        atomicAdd(out + orow, w * acc[mt][0][r]);
        atomicAdd(out + orow + 16, w * acc[mt][1][r]);
      }
    }
  }
}

// ---------------- K3 fallback (fp32 VALU) -----------------------------------
#define TM 64
#define TN 256
#define KC 16
__global__ __launch_bounds__(256, 2) void k3_fst(
    const float* __restrict__ features, const float* __restrict__ fst_w,
    const int* __restrict__ cnt, const int* __restrict__ tlist,
    const float* __restrict__ wlist, float* __restrict__ out) {
  __shared__ float Ws[2][KC][TN];
  __shared__ float Ft[2][KC][TM];
  __shared__ int tl[TM];
  __shared__ float wl[TM];

  int tid = threadIdx.x;
  int e = blockIdx.x & 63;
  int rest = blockIdx.x >> 6;
  int tile = rest >> 1;
  int ch = rest & 1;
  int c0 = ch * TN;
  int c_e = cnt[e];
  int t0 = tile * TM;
  if (t0 >= c_e) return;

  if (tid < TM) {
    int t = t0 + tid;
    if (t < c_e) {
      tl[tid] = tlist[e * B_N + t];
      wl[tid] = wlist[e * B_N + t];
    } else {
      tl[tid] = tlist[e * B_N + t0];
      wl[tid] = 0.0f;
    }
  }
  __syncthreads();

  const float* fw_e = fst_w + (size_t)e * (512 * 512);
  int wave = tid >> 6, lane = tid & 63;
  int tg = wave * 2 + (lane >> 5);
  int cg = lane & 31;
  int ft_t = tid >> 2;
  int ft_fq = tid & 3;
  const float* ft_src_row = features + (size_t)tl[ft_t] * 512;

  auto stageWs = [&](int kc, int buf) {
    int f0 = kc * KC;
    #pragma unroll
    for (int r = 0; r < 4; ++r) {
      int f = wave * 4 + r;
      const float* src = fw_e + (size_t)(f0 + f) * 512 + c0 + lane * 4;
      __builtin_amdgcn_global_load_lds(
          (const __attribute__((address_space(1))) void*)src,
          (__attribute__((address_space(3))) void*)&Ws[buf][f][0], 16, 0, 0);
    }
  };
  auto loadFt = [&](int kc) -> float4 {
    return *(const float4*)&ft_src_row[kc * KC + ft_fq * 4];
  };
  auto writeFt = [&](float4 v, int buf) {
    Ft[buf][ft_fq * 4 + 0][ft_t] = v.x;
    Ft[buf][ft_fq * 4 + 1][ft_t] = v.y;
    Ft[buf][ft_fq * 4 + 2][ft_t] = v.z;
    Ft[buf][ft_fq * 4 + 3][ft_t] = v.w;
  };

  float acc[8][8];
  #pragma unroll
  for (int j = 0; j < 8; ++j)
    #pragma unroll
    for (int i = 0; i < 8; ++i) acc[j][i] = 0.0f;

  auto compute = [&](int buf) {
    #pragma unroll 4
    for (int f = 0; f < KC; ++f) {
      float4 a0 = *(const float4*)&Ft[buf][f][tg * 8];
      float4 a1 = *(const float4*)&Ft[buf][f][tg * 8 + 4];
      float4 w0 = *(const float4*)&Ws[buf][f][cg * 4];
      float4 w1 = *(const float4*)&Ws[buf][f][cg * 4 + 128];
      float av[8] = {a0.x, a0.y, a0.z, a0.w, a1.x, a1.y, a1.z, a1.w};
      float wv[8] = {w0.x, w0.y, w0.z, w0.w, w1.x, w1.y, w1.z, w1.w};
      #pragma unroll
      for (int j = 0; j < 8; ++j)
        #pragma unroll
        for (int i = 0; i < 8; ++i)
          acc[j][i] = fmaf(av[j], wv[i], acc[j][i]);
    }
  };

  stageWs(0, 0);
  float4 rf = loadFt(0);
  writeFt(rf, 0);
  __syncthreads();

  for (int kc = 0; kc < 32; ++kc) {
    int cb = kc & 1, nb = cb ^ 1;
    float4 rn = make_float4(0.f, 0.f, 0.f, 0.f);
    if (kc < 31) {
      stageWs(kc + 1, nb);
      rn = loadFt(kc + 1);
    }
    compute(cb);
    if (kc < 31) writeFt(rn, nb);
    __syncthreads();
  }

  #pragma unroll
  for (int j = 0; j < 8; ++j) {
    int lt = tg * 8 + j;
    float w = wl[lt];
    if (w != 0.0f) {
      size_t orow = (size_t)tl[lt] * 512 + c0 + cg * 4;
      #pragma unroll
      for (int i = 0; i < 4; ++i) atomicAdd(&out[orow + i], w * acc[j][i]);
      #pragma unroll
      for (int i = 0; i < 4; ++i)
        atomicAdd(&out[orow + 128 + i], w * acc[j][i + 4]);
    }
  }
}

// ---------------- launch ----------------------------------------------------
extern "C" void kernel_launch(void* const* d_in, const int* in_sizes, int n_in,
                              void* d_out, int out_size, void* d_ws,
                              size_t ws_size, hipStream_t stream) {
  const float* features = (const float*)d_in[0];
  const float* proj_w = (const float*)d_in[1];
  const float* proj_b = (const float*)d_in[2];
  const float* expert_emb = (const float*)d_in[3];
  const float* expert_features = (const float*)d_in[4];
  const float* trust = (const float*)d_in[5];
  const float* dt = (const float*)d_in[6];
  const float* fst_w = (const float*)d_in[7];
  const float* fst_b = (const float*)d_in[8];
  float* out = (float*)d_out;

  float* ws = (float*)d_ws;
  float* pwT = ws;                           // 512*256
  float* embT = pwT + 131072;                // 256*64
  float* enT = embT + 16384;                 // 512*64
  float* coef = enT + 32768;                 // 64
  int* cnt = (int*)(coef + 64);              // 64
  int* tk_idx = cnt + 64;                    // 2048*8
  float* tk_w = (float*)(tk_idx + 16384);    // 2048*8
  int* tlist = (int*)(tk_w + 16384);         // 64*2048
  float* wlist = (float*)(tlist + 131072);   // 64*2048
  float* Gpack = wlist + 131072;             // 512*64*2
  float* gbias = Gpack + 65536;              // 64
  int* jobs = (int*)(gbias + 64);            // 2048
  int* njobs = jobs + 2048;                  // 64 (pad)
  _Float16* Fh = (_Float16*)(njobs + 64);    // 2048*512
  _Float16* WhT = Fh + (1 << 20);            // 64*512*512
  size_t need = (size_t)((char*)(WhT + (1 << 24)) - (char*)d_ws);
  bool big = ws_size >= need;

  hipLaunchKernelGGL(k0_prep, dim3(576), dim3(256), 0, stream, proj_w,
                     expert_emb, expert_features, trust, dt, pwT, embT, enT,
                     coef, cnt);
  hipLaunchKernelGGL(k0g, dim3(513), dim3(64), 0, stream, pwT, proj_b, embT,
                     enT, Gpack, gbias);
  if (big) {
    hipLaunchKernelGGL(k_convF, dim3(512), dim3(256), 0, stream, features, Fh);
    hipLaunchKernelGGL(k_convW, dim3(1024), dim3(256), 0, stream, fst_w, WhT);
  }
  hipLaunchKernelGGL(k1_score, dim3(1024), dim3(256), 0, stream, features,
                     Gpack, gbias, coef, cnt, tk_idx, tk_w, tlist, wlist);
  hipLaunchKernelGGL(k2_bias, dim3(2048), dim3(256), 0, stream, tk_idx, tk_w,
                     fst_b, out);
  if (big) {
    hipLaunchKernelGGL(k_sched, dim3(1), dim3(64), 0, stream, cnt, jobs,
                       njobs);
    hipLaunchKernelGGL(k3_mfma, dim3(2048), dim3(256), 0, stream, Fh, WhT, cnt,
                       tlist, wlist, jobs, njobs, out);
  } else {
    hipLaunchKernelGGL(k3_fst, dim3(4096), dim3(256), 0, stream, features,
                       fst_w, cnt, tlist, wlist, out);
  }
}

// Round 9
// 136.189 us; speedup vs baseline: 2.0463x; 1.0793x over previous
//
#include <hip/hip_runtime.h>
#include <hip/hip_fp16.h>
#include <math.h>

#define B_N 2048
#define F_N 512
#define H_N 256
#define E_N 64

typedef __attribute__((ext_vector_type(8))) _Float16 half8;
typedef __attribute__((ext_vector_type(4))) float f32x4;

// ---------------- K0: prep (transposes, expert norms, coef, zero counts) ----
__global__ __launch_bounds__(256) void k0_prep(
    const float* __restrict__ proj_w, const float* __restrict__ expert_emb,
    const float* __restrict__ expert_features, const float* __restrict__ trust,
    const float* __restrict__ dt, float* __restrict__ pwT,
    float* __restrict__ embT, float* __restrict__ enT,
    float* __restrict__ coef, int* __restrict__ cnt) {
  int bid = blockIdx.x, tid = threadIdx.x;
  if (bid < 512) {
    int idx = bid * 256 + tid;
    int f = idx >> 8, h = idx & 255;
    pwT[idx] = proj_w[h * 512 + f];
    if (bid == 0 && tid < E_N) cnt[tid] = 0;
  } else {
    int e = bid - 512;  // 0..63
    float v0 = expert_features[e * 512 + tid];
    float v1 = expert_features[e * 512 + tid + 256];
    float ss = v0 * v0 + v1 * v1;
    #pragma unroll
    for (int off = 32; off; off >>= 1) ss += __shfl_xor(ss, off);
    __shared__ float parts[4];
    if ((tid & 63) == 0) parts[tid >> 6] = ss;
    __syncthreads();
    float tot = parts[0] + parts[1] + parts[2] + parts[3];
    float inv = 1.0f / fmaxf(sqrtf(tot), 1e-8f);
    enT[tid * 64 + e] = v0 * inv;
    enT[(tid + 256) * 64 + e] = v1 * inv;
    embT[tid * 64 + e] = expert_emb[e * 256 + tid];
    if (tid == 0) {
      float st = fmaxf(0.1f, expf(-0.005f * dt[e]));
      coef[e] = trust[e] * st;
    }
  }
}

// ---------------- K0g: Gpack[f][e] = (pwT[f]·embT[:,e], enT[f][e]); gbias ---
__global__ __launch_bounds__(64) void k0g(
    const float* __restrict__ pwT, const float* __restrict__ proj_b,
    const float* __restrict__ embT, const float* __restrict__ enT,
    float* __restrict__ Gpack, float* __restrict__ gbias) {
  __shared__ float row[256];
  int f = blockIdx.x;
  int e = threadIdx.x;  // 0..63
  const float* src = (f < 512) ? (pwT + f * 256) : proj_b;
  *(float4*)&row[e * 4] = *(const float4*)&src[e * 4];
  __syncthreads();
  float g = 0.0f;
  #pragma unroll 8
  for (int h = 0; h < 256; ++h) g = fmaf(row[h], embT[h * 64 + e], g);
  if (f < 512) {
    Gpack[(f * 64 + e) * 2 + 0] = g;
    Gpack[(f * 64 + e) * 2 + 1] = enT[f * 64 + e];
  } else {
    gbias[e] = g;
  }
}

// ---------------- K0s: Gpack -> GhT/GlT fp16 2-term, [128 col][512 k] -------
// col e   = gate matrix G[f][e];  col 64+e = enT[f][e].  lo scaled by 2^11.
__global__ __launch_bounds__(64) void k0s(const float* __restrict__ Gpack,
                                          _Float16* __restrict__ GhT,
                                          _Float16* __restrict__ GlT) {
  int f = blockIdx.x;   // 0..511
  int e = threadIdx.x;  // 0..63
  float2 gp = *(const float2*)&Gpack[(f * 64 + e) * 2];
  _Float16 h0 = (_Float16)gp.x;
  GhT[e * 512 + f] = h0;
  GlT[e * 512 + f] = (_Float16)((gp.x - (float)h0) * 2048.0f);
  _Float16 h1 = (_Float16)gp.y;
  GhT[(64 + e) * 512 + f] = h1;
  GlT[(64 + e) * 512 + f] = (_Float16)((gp.y - (float)h1) * 2048.0f);
}

// ---------------- conv: features -> fp16 hi (+ scaled lo + row norms) -------
__global__ __launch_bounds__(256) void k_convF(const float* __restrict__ f,
                                               _Float16* __restrict__ Fh,
                                               _Float16* __restrict__ Fl,
                                               float* __restrict__ fnorm,
                                               int extra) {
  int gid = blockIdx.x * 256 + threadIdx.x;
  int i = gid * 8;
  float4 v0 = *(const float4*)(f + i);
  float4 v1 = *(const float4*)(f + i + 4);
  float xs[8] = {v0.x, v0.y, v0.z, v0.w, v1.x, v1.y, v1.z, v1.w};
  half8 h;
  #pragma unroll
  for (int j = 0; j < 8; ++j) h[j] = (_Float16)xs[j];
  *(half8*)(Fh + i) = h;
  if (extra) {
    half8 l;
    float ss = 0.0f;
    #pragma unroll
    for (int j = 0; j < 8; ++j) {
      l[j] = (_Float16)((xs[j] - (float)h[j]) * 2048.0f);
      ss = fmaf(xs[j], xs[j], ss);
    }
    *(half8*)(Fl + i) = l;
    // wave = one feature row (64 lanes x 8 = 512)
    #pragma unroll
    for (int off = 32; off; off >>= 1) ss += __shfl_xor(ss, off);
    if ((threadIdx.x & 63) == 0) fnorm[gid >> 6] = ss;
  }
}

// ---------------- conv: fst_w -> transposed fp16 [e][col][k] ----------------
__global__ __launch_bounds__(256) void k_convW(const float* __restrict__ fst_w,
                                               _Float16* __restrict__ WhT) {
  __shared__ float tile[16704];    // 64*260 + stagger slack
  int bid = blockIdx.x;            // 1024 = 64e x 8kb x 2cb
  int e = bid >> 4;
  int kb = (bid >> 1) & 7;
  int cb = bid & 1;
  int tid = threadIdx.x;

  const float* src = fst_w + ((size_t)e << 18) + (size_t)(kb * 64) * 512 +
                     cb * 256;
  int kr = tid >> 6;        // wave id
  int c4 = (tid & 63) * 4;
  #pragma unroll
  for (int r = 0; r < 16; ++r) {
    int k = r * 4 + kr;
    *(float4*)&tile[k * 260 + ((k >> 3) << 2) + c4] =
        *(const float4*)&src[(size_t)k * 512 + c4];
  }
  __syncthreads();

  int co = tid >> 3;        // 0..31
  int ko = (tid & 7) * 8;   // 0,8,..,56
  #pragma unroll
  for (int g = 0; g < 8; ++g) {
    int c = g * 32 + co;
    half8 vh;
    #pragma unroll
    for (int i = 0; i < 8; ++i) {
      int k = ko + i;
      vh[i] = (_Float16)tile[k * 260 + ((k >> 3) << 2) + c];
    }
    size_t dbase =
        ((size_t)e << 18) + (size_t)(cb * 256 + c) * 512 + kb * 64 + ko;
    *(half8*)(WhT + dbase) = vh;
  }
}

// ---------------- K_sched: compact job list (e, tile) via wave prefix sum ---
__global__ __launch_bounds__(64) void k_sched(const int* __restrict__ cnt,
                                              int* __restrict__ jobs,
                                              int* __restrict__ njobs) {
  int e = threadIdx.x;  // 0..63, one wave
  int nt = (cnt[e] + 63) >> 6;
  int inc = nt;
  #pragma unroll
  for (int d = 1; d < 64; d <<= 1) {
    int v = __shfl_up(inc, d);
    if (e >= d) inc += v;
  }
  int base = inc - nt;  // exclusive prefix
  for (int t = 0; t < nt; ++t) jobs[base + t] = (e << 8) | t;
  if (e == 63) njobs[0] = inc;
}

// ---------------- K1a: scoring GEMM via MFMA, fp16 2-term, K-split 4 --------
// [2048 tok x 512] x [512 x 128 cols] -> scores4[kc][2048][128] partials.
// Block: 32 tok x 128 col x K=128 (2 steps of 64). 4 waves, wave M32xN32.
// Same staging/swizzle/dbuf skeleton as k3_mfma (validated r6-r8).
__global__ __launch_bounds__(256, 2) void k1a_mfma(
    const _Float16* __restrict__ Fh, const _Float16* __restrict__ Fl,
    const _Float16* __restrict__ GhT, const _Float16* __restrict__ GlT,
    float* __restrict__ scores4) {
  __shared__ _Float16 Bh[2][128 * 64];  // 32 KB
  __shared__ _Float16 Bl[2][128 * 64];  // 32 KB
  __shared__ _Float16 Ah[2][32 * 64];   // 8 KB
  __shared__ _Float16 Al[2][32 * 64];   // 8 KB

  int tid = threadIdx.x;
  int kc = blockIdx.x & 3;
  int tt = blockIdx.x >> 2;   // 0..63
  int b0 = tt * 32;
  int k0 = kc * 128;
  int wave = tid >> 6, lane = tid & 63;

  size_t bsrc[4];
  int bdst[4];
  #pragma unroll
  for (int i = 0; i < 4; ++i) {
    int cw = wave * 32 + i * 8;
    int cl = cw + (lane >> 3);
    int g = (lane & 7) ^ (cl & 7);
    bsrc[i] = (size_t)cl * 512 + k0 + g * 8;
    bdst[i] = cw * 64;
  }
  int tw = wave * 8;
  int tkl = tw + (lane >> 3);
  int ga = (lane & 7) ^ (tkl & 7);
  size_t asrc = (size_t)(b0 + tkl) * 512 + k0 + ga * 8;
  int adst = tw * 64;

  f32x4 accH[2][2], accM[2][2];
  #pragma unroll
  for (int mt = 0; mt < 2; ++mt)
    #pragma unroll
    for (int ct = 0; ct < 2; ++ct) {
      accH[mt][ct] = (f32x4){0.f, 0.f, 0.f, 0.f};
      accM[mt][ct] = (f32x4){0.f, 0.f, 0.f, 0.f};
    }

  int kg = lane >> 4;
  int mrow = lane & 15;

  #define STAGE1(K0S, BUF)                                                    \
    do {                                                                      \
      _Pragma("unroll")                                                       \
      for (int i = 0; i < 4; ++i) {                                           \
        __builtin_amdgcn_global_load_lds(                                     \
            (const __attribute__((address_space(1))) void*)(GhT + bsrc[i] + (K0S)), \
            (__attribute__((address_space(3))) void*)(&Bh[BUF][0] + bdst[i]), 16, 0, 0);\
        __builtin_amdgcn_global_load_lds(                                     \
            (const __attribute__((address_space(1))) void*)(GlT + bsrc[i] + (K0S)), \
            (__attribute__((address_space(3))) void*)(&Bl[BUF][0] + bdst[i]), 16, 0, 0);\
      }                                                                       \
      __builtin_amdgcn_global_load_lds(                                       \
          (const __attribute__((address_space(1))) void*)(Fh + asrc + (K0S)),  \
          (__attribute__((address_space(3))) void*)(&Ah[BUF][0] + adst), 16, 0, 0);\
      __builtin_amdgcn_global_load_lds(                                       \
          (const __attribute__((address_space(1))) void*)(Fl + asrc + (K0S)),  \
          (__attribute__((address_space(3))) void*)(&Al[BUF][0] + adst), 16, 0, 0);\
    } while (0)

  STAGE1(0, 0);
  __syncthreads();

  int buf = 0;
  #pragma unroll
  for (int s = 0; s < 2; ++s) {
    if (s < 1) STAGE1(64, 1);
    #pragma unroll
    for (int kh = 0; kh < 2; ++kh) {
      int gq = kh * 4 + kg;
      half8 afh[2], afl[2], bfh[2], bfl[2];
      #pragma unroll
      for (int mt = 0; mt < 2; ++mt) {
        int tr = mt * 16 + mrow;
        int off = tr * 64 + ((gq ^ (tr & 7)) * 8);
        afh[mt] = *(const half8*)(&Ah[buf][0] + off);
        afl[mt] = *(const half8*)(&Al[buf][0] + off);
      }
      #pragma unroll
      for (int ct = 0; ct < 2; ++ct) {
        int cl = wave * 32 + ct * 16 + mrow;
        int off = cl * 64 + ((gq ^ (cl & 7)) * 8);
        bfh[ct] = *(const half8*)(&Bh[buf][0] + off);
        bfl[ct] = *(const half8*)(&Bl[buf][0] + off);
      }
      #pragma unroll
      for (int mt = 0; mt < 2; ++mt)
        #pragma unroll
        for (int ct = 0; ct < 2; ++ct) {
          accH[mt][ct] = __builtin_amdgcn_mfma_f32_16x16x32_f16(
              afh[mt], bfh[ct], accH[mt][ct], 0, 0, 0);
          accM[mt][ct] = __builtin_amdgcn_mfma_f32_16x16x32_f16(
              afh[mt], bfl[ct], accM[mt][ct], 0, 0, 0);
          accM[mt][ct] = __builtin_amdgcn_mfma_f32_16x16x32_f16(
              afl[mt], bfh[ct], accM[mt][ct], 0, 0, 0);
        }
    }
    __syncthreads();
    buf ^= 1;
  }
  #undef STAGE1

  // epilogue: C/D layout col=lane&15, row=(lane>>4)*4+r; plain stores
  int rbase = (lane >> 4) * 4;
  #pragma unroll
  for (int mt = 0; mt < 2; ++mt)
    #pragma unroll
    for (int ct = 0; ct < 2; ++ct)
      #pragma unroll
      for (int r = 0; r < 4; ++r) {
        int tok = b0 + mt * 16 + rbase + r;
        int col = wave * 32 + ct * 16 + mrow;
        scores4[((size_t)(kc * 2048 + tok) << 7) + col] =
            accH[mt][ct][r] + accM[mt][ct][r] * (1.0f / 2048.0f);
      }
}

// ---------------- K1b: finalize scores, top-8, softmax, scatter -------------
__global__ __launch_bounds__(64) void k1b_top8(
    const float* __restrict__ scores4, const float* __restrict__ fnorm,
    const float* __restrict__ coef, const float* __restrict__ gbias,
    int* __restrict__ cnt, int* __restrict__ tk_idx, float* __restrict__ tk_w,
    int* __restrict__ tlist, float* __restrict__ wlist) {
  int b = blockIdx.x;
  int e = threadIdx.x;  // 0..63
  float l = 0.f, s = 0.f;
  #pragma unroll
  for (int kc = 0; kc < 4; ++kc) {
    const float* row = scores4 + ((size_t)(kc * 2048 + b) << 7);
    l += row[e];
    s += row[64 + e];
  }
  float inv_n = 1.0f / fmaxf(sqrtf(fnorm[b]), 1e-8f);
  float gate = 1.0f / (1.0f + expf(-(l + gbias[e]) * 0.0625f));
  float sim = fmaxf(s * inv_n, 0.0f);
  float score = gate * sim * coef[e];

  // top-8: butterfly max with (value desc, index asc) tie-break
  float cur = score;
  float bv[8];
  int bi[8];
  #pragma unroll
  for (int r = 0; r < 8; ++r) {
    float mv = cur;
    int mi = e;
    #pragma unroll
    for (int off = 1; off < 64; off <<= 1) {
      float ov = __shfl_xor(mv, off);
      int oi = __shfl_xor(mi, off);
      if (ov > mv || (ov == mv && oi < mi)) { mv = ov; mi = oi; }
    }
    bv[r] = mv;
    bi[r] = mi;
    if (e == mi) cur = -1.0f;  // scores >= 0
  }
  float m0 = bv[0];
  float ex[8];
  float sum = 0.0f;
  #pragma unroll
  for (int r = 0; r < 8; ++r) { ex[r] = expf(bv[r] - m0); sum += ex[r]; }
  float isum = 1.0f / sum;

  if (e < 8) {
    int ir = 0; float er = 0.0f;
    switch (e) {
      case 0: ir = bi[0]; er = ex[0]; break;
      case 1: ir = bi[1]; er = ex[1]; break;
      case 2: ir = bi[2]; er = ex[2]; break;
      case 3: ir = bi[3]; er = ex[3]; break;
      case 4: ir = bi[4]; er = ex[4]; break;
      case 5: ir = bi[5]; er = ex[5]; break;
      case 6: ir = bi[6]; er = ex[6]; break;
      case 7: ir = bi[7]; er = ex[7]; break;
    }
    float wr = er * isum;
    int pos = atomicAdd(&cnt[ir], 1);
    tlist[ir * B_N + pos] = b;
    wlist[ir * B_N + pos] = wr;
    tk_idx[b * 8 + e] = ir;
    tk_w[b * 8 + e] = wr;
  }
}

// ---------------- K1 fallback (r8 version, Gpack streaming) -----------------
__global__ __launch_bounds__(256) void k1_score(
    const float* __restrict__ features, const float* __restrict__ Gpack,
    const float* __restrict__ gbias, const float* __restrict__ coef,
    int* __restrict__ cnt, int* __restrict__ tk_idx, float* __restrict__ tk_w,
    int* __restrict__ tlist, float* __restrict__ wlist) {
  __shared__ float Ft[2][512];
  __shared__ float pl[4][64];
  __shared__ float ps[4][64];
  __shared__ float pn[4];
  int tid = threadIdx.x;
  int b0 = blockIdx.x * 2;
  {
    int t = tid >> 7;
    int fo = (tid & 127) * 4;
    *(float4*)&Ft[t][fo] =
        *(const float4*)&features[(size_t)(b0 + t) * 512 + fo];
  }
  __syncthreads();
  int wave = tid >> 6, e = tid & 63;
  int tok = wave & 1;
  int f0 = (wave >> 1) * 256;
  float la = 0.f, lb = 0.f, sa = 0.f, sb = 0.f;
  #pragma unroll 4
  for (int f = f0; f < f0 + 256; f += 2) {
    float2 g0 = *(const float2*)&Gpack[(f * 64 + e) * 2];
    float2 g1 = *(const float2*)&Gpack[((f + 1) * 64 + e) * 2];
    float x0 = Ft[tok][f];
    float x1 = Ft[tok][f + 1];
    la = fmaf(x0, g0.x, la);
    sa = fmaf(x0, g0.y, sa);
    lb = fmaf(x1, g1.x, lb);
    sb = fmaf(x1, g1.y, sb);
  }
  float nn = 0.f;
  #pragma unroll
  for (int j = 0; j < 4; ++j) {
    float v = Ft[tok][f0 + e + 64 * j];
    nn = fmaf(v, v, nn);
  }
  #pragma unroll
  for (int off = 32; off; off >>= 1) nn += __shfl_xor(nn, off);
  pl[wave][e] = la + lb;
  ps[wave][e] = sa + sb;
  if (e == 0) pn[wave] = nn;
  __syncthreads();
  if (wave < 2) {
    int b = b0 + wave;
    float l = pl[wave][e] + pl[wave + 2][e];
    float s = ps[wave][e] + ps[wave + 2][e];
    float ntot = pn[wave] + pn[wave + 2];
    float cf = coef[e];
    float gb = gbias[e];
    float inv_n = 1.0f / fmaxf(sqrtf(ntot), 1e-8f);
    float gate = 1.0f / (1.0f + expf(-(l + gb) * 0.0625f));
    float sim = fmaxf(s * inv_n, 0.0f);
    float score = gate * sim * cf;
    float cur = score;
    float bv[8];
    int bi[8];
    #pragma unroll
    for (int r = 0; r < 8; ++r) {
      float mv = cur;
      int mi = e;
      #pragma unroll
      for (int off = 1; off < 64; off <<= 1) {
        float ov = __shfl_xor(mv, off);
        int oi = __shfl_xor(mi, off);
        if (ov > mv || (ov == mv && oi < mi)) { mv = ov; mi = oi; }
      }
      bv[r] = mv;
      bi[r] = mi;
      if (e == mi) cur = -1.0f;
    }
    float m0 = bv[0];
    float ex[8];
    float sum = 0.0f;
    #pragma unroll
    for (int r = 0; r < 8; ++r) { ex[r] = expf(bv[r] - m0); sum += ex[r]; }
    float isum = 1.0f / sum;
    if (e < 8) {
      int ir = 0; float er = 0.0f;
      switch (e) {
        case 0: ir = bi[0]; er = ex[0]; break;
        case 1: ir = bi[1]; er = ex[1]; break;
        case 2: ir = bi[2]; er = ex[2]; break;
        case 3: ir = bi[3]; er = ex[3]; break;
        case 4: ir = bi[4]; er = ex[4]; break;
        case 5: ir = bi[5]; er = ex[5]; break;
        case 6: ir = bi[6]; er = ex[6]; break;
        case 7: ir = bi[7]; er = ex[7]; break;
      }
      float wr = er * isum;
      int pos = atomicAdd(&cnt[ir], 1);
      tlist[ir * B_N + pos] = b;
      wlist[ir * B_N + pos] = wr;
      tk_idx[b * 8 + e] = ir;
      tk_w[b * 8 + e] = wr;
    }
  }
}

// ---------------- K2: out[b,:] = sum_k w_k * fst_b[e_k,:]  ------------------
__global__ __launch_bounds__(256) void k2_bias(
    const int* __restrict__ tk_idx, const float* __restrict__ tk_w,
    const float* __restrict__ fst_b, float* __restrict__ out) {
  int b = blockIdx.x, tid = threadIdx.x;
  int ir[8];
  float wr[8];
  #pragma unroll
  for (int r = 0; r < 8; ++r) {
    ir[r] = tk_idx[b * 8 + r];
    wr[r] = tk_w[b * 8 + r];
  }
  #pragma unroll
  for (int q = 0; q < 2; ++q) {
    int f = tid + q * 256;
    float a = 0.0f;
    #pragma unroll
    for (int r = 0; r < 8; ++r) a = fmaf(wr[r], fst_b[ir[r] * 512 + f], a);
    out[(size_t)b * 512 + f] = a;
  }
}

// ---------------- K3 (MFMA): gathered per-expert FST, fp16, job-compacted ---
__global__ __launch_bounds__(256, 3) void k3_mfma(
    const _Float16* __restrict__ Fh, const _Float16* __restrict__ WhT,
    const int* __restrict__ cnt, const int* __restrict__ tlist,
    const float* __restrict__ wlist, const int* __restrict__ jobs,
    const int* __restrict__ njobs, float* __restrict__ out) {
  __shared__ _Float16 Bh[2][128 * 64];  // 32 KB
  __shared__ _Float16 Ah[2][64 * 64];   // 16 KB
  __shared__ int tl[64];
  __shared__ float wl[64];

  int tid = threadIdx.x;
  int job = blockIdx.x >> 2;
  int chunk = blockIdx.x & 3;
  if (job >= njobs[0]) return;
  int jb = jobs[job];
  int e = jb >> 8;
  int tile = jb & 255;
  int c0 = chunk * 128;
  int c_e = cnt[e];
  int t0 = tile * 64;

  if (tid < 64) {
    int t = t0 + tid;
    tl[tid] = tlist[e * B_N + (t < c_e ? t : t0)];
    wl[tid] = (t < c_e) ? wlist[e * B_N + t] : 0.0f;
  }
  __syncthreads();

  int wave = tid >> 6, lane = tid & 63;
  const _Float16* WhT_e = WhT + ((size_t)e << 18);

  size_t bsrc[4];
  int bdst[4];
  #pragma unroll
  for (int i = 0; i < 4; ++i) {
    int cw = wave * 32 + i * 8;
    int cl = cw + (lane >> 3);
    int g = (lane & 7) ^ (cl & 7);
    bsrc[i] = (size_t)(c0 + cl) * 512 + g * 8;
    bdst[i] = cw * 64;
  }
  size_t asrc[2];
  int adst[2];
  #pragma unroll
  for (int j = 0; j < 2; ++j) {
    int tw = wave * 16 + j * 8;
    int tkl = tw + (lane >> 3);
    int g = (lane & 7) ^ (tkl & 7);
    asrc[j] = (size_t)tl[tkl] * 512 + g * 8;
    adst[j] = tw * 64;
  }

  f32x4 acc[4][2];
  #pragma unroll
  for (int mt = 0; mt < 4; ++mt)
    #pragma unroll
    for (int ct = 0; ct < 2; ++ct) acc[mt][ct] = (f32x4){0.f, 0.f, 0.f, 0.f};

  int kg = lane >> 4;
  int mrow = lane & 15;

  #define STAGE(K0S, BUF)                                                     \
    do {                                                                      \
      _Pragma("unroll")                                                       \
      for (int i = 0; i < 4; ++i) {                                           \
        __builtin_amdgcn_global_load_lds(                                     \
            (const __attribute__((address_space(1))) void*)(WhT_e + bsrc[i] + (K0S)), \
            (__attribute__((address_space(3))) void*)(&Bh[BUF][0] + bdst[i]), 16, 0, 0);\
      }                                                                       \
      _Pragma("unroll")                                                       \
      for (int j = 0; j < 2; ++j) {                                           \
        __builtin_amdgcn_global_load_lds(                                     \
            (const __attribute__((address_space(1))) void*)(Fh + asrc[j] + (K0S)), \
            (__attribute__((address_space(3))) void*)(&Ah[BUF][0] + adst[j]), 16, 0, 0);\
      }                                                                       \
    } while (0)

  STAGE(0, 0);
  __syncthreads();  // prologue drain

  int buf = 0;
  for (int s = 0; s < 8; ++s) {
    if (s < 7) STAGE((s + 1) * 64, buf ^ 1);  // issue next-step loads FIRST
    #pragma unroll
    for (int kh = 0; kh < 2; ++kh) {
      int gq = kh * 4 + kg;
      half8 af[4], bf[2];
      #pragma unroll
      for (int mt = 0; mt < 4; ++mt) {
        int tr = mt * 16 + mrow;
        af[mt] = *(const half8*)(&Ah[buf][0] + tr * 64 + ((gq ^ (tr & 7)) * 8));
      }
      #pragma unroll
      for (int ct = 0; ct < 2; ++ct) {
        int cl = wave * 32 + ct * 16 + mrow;
        bf[ct] = *(const half8*)(&Bh[buf][0] + cl * 64 + ((gq ^ (cl & 7)) * 8));
      }
      #pragma unroll
      for (int mt = 0; mt < 4; ++mt)
        #pragma unroll
        for (int ct = 0; ct < 2; ++ct)
          acc[mt][ct] = __builtin_amdgcn_mfma_f32_16x16x32_f16(
              af[mt], bf[ct], acc[mt][ct], 0, 0, 0);
    }
    __syncthreads();  // drains vmcnt: next buf staged, cur buf free
    buf ^= 1;
  }
  #undef STAGE

  int rbase = (lane >> 4) * 4;
  #pragma unroll
  for (int mt = 0; mt < 4; ++mt) {
    #pragma unroll
    for (int r = 0; r < 4; ++r) {
      int tloc = mt * 16 + rbase + r;
      float w = wl[tloc];
      if (w != 0.0f) {
        size_t orow = (size_t)tl[tloc] * 512 + c0 + wave * 32 + mrow;
        atomicAdd(out + orow, w * acc[mt][0][r]);
        atomicAdd(out + orow + 16, w * acc[mt][1][r]);
      }
    }
  }
}

// ---------------- K3 fallback (fp32 VALU) -----------------------------------
#define TM 64
#define TN 256
#define KC 16
__global__ __launch_bounds__(256, 2) void k3_fst(
    const float* __restrict__ features, const float* __restrict__ fst_w,
    const int* __restrict__ cnt, const int* __restrict__ tlist,
    const float* __restrict__ wlist, float* __restrict__ out) {
  __shared__ float Ws[2][KC][TN];
  __shared__ float Ft[2][KC][TM];
  __shared__ int tl[TM];
  __shared__ float wl[TM];

  int tid = threadIdx.x;
  int e = blockIdx.x & 63;
  int rest = blockIdx.x >> 6;
  int tile = rest >> 1;
  int ch = rest & 1;
  int c0 = ch * TN;
  int c_e = cnt[e];
  int t0 = tile * TM;
  if (t0 >= c_e) return;

  if (tid < TM) {
    int t = t0 + tid;
    if (t < c_e) {
      tl[tid] = tlist[e * B_N + t];
      wl[tid] = wlist[e * B_N + t];
    } else {
      tl[tid] = tlist[e * B_N + t0];
      wl[tid] = 0.0f;
    }
  }
  __syncthreads();

  const float* fw_e = fst_w + (size_t)e * (512 * 512);
  int wave = tid >> 6, lane = tid & 63;
  int tg = wave * 2 + (lane >> 5);
  int cg = lane & 31;
  int ft_t = tid >> 2;
  int ft_fq = tid & 3;
  const float* ft_src_row = features + (size_t)tl[ft_t] * 512;

  auto stageWs = [&](int kc, int buf) {
    int f0 = kc * KC;
    #pragma unroll
    for (int r = 0; r < 4; ++r) {
      int f = wave * 4 + r;
      const float* src = fw_e + (size_t)(f0 + f) * 512 + c0 + lane * 4;
      __builtin_amdgcn_global_load_lds(
          (const __attribute__((address_space(1))) void*)src,
          (__attribute__((address_space(3))) void*)&Ws[buf][f][0], 16, 0, 0);
    }
  };
  auto loadFt = [&](int kc) -> float4 {
    return *(const float4*)&ft_src_row[kc * KC + ft_fq * 4];
  };
  auto writeFt = [&](float4 v, int buf) {
    Ft[buf][ft_fq * 4 + 0][ft_t] = v.x;
    Ft[buf][ft_fq * 4 + 1][ft_t] = v.y;
    Ft[buf][ft_fq * 4 + 2][ft_t] = v.z;
    Ft[buf][ft_fq * 4 + 3][ft_t] = v.w;
  };

  float acc[8][8];
  #pragma unroll
  for (int j = 0; j < 8; ++j)
    #pragma unroll
    for (int i = 0; i < 8; ++i) acc[j][i] = 0.0f;

  auto compute = [&](int buf) {
    #pragma unroll 4
    for (int f = 0; f < KC; ++f) {
      float4 a0 = *(const float4*)&Ft[buf][f][tg * 8];
      float4 a1 = *(const float4*)&Ft[buf][f][tg * 8 + 4];
      float4 w0 = *(const float4*)&Ws[buf][f][cg * 4];
      float4 w1 = *(const float4*)&Ws[buf][f][cg * 4 + 128];
      float av[8] = {a0.x, a0.y, a0.z, a0.w, a1.x, a1.y, a1.z, a1.w};
      float wv[8] = {w0.x, w0.y, w0.z, w0.w, w1.x, w1.y, w1.z, w1.w};
      #pragma unroll
      for (int j = 0; j < 8; ++j)
        #pragma unroll
        for (int i = 0; i < 8; ++i)
          acc[j][i] = fmaf(av[j], wv[i], acc[j][i]);
    }
  };

  stageWs(0, 0);
  float4 rf = loadFt(0);
  writeFt(rf, 0);
  __syncthreads();

  for (int kc = 0; kc < 32; ++kc) {
    int cb = kc & 1, nb = cb ^ 1;
    float4 rn = make_float4(0.f, 0.f, 0.f, 0.f);
    if (kc < 31) {
      stageWs(kc + 1, nb);
      rn = loadFt(kc + 1);
    }
    compute(cb);
    if (kc < 31) writeFt(rn, nb);
    __syncthreads();
  }

  #pragma unroll
  for (int j = 0; j < 8; ++j) {
    int lt = tg * 8 + j;
    float w = wl[lt];
    if (w != 0.0f) {
      size_t orow = (size_t)tl[lt] * 512 + c0 + cg * 4;
      #pragma unroll
      for (int i = 0; i < 4; ++i) atomicAdd(&out[orow + i], w * acc[j][i]);
      #pragma unroll
      for (int i = 0; i < 4; ++i)
        atomicAdd(&out[orow + 128 + i], w * acc[j][i + 4]);
    }
  }
}

// ---------------- launch ----------------------------------------------------
extern "C" void kernel_launch(void* const* d_in, const int* in_sizes, int n_in,
                              void* d_out, int out_size, void* d_ws,
                              size_t ws_size, hipStream_t stream) {
  const float* features = (const float*)d_in[0];
  const float* proj_w = (const float*)d_in[1];
  const float* proj_b = (const float*)d_in[2];
  const float* expert_emb = (const float*)d_in[3];
  const float* expert_features = (const float*)d_in[4];
  const float* trust = (const float*)d_in[5];
  const float* dt = (const float*)d_in[6];
  const float* fst_w = (const float*)d_in[7];
  const float* fst_b = (const float*)d_in[8];
  float* out = (float*)d_out;

  float* ws = (float*)d_ws;
  float* pwT = ws;                           // 512*256
  float* embT = pwT + 131072;                // 256*64
  float* enT = embT + 16384;                 // 512*64
  float* coef = enT + 32768;                 // 64
  int* cnt = (int*)(coef + 64);              // 64
  int* tk_idx = cnt + 64;                    // 2048*8
  float* tk_w = (float*)(tk_idx + 16384);    // 2048*8
  int* tlist = (int*)(tk_w + 16384);         // 64*2048
  float* wlist = (float*)(tlist + 131072);   // 64*2048
  float* Gpack = wlist + 131072;             // 512*64*2
  float* gbias = Gpack + 65536;              // 64
  int* jobs = (int*)(gbias + 64);            // 2048
  int* njobs = jobs + 2048;                  // 64 (pad)
  _Float16* Fh = (_Float16*)(njobs + 64);    // 2048*512
  _Float16* WhT = Fh + (1 << 20);            // 64*512*512
  _Float16* Fl16 = WhT + (1 << 24);          // 2048*512 (lo * 2^11)
  _Float16* GhT = Fl16 + (1 << 20);          // 128*512
  _Float16* GlT = GhT + 65536;               // 128*512
  float* fnorm = (float*)(GlT + 65536);      // 2048 (sum of squares)
  float* scores4 = fnorm + 2048;             // 4*2048*128
  size_t need = (size_t)((char*)Fl16 - (char*)d_ws);          // big path
  size_t need2 = (size_t)((char*)(scores4 + (1 << 20)) - (char*)d_ws);
  bool big = ws_size >= need;
  bool big2 = ws_size >= need2;

  hipLaunchKernelGGL(k0_prep, dim3(576), dim3(256), 0, stream, proj_w,
                     expert_emb, expert_features, trust, dt, pwT, embT, enT,
                     coef, cnt);
  hipLaunchKernelGGL(k0g, dim3(513), dim3(64), 0, stream, pwT, proj_b, embT,
                     enT, Gpack, gbias);
  if (big) {
    hipLaunchKernelGGL(k_convF, dim3(512), dim3(256), 0, stream, features, Fh,
                       Fl16, fnorm, big2 ? 1 : 0);
    hipLaunchKernelGGL(k_convW, dim3(1024), dim3(256), 0, stream, fst_w, WhT);
  }
  if (big2) {
    hipLaunchKernelGGL(k0s, dim3(512), dim3(64), 0, stream, Gpack, GhT, GlT);
    hipLaunchKernelGGL(k1a_mfma, dim3(256), dim3(256), 0, stream, Fh, Fl16,
                       GhT, GlT, scores4);
    hipLaunchKernelGGL(k1b_top8, dim3(2048), dim3(64), 0, stream, scores4,
                       fnorm, coef, gbias, cnt, tk_idx, tk_w, tlist, wlist);
  } else {
    hipLaunchKernelGGL(k1_score, dim3(1024), dim3(256), 0, stream, features,
                       Gpack, gbias, coef, cnt, tk_idx, tk_w, tlist, wlist);
  }
  hipLaunchKernelGGL(k2_bias, dim3(2048), dim3(256), 0, stream, tk_idx, tk_w,
                     fst_b, out);
  if (big) {
    hipLaunchKernelGGL(k_sched, dim3(1), dim3(64), 0, stream, cnt, jobs,
                       njobs);
    hipLaunchKernelGGL(k3_mfma, dim3(2048), dim3(256), 0, stream, Fh, WhT, cnt,
                       tlist, wlist, jobs, njobs, out);
  } else {
    hipLaunchKernelGGL(k3_fst, dim3(4096), dim3(256), 0, stream, features,
                       fst_w, cnt, tlist, wlist, out);
  }
}

// Round 10
// 124.699 us; speedup vs baseline: 2.2348x; 1.0921x over previous
//
#include <hip/hip_runtime.h>
#include <hip/hip_fp16.h>
#include <math.h>

#define B_N 2048
#define F_N 512
#define H_N 256
#define E_N 64

typedef __attribute__((ext_vector_type(8))) _Float16 half8;
typedef __attribute__((ext_vector_type(4))) float f32x4;

// ================= NEW PATH (6 kernels) =====================================

// ---- k_prep: fused input transforms. grid 2112 (new) or 576 (fallback).
// [0,512): pwT transpose   [512,576): expert norms/enT/embT/coef + cnt zero
// [576,1088): convF (features -> Fh, Fl, fnorm)   [1088,2112): convW
__global__ __launch_bounds__(256) void k_prep(
    const float* __restrict__ proj_w, const float* __restrict__ expert_emb,
    const float* __restrict__ expert_features, const float* __restrict__ trust,
    const float* __restrict__ dt, const float* __restrict__ features,
    const float* __restrict__ fst_w, float* __restrict__ pwT,
    float* __restrict__ embT, float* __restrict__ enT,
    float* __restrict__ coef, int* __restrict__ cnt, _Float16* __restrict__ Fh,
    _Float16* __restrict__ Fl, float* __restrict__ fnorm,
    _Float16* __restrict__ WhT) {
  __shared__ float tile[16704];  // convW staging (65 KB)
  __shared__ float parts[4];
  int bid = blockIdx.x, tid = threadIdx.x;
  if (bid < 512) {
    int idx = bid * 256 + tid;
    int f = idx >> 8, h = idx & 255;
    pwT[idx] = proj_w[h * 512 + f];
    if (bid == 0 && tid < E_N) cnt[tid] = 0;
  } else if (bid < 576) {
    int e = bid - 512;  // 0..63
    float v0 = expert_features[e * 512 + tid];
    float v1 = expert_features[e * 512 + tid + 256];
    float ss = v0 * v0 + v1 * v1;
    #pragma unroll
    for (int off = 32; off; off >>= 1) ss += __shfl_xor(ss, off);
    if ((tid & 63) == 0) parts[tid >> 6] = ss;
    __syncthreads();
    float tot = parts[0] + parts[1] + parts[2] + parts[3];
    float inv = 1.0f / fmaxf(sqrtf(tot), 1e-8f);
    enT[tid * 64 + e] = v0 * inv;
    enT[(tid + 256) * 64 + e] = v1 * inv;
    embT[tid * 64 + e] = expert_emb[e * 256 + tid];
    if (tid == 0) {
      float st = fmaxf(0.1f, expf(-0.005f * dt[e]));
      coef[e] = trust[e] * st;
    }
  } else if (bid < 1088) {
    // convF: fp16 hi + scaled lo + row norms
    int gid = (bid - 576) * 256 + tid;
    int i = gid * 8;
    float4 v0 = *(const float4*)(features + i);
    float4 v1 = *(const float4*)(features + i + 4);
    float xs[8] = {v0.x, v0.y, v0.z, v0.w, v1.x, v1.y, v1.z, v1.w};
    half8 h, l;
    float ss = 0.0f;
    #pragma unroll
    for (int j = 0; j < 8; ++j) {
      h[j] = (_Float16)xs[j];
      l[j] = (_Float16)((xs[j] - (float)h[j]) * 2048.0f);
      ss = fmaf(xs[j], xs[j], ss);
    }
    *(half8*)(Fh + i) = h;
    *(half8*)(Fl + i) = l;
    #pragma unroll
    for (int off = 32; off; off >>= 1) ss += __shfl_xor(ss, off);
    if ((tid & 63) == 0) fnorm[gid >> 6] = ss;
  } else {
    // convW: fst_w -> transposed fp16 [e][col][k]
    int b2 = bid - 1088;  // 1024 = 64e x 8kb x 2cb
    int e = b2 >> 4;
    int kb = (b2 >> 1) & 7;
    int cb = b2 & 1;
    const float* src = fst_w + ((size_t)e << 18) + (size_t)(kb * 64) * 512 +
                       cb * 256;
    int kr = tid >> 6;
    int c4 = (tid & 63) * 4;
    #pragma unroll
    for (int r = 0; r < 16; ++r) {
      int k = r * 4 + kr;
      *(float4*)&tile[k * 260 + ((k >> 3) << 2) + c4] =
          *(const float4*)&src[(size_t)k * 512 + c4];
    }
    __syncthreads();
    int co = tid >> 3;
    int ko = (tid & 7) * 8;
    #pragma unroll
    for (int g = 0; g < 8; ++g) {
      int c = g * 32 + co;
      half8 vh;
      #pragma unroll
      for (int i = 0; i < 8; ++i) {
        int k = ko + i;
        vh[i] = (_Float16)tile[k * 260 + ((k >> 3) << 2) + c];
      }
      size_t dbase =
          ((size_t)e << 18) + (size_t)(cb * 256 + c) * 512 + kb * 64 + ko;
      *(half8*)(WhT + dbase) = vh;
    }
  }
}

// ---- k0gs: gate matrix + enT -> fp16 2-term GhT/GlT [128 col][512 k]; gbias
__global__ __launch_bounds__(64) void k0gs(
    const float* __restrict__ pwT, const float* __restrict__ proj_b,
    const float* __restrict__ embT, const float* __restrict__ enT,
    _Float16* __restrict__ GhT, _Float16* __restrict__ GlT,
    float* __restrict__ gbias) {
  __shared__ float row[256];
  int f = blockIdx.x;
  int e = threadIdx.x;
  const float* src = (f < 512) ? (pwT + f * 256) : proj_b;
  *(float4*)&row[e * 4] = *(const float4*)&src[e * 4];
  __syncthreads();
  float g = 0.0f;
  #pragma unroll 8
  for (int h = 0; h < 256; ++h) g = fmaf(row[h], embT[h * 64 + e], g);
  if (f < 512) {
    _Float16 h0 = (_Float16)g;
    GhT[e * 512 + f] = h0;
    GlT[e * 512 + f] = (_Float16)((g - (float)h0) * 2048.0f);
    float en = enT[f * 64 + e];
    _Float16 h1 = (_Float16)en;
    GhT[(64 + e) * 512 + f] = h1;
    GlT[(64 + e) * 512 + f] = (_Float16)((en - (float)h1) * 2048.0f);
  } else {
    gbias[e] = g;
  }
}

// ---- k1_mfma: fused scoring GEMM (full K) + in-LDS top-8 + scatter.
// grid 64 x 32 tokens. 4 waves: wave = N-slice 32 cols, M=32 tok. 8 K-steps.
// Scatter packs slot into tlist bits 12+.
__global__ __launch_bounds__(256) void k1_mfma(
    const _Float16* __restrict__ Fh, const _Float16* __restrict__ Fl,
    const _Float16* __restrict__ GhT, const _Float16* __restrict__ GlT,
    const float* __restrict__ fnorm, const float* __restrict__ coef,
    const float* __restrict__ gbias, int* __restrict__ cnt,
    int* __restrict__ tlist, float* __restrict__ wlist) {
  __shared__ _Float16 Bh[2][128 * 64];  // 32 KB (Bh[0] reused as scores f32)
  __shared__ _Float16 Bl[2][128 * 64];  // 32 KB
  __shared__ _Float16 Ah[2][32 * 64];   // 8 KB
  __shared__ _Float16 Al[2][32 * 64];   // 8 KB

  int tid = threadIdx.x;
  int b0 = blockIdx.x * 32;
  int wave = tid >> 6, lane = tid & 63;

  size_t bsrc[4];
  int bdst[4];
  #pragma unroll
  for (int i = 0; i < 4; ++i) {
    int cw = wave * 32 + i * 8;
    int cl = cw + (lane >> 3);
    int g = (lane & 7) ^ (cl & 7);
    bsrc[i] = (size_t)cl * 512 + g * 8;
    bdst[i] = cw * 64;
  }
  int tw = wave * 8;
  int tkl = tw + (lane >> 3);
  int ga = (lane & 7) ^ (tkl & 7);
  size_t asrc = (size_t)(b0 + tkl) * 512 + ga * 8;
  int adst = tw * 64;

  f32x4 accH[2][2], accM[2][2];
  #pragma unroll
  for (int mt = 0; mt < 2; ++mt)
    #pragma unroll
    for (int ct = 0; ct < 2; ++ct) {
      accH[mt][ct] = (f32x4){0.f, 0.f, 0.f, 0.f};
      accM[mt][ct] = (f32x4){0.f, 0.f, 0.f, 0.f};
    }
  int kg = lane >> 4;
  int mrow = lane & 15;

  #define STG(K0S, BUF)                                                       \
    do {                                                                      \
      _Pragma("unroll")                                                       \
      for (int i = 0; i < 4; ++i) {                                           \
        __builtin_amdgcn_global_load_lds(                                     \
            (const __attribute__((address_space(1))) void*)(GhT + bsrc[i] + (K0S)), \
            (__attribute__((address_space(3))) void*)(&Bh[BUF][0] + bdst[i]), 16, 0, 0);\
        __builtin_amdgcn_global_load_lds(                                     \
            (const __attribute__((address_space(1))) void*)(GlT + bsrc[i] + (K0S)), \
            (__attribute__((address_space(3))) void*)(&Bl[BUF][0] + bdst[i]), 16, 0, 0);\
      }                                                                       \
      __builtin_amdgcn_global_load_lds(                                       \
          (const __attribute__((address_space(1))) void*)(Fh + asrc + (K0S)),  \
          (__attribute__((address_space(3))) void*)(&Ah[BUF][0] + adst), 16, 0, 0);\
      __builtin_amdgcn_global_load_lds(                                       \
          (const __attribute__((address_space(1))) void*)(Fl + asrc + (K0S)),  \
          (__attribute__((address_space(3))) void*)(&Al[BUF][0] + adst), 16, 0, 0);\
    } while (0)

  STG(0, 0);
  __syncthreads();
  int buf = 0;
  for (int s = 0; s < 8; ++s) {
    if (s < 7) STG((s + 1) * 64, buf ^ 1);
    #pragma unroll
    for (int kh = 0; kh < 2; ++kh) {
      int gq = kh * 4 + kg;
      half8 afh[2], afl[2], bfh[2], bfl[2];
      #pragma unroll
      for (int mt = 0; mt < 2; ++mt) {
        int tr = mt * 16 + mrow;
        int off = tr * 64 + ((gq ^ (tr & 7)) * 8);
        afh[mt] = *(const half8*)(&Ah[buf][0] + off);
        afl[mt] = *(const half8*)(&Al[buf][0] + off);
      }
      #pragma unroll
      for (int ct = 0; ct < 2; ++ct) {
        int cl = wave * 32 + ct * 16 + mrow;
        int off = cl * 64 + ((gq ^ (cl & 7)) * 8);
        bfh[ct] = *(const half8*)(&Bh[buf][0] + off);
        bfl[ct] = *(const half8*)(&Bl[buf][0] + off);
      }
      #pragma unroll
      for (int mt = 0; mt < 2; ++mt)
        #pragma unroll
        for (int ct = 0; ct < 2; ++ct) {
          accH[mt][ct] = __builtin_amdgcn_mfma_f32_16x16x32_f16(
              afh[mt], bfh[ct], accH[mt][ct], 0, 0, 0);
          accM[mt][ct] = __builtin_amdgcn_mfma_f32_16x16x32_f16(
              afh[mt], bfl[ct], accM[mt][ct], 0, 0, 0);
          accM[mt][ct] = __builtin_amdgcn_mfma_f32_16x16x32_f16(
              afl[mt], bfh[ct], accM[mt][ct], 0, 0, 0);
        }
    }
    __syncthreads();
    buf ^= 1;
  }
  #undef STG

  // scores into LDS (reuse Bh[0]: 16 KB, all reads drained by barrier above)
  float* sc = (float*)&Bh[0][0];  // [32][128]
  int rbase = (lane >> 4) * 4;
  #pragma unroll
  for (int mt = 0; mt < 2; ++mt)
    #pragma unroll
    for (int ct = 0; ct < 2; ++ct)
      #pragma unroll
      for (int r = 0; r < 4; ++r) {
        int tok = mt * 16 + rbase + r;
        int col = wave * 32 + ct * 16 + mrow;
        sc[tok * 128 + col] = accH[mt][ct][r] + accM[mt][ct][r] * (1.0f / 2048.0f);
      }
  __syncthreads();

  // top-8 per token: wave handles tokens wave*8..+7, lane = expert
  float cf = coef[lane];
  float gb = gbias[lane];
  for (int j = 0; j < 8; ++j) {
    int t = wave * 8 + j;
    int b = b0 + t;
    float l = sc[t * 128 + lane];
    float s = sc[t * 128 + 64 + lane];
    float inv_n = 1.0f / fmaxf(sqrtf(fnorm[b]), 1e-8f);
    float gate = 1.0f / (1.0f + expf(-(l + gb) * 0.0625f));
    float sim = fmaxf(s * inv_n, 0.0f);
    float score = gate * sim * cf;

    float cur = score;
    float bv[8];
    int bi[8];
    #pragma unroll
    for (int r = 0; r < 8; ++r) {
      float mv = cur;
      int mi = lane;
      #pragma unroll
      for (int off = 1; off < 64; off <<= 1) {
        float ov = __shfl_xor(mv, off);
        int oi = __shfl_xor(mi, off);
        if (ov > mv || (ov == mv && oi < mi)) { mv = ov; mi = oi; }
      }
      bv[r] = mv;
      bi[r] = mi;
      if (lane == mi) cur = -1.0f;  // scores >= 0
    }
    float m0 = bv[0];
    float ex[8];
    float sum = 0.0f;
    #pragma unroll
    for (int r = 0; r < 8; ++r) { ex[r] = expf(bv[r] - m0); sum += ex[r]; }
    float isum = 1.0f / sum;

    if (lane < 8) {
      int ir = 0; float er = 0.0f;
      switch (lane) {
        case 0: ir = bi[0]; er = ex[0]; break;
        case 1: ir = bi[1]; er = ex[1]; break;
        case 2: ir = bi[2]; er = ex[2]; break;
        case 3: ir = bi[3]; er = ex[3]; break;
        case 4: ir = bi[4]; er = ex[4]; break;
        case 5: ir = bi[5]; er = ex[5]; break;
        case 6: ir = bi[6]; er = ex[6]; break;
        case 7: ir = bi[7]; er = ex[7]; break;
      }
      float wr = er * isum;
      int pos = atomicAdd(&cnt[ir], 1);
      tlist[ir * B_N + pos] = b | (lane << 12);  // pack slot
      wlist[ir * B_N + pos] = wr;
    }
  }
}

// ---- k_sched: compact job list via wave prefix sum (64-token tiles)
__global__ __launch_bounds__(64) void k_sched(const int* __restrict__ cnt,
                                              int* __restrict__ jobs,
                                              int* __restrict__ njobs) {
  int e = threadIdx.x;
  int nt = (cnt[e] + 63) >> 6;
  int inc = nt;
  #pragma unroll
  for (int d = 1; d < 64; d <<= 1) {
    int v = __shfl_up(inc, d);
    if (e >= d) inc += v;
  }
  int base = inc - nt;
  for (int t = 0; t < nt; ++t) jobs[base + t] = (e << 8) | t;
  if (e == 63) njobs[0] = inc;
}

// ---- k3_mfma: gathered FST GEMM; PLAIN STORES (bias fused) to ypart --------
__global__ __launch_bounds__(256, 3) void k3_mfma(
    const _Float16* __restrict__ Fh, const _Float16* __restrict__ WhT,
    const float* __restrict__ fst_b, const int* __restrict__ cnt,
    const int* __restrict__ tlist, const float* __restrict__ wlist,
    const int* __restrict__ jobs, const int* __restrict__ njobs,
    float* __restrict__ ypart) {
  __shared__ _Float16 Bh[2][128 * 64];  // 32 KB
  __shared__ _Float16 Ah[2][64 * 64];   // 16 KB
  __shared__ int tl[64];
  __shared__ float wl[64];

  int tid = threadIdx.x;
  int job = blockIdx.x >> 2;
  int chunk = blockIdx.x & 3;
  if (job >= njobs[0]) return;
  int jb = jobs[job];
  int e = jb >> 8;
  int tile = jb & 255;
  int c0 = chunk * 128;
  int c_e = cnt[e];
  int t0 = tile * 64;

  if (tid < 64) {
    int t = t0 + tid;
    tl[tid] = tlist[e * B_N + (t < c_e ? t : t0)];
    wl[tid] = (t < c_e) ? wlist[e * B_N + t] : 0.0f;
  }
  __syncthreads();

  int wave = tid >> 6, lane = tid & 63;
  const _Float16* WhT_e = WhT + ((size_t)e << 18);

  size_t bsrc[4];
  int bdst[4];
  #pragma unroll
  for (int i = 0; i < 4; ++i) {
    int cw = wave * 32 + i * 8;
    int cl = cw + (lane >> 3);
    int g = (lane & 7) ^ (cl & 7);
    bsrc[i] = (size_t)(c0 + cl) * 512 + g * 8;
    bdst[i] = cw * 64;
  }
  size_t asrc[2];
  int adst[2];
  #pragma unroll
  for (int j = 0; j < 2; ++j) {
    int tw = wave * 16 + j * 8;
    int tkl = tw + (lane >> 3);
    int g = (lane & 7) ^ (tkl & 7);
    asrc[j] = (size_t)(tl[tkl] & 4095) * 512 + g * 8;
    adst[j] = tw * 64;
  }

  f32x4 acc[4][2];
  #pragma unroll
  for (int mt = 0; mt < 4; ++mt)
    #pragma unroll
    for (int ct = 0; ct < 2; ++ct) acc[mt][ct] = (f32x4){0.f, 0.f, 0.f, 0.f};

  int kg = lane >> 4;
  int mrow = lane & 15;

  #define STAGE(K0S, BUF)                                                     \
    do {                                                                      \
      _Pragma("unroll")                                                       \
      for (int i = 0; i < 4; ++i) {                                           \
        __builtin_amdgcn_global_load_lds(                                     \
            (const __attribute__((address_space(1))) void*)(WhT_e + bsrc[i] + (K0S)), \
            (__attribute__((address_space(3))) void*)(&Bh[BUF][0] + bdst[i]), 16, 0, 0);\
      }                                                                       \
      _Pragma("unroll")                                                       \
      for (int j = 0; j < 2; ++j) {                                           \
        __builtin_amdgcn_global_load_lds(                                     \
            (const __attribute__((address_space(1))) void*)(Fh + asrc[j] + (K0S)), \
            (__attribute__((address_space(3))) void*)(&Ah[BUF][0] + adst[j]), 16, 0, 0);\
      }                                                                       \
    } while (0)

  STAGE(0, 0);
  __syncthreads();

  int buf = 0;
  for (int s = 0; s < 8; ++s) {
    if (s < 7) STAGE((s + 1) * 64, buf ^ 1);
    #pragma unroll
    for (int kh = 0; kh < 2; ++kh) {
      int gq = kh * 4 + kg;
      half8 af[4], bf[2];
      #pragma unroll
      for (int mt = 0; mt < 4; ++mt) {
        int tr = mt * 16 + mrow;
        af[mt] = *(const half8*)(&Ah[buf][0] + tr * 64 + ((gq ^ (tr & 7)) * 8));
      }
      #pragma unroll
      for (int ct = 0; ct < 2; ++ct) {
        int cl = wave * 32 + ct * 16 + mrow;
        bf[ct] = *(const half8*)(&Bh[buf][0] + cl * 64 + ((gq ^ (cl & 7)) * 8));
      }
      #pragma unroll
      for (int mt = 0; mt < 4; ++mt)
        #pragma unroll
        for (int ct = 0; ct < 2; ++ct)
          acc[mt][ct] = __builtin_amdgcn_mfma_f32_16x16x32_f16(
              af[mt], bf[ct], acc[mt][ct], 0, 0, 0);
    }
    __syncthreads();
    buf ^= 1;
  }
  #undef STAGE

  // epilogue: plain stores, bias fused: ypart[tok][slot][col] = w*(y + b_e)
  int rbase = (lane >> 4) * 4;
  int colbase = c0 + wave * 32 + mrow;
  float bia0 = fst_b[e * 512 + colbase];
  float bia1 = fst_b[e * 512 + colbase + 16];
  #pragma unroll
  for (int mt = 0; mt < 4; ++mt) {
    #pragma unroll
    for (int r = 0; r < 4; ++r) {
      int tloc = mt * 16 + rbase + r;
      float w = wl[tloc];
      if (w != 0.0f) {
        int v = tl[tloc];
        int tok = v & 4095;
        int slot = v >> 12;
        float* yp = ypart + (((size_t)tok * 8 + slot) << 9) + colbase;
        yp[0] = w * (acc[mt][0][r] + bia0);
        yp[16] = w * (acc[mt][1][r] + bia1);
      }
    }
  }
}

// ---- k4: out[b][f] = sum_s ypart[b][s][f] ----------------------------------
__global__ __launch_bounds__(256) void k4_reduce(const float* __restrict__ ypart,
                                                 float* __restrict__ out) {
  int b = blockIdx.x, tid = threadIdx.x;
  #pragma unroll
  for (int q = 0; q < 2; ++q) {
    int f = tid + q * 256;
    float a = 0.0f;
    #pragma unroll
    for (int s = 0; s < 8; ++s) a += ypart[(((size_t)b * 8 + s) << 9) + f];
    out[(size_t)b * 512 + f] = a;
  }
}

// ================= FP32 FALLBACK PATH (ws too small; never expected) ========
__global__ __launch_bounds__(64) void k0g(
    const float* __restrict__ pwT, const float* __restrict__ proj_b,
    const float* __restrict__ embT, const float* __restrict__ enT,
    float* __restrict__ Gpack, float* __restrict__ gbias) {
  __shared__ float row[256];
  int f = blockIdx.x;
  int e = threadIdx.x;
  const float* src = (f < 512) ? (pwT + f * 256) : proj_b;
  *(float4*)&row[e * 4] = *(const float4*)&src[e * 4];
  __syncthreads();
  float g = 0.0f;
  #pragma unroll 8
  for (int h = 0; h < 256; ++h) g = fmaf(row[h], embT[h * 64 + e], g);
  if (f < 512) {
    Gpack[(f * 64 + e) * 2 + 0] = g;
    Gpack[(f * 64 + e) * 2 + 1] = enT[f * 64 + e];
  } else {
    gbias[e] = g;
  }
}

__global__ __launch_bounds__(256) void k1_score(
    const float* __restrict__ features, const float* __restrict__ Gpack,
    const float* __restrict__ gbias, const float* __restrict__ coef,
    int* __restrict__ cnt, int* __restrict__ tk_idx, float* __restrict__ tk_w,
    int* __restrict__ tlist, float* __restrict__ wlist) {
  __shared__ float Ft[2][512];
  __shared__ float pl[4][64];
  __shared__ float ps[4][64];
  __shared__ float pn[4];
  int tid = threadIdx.x;
  int b0 = blockIdx.x * 2;
  {
    int t = tid >> 7;
    int fo = (tid & 127) * 4;
    *(float4*)&Ft[t][fo] =
        *(const float4*)&features[(size_t)(b0 + t) * 512 + fo];
  }
  __syncthreads();
  int wave = tid >> 6, e = tid & 63;
  int tok = wave & 1;
  int f0 = (wave >> 1) * 256;
  float la = 0.f, lb = 0.f, sa = 0.f, sb = 0.f;
  #pragma unroll 4
  for (int f = f0; f < f0 + 256; f += 2) {
    float2 g0 = *(const float2*)&Gpack[(f * 64 + e) * 2];
    float2 g1 = *(const float2*)&Gpack[((f + 1) * 64 + e) * 2];
    float x0 = Ft[tok][f];
    float x1 = Ft[tok][f + 1];
    la = fmaf(x0, g0.x, la);
    sa = fmaf(x0, g0.y, sa);
    lb = fmaf(x1, g1.x, lb);
    sb = fmaf(x1, g1.y, sb);
  }
  float nn = 0.f;
  #pragma unroll
  for (int j = 0; j < 4; ++j) {
    float v = Ft[tok][f0 + e + 64 * j];
    nn = fmaf(v, v, nn);
  }
  #pragma unroll
  for (int off = 32; off; off >>= 1) nn += __shfl_xor(nn, off);
  pl[wave][e] = la + lb;
  ps[wave][e] = sa + sb;
  if (e == 0) pn[wave] = nn;
  __syncthreads();
  if (wave < 2) {
    int b = b0 + wave;
    float l = pl[wave][e] + pl[wave + 2][e];
    float s = ps[wave][e] + ps[wave + 2][e];
    float ntot = pn[wave] + pn[wave + 2];
    float inv_n = 1.0f / fmaxf(sqrtf(ntot), 1e-8f);
    float gate = 1.0f / (1.0f + expf(-(l + gbias[e]) * 0.0625f));
    float sim = fmaxf(s * inv_n, 0.0f);
    float score = gate * sim * coef[e];
    float cur = score;
    float bv[8];
    int bi[8];
    #pragma unroll
    for (int r = 0; r < 8; ++r) {
      float mv = cur;
      int mi = e;
      #pragma unroll
      for (int off = 1; off < 64; off <<= 1) {
        float ov = __shfl_xor(mv, off);
        int oi = __shfl_xor(mi, off);
        if (ov > mv || (ov == mv && oi < mi)) { mv = ov; mi = oi; }
      }
      bv[r] = mv;
      bi[r] = mi;
      if (e == mi) cur = -1.0f;
    }
    float m0 = bv[0];
    float ex[8];
    float sum = 0.0f;
    #pragma unroll
    for (int r = 0; r < 8; ++r) { ex[r] = expf(bv[r] - m0); sum += ex[r]; }
    float isum = 1.0f / sum;
    if (e < 8) {
      int ir = 0; float er = 0.0f;
      switch (e) {
        case 0: ir = bi[0]; er = ex[0]; break;
        case 1: ir = bi[1]; er = ex[1]; break;
        case 2: ir = bi[2]; er = ex[2]; break;
        case 3: ir = bi[3]; er = ex[3]; break;
        case 4: ir = bi[4]; er = ex[4]; break;
        case 5: ir = bi[5]; er = ex[5]; break;
        case 6: ir = bi[6]; er = ex[6]; break;
        case 7: ir = bi[7]; er = ex[7]; break;
      }
      float wr = er * isum;
      int pos = atomicAdd(&cnt[ir], 1);
      tlist[ir * B_N + pos] = b;
      wlist[ir * B_N + pos] = wr;
      tk_idx[b * 8 + e] = ir;
      tk_w[b * 8 + e] = wr;
    }
  }
}

__global__ __launch_bounds__(256) void k2_bias(
    const int* __restrict__ tk_idx, const float* __restrict__ tk_w,
    const float* __restrict__ fst_b, float* __restrict__ out) {
  int b = blockIdx.x, tid = threadIdx.x;
  int ir[8];
  float wr[8];
  #pragma unroll
  for (int r = 0; r < 8; ++r) {
    ir[r] = tk_idx[b * 8 + r];
    wr[r] = tk_w[b * 8 + r];
  }
  #pragma unroll
  for (int q = 0; q < 2; ++q) {
    int f = tid + q * 256;
    float a = 0.0f;
    #pragma unroll
    for (int r = 0; r < 8; ++r) a = fmaf(wr[r], fst_b[ir[r] * 512 + f], a);
    out[(size_t)b * 512 + f] = a;
  }
}

#define TM 64
#define TN 256
#define KC 16
__global__ __launch_bounds__(256, 2) void k3_fst(
    const float* __restrict__ features, const float* __restrict__ fst_w,
    const int* __restrict__ cnt, const int* __restrict__ tlist,
    const float* __restrict__ wlist, float* __restrict__ out) {
  __shared__ float Ws[2][KC][TN];
  __shared__ float Ft[2][KC][TM];
  __shared__ int tl[TM];
  __shared__ float wl[TM];

  int tid = threadIdx.x;
  int e = blockIdx.x & 63;
  int rest = blockIdx.x >> 6;
  int tile = rest >> 1;
  int ch = rest & 1;
  int c0 = ch * TN;
  int c_e = cnt[e];
  int t0 = tile * TM;
  if (t0 >= c_e) return;

  if (tid < TM) {
    int t = t0 + tid;
    if (t < c_e) {
      tl[tid] = tlist[e * B_N + t] & 4095;
      wl[tid] = wlist[e * B_N + t];
    } else {
      tl[tid] = tlist[e * B_N + t0] & 4095;
      wl[tid] = 0.0f;
    }
  }
  __syncthreads();

  const float* fw_e = fst_w + (size_t)e * (512 * 512);
  int wave = tid >> 6, lane = tid & 63;
  int tg = wave * 2 + (lane >> 5);
  int cg = lane & 31;
  int ft_t = tid >> 2;
  int ft_fq = tid & 3;
  const float* ft_src_row = features + (size_t)tl[ft_t] * 512;

  auto stageWs = [&](int kc, int buf) {
    int f0 = kc * KC;
    #pragma unroll
    for (int r = 0; r < 4; ++r) {
      int f = wave * 4 + r;
      const float* src = fw_e + (size_t)(f0 + f) * 512 + c0 + lane * 4;
      __builtin_amdgcn_global_load_lds(
          (const __attribute__((address_space(1))) void*)src,
          (__attribute__((address_space(3))) void*)&Ws[buf][f][0], 16, 0, 0);
    }
  };
  auto loadFt = [&](int kc) -> float4 {
    return *(const float4*)&ft_src_row[kc * KC + ft_fq * 4];
  };
  auto writeFt = [&](float4 v, int buf) {
    Ft[buf][ft_fq * 4 + 0][ft_t] = v.x;
    Ft[buf][ft_fq * 4 + 1][ft_t] = v.y;
    Ft[buf][ft_fq * 4 + 2][ft_t] = v.z;
    Ft[buf][ft_fq * 4 + 3][ft_t] = v.w;
  };

  float acc[8][8];
  #pragma unroll
  for (int j = 0; j < 8; ++j)
    #pragma unroll
    for (int i = 0; i < 8; ++i) acc[j][i] = 0.0f;

  auto compute = [&](int buf) {
    #pragma unroll 4
    for (int f = 0; f < KC; ++f) {
      float4 a0 = *(const float4*)&Ft[buf][f][tg * 8];
      float4 a1 = *(const float4*)&Ft[buf][f][tg * 8 + 4];
      float4 w0 = *(const float4*)&Ws[buf][f][cg * 4];
      float4 w1 = *(const float4*)&Ws[buf][f][cg * 4 + 128];
      float av[8] = {a0.x, a0.y, a0.z, a0.w, a1.x, a1.y, a1.z, a1.w};
      float wv[8] = {w0.x, w0.y, w0.z, w0.w, w1.x, w1.y, w1.z, w1.w};
      #pragma unroll
      for (int j = 0; j < 8; ++j)
        #pragma unroll
        for (int i = 0; i < 8; ++i)
          acc[j][i] = fmaf(av[j], wv[i], acc[j][i]);
    }
  };

  stageWs(0, 0);
  float4 rf = loadFt(0);
  writeFt(rf, 0);
  __syncthreads();

  for (int kc = 0; kc < 32; ++kc) {
    int cb = kc & 1, nb = cb ^ 1;
    float4 rn = make_float4(0.f, 0.f, 0.f, 0.f);
    if (kc < 31) {
      stageWs(kc + 1, nb);
      rn = loadFt(kc + 1);
    }
    compute(cb);
    if (kc < 31) writeFt(rn, nb);
    __syncthreads();
  }

  #pragma unroll
  for (int j = 0; j < 8; ++j) {
    int lt = tg * 8 + j;
    float w = wl[lt];
    if (w != 0.0f) {
      size_t orow = (size_t)tl[lt] * 512 + c0 + cg * 4;
      #pragma unroll
      for (int i = 0; i < 4; ++i) atomicAdd(&out[orow + i], w * acc[j][i]);
      #pragma unroll
      for (int i = 0; i < 4; ++i)
        atomicAdd(&out[orow + 128 + i], w * acc[j][i + 4]);
    }
  }
}

// ---------------- launch ----------------------------------------------------
extern "C" void kernel_launch(void* const* d_in, const int* in_sizes, int n_in,
                              void* d_out, int out_size, void* d_ws,
                              size_t ws_size, hipStream_t stream) {
  const float* features = (const float*)d_in[0];
  const float* proj_w = (const float*)d_in[1];
  const float* proj_b = (const float*)d_in[2];
  const float* expert_emb = (const float*)d_in[3];
  const float* expert_features = (const float*)d_in[4];
  const float* trust = (const float*)d_in[5];
  const float* dt = (const float*)d_in[6];
  const float* fst_w = (const float*)d_in[7];
  const float* fst_b = (const float*)d_in[8];
  float* out = (float*)d_out;
  float* ws = (float*)d_ws;

  // ---- new-path layout (unioned; 70,263,808 B total) ----
  float* coef = ws;                          // 64
  int* cnt = (int*)(ws + 64);                // 64
  float* gbias = ws + 128;                   // 64
  int* njobs = (int*)(ws + 192);             // 64
  int* jobs = (int*)(ws + 256);              // 2048
  int* tlist = (int*)(ws + 2304);            // 64*2048
  float* wlist = ws + 133376;                // 64*2048
  _Float16* Fh = (_Float16*)(ws + 264448);   // 2048*512 halfs
  _Float16* WhT = (_Float16*)(ws + 788736);  // 64*512*512 halfs
  float* U = ws + 9177344;                   // union region
  float* pwT = U;                            // 512*256 (pre-k3 only)
  float* embT = U + 131072;                  // 256*64
  float* enT = U + 147456;                   // 512*64
  _Float16* Fl = (_Float16*)(U + 180224);    // 2048*512 halfs
  _Float16* GhT = (_Float16*)(U + 704512);   // 128*512 halfs
  _Float16* GlT = (_Float16*)(U + 737280);   // 128*512 halfs
  float* fnorm = U + 770048;                 // 2048
  float* ypart = U;                          // 2048*8*512 (k3/k4, clobbers above)
  size_t need3 = (size_t)(9177344 + 8388608) * 4;

  if (ws_size >= need3) {
    hipLaunchKernelGGL(k_prep, dim3(2112), dim3(256), 0, stream, proj_w,
                       expert_emb, expert_features, trust, dt, features, fst_w,
                       pwT, embT, enT, coef, cnt, Fh, Fl, fnorm, WhT);
    hipLaunchKernelGGL(k0gs, dim3(513), dim3(64), 0, stream, pwT, proj_b,
                       embT, enT, GhT, GlT, gbias);
    hipLaunchKernelGGL(k1_mfma, dim3(64), dim3(256), 0, stream, Fh, Fl, GhT,
                       GlT, fnorm, coef, gbias, cnt, tlist, wlist);
    hipLaunchKernelGGL(k_sched, dim3(1), dim3(64), 0, stream, cnt, jobs,
                       njobs);
    hipLaunchKernelGGL(k3_mfma, dim3(2048), dim3(256), 0, stream, Fh, WhT,
                       fst_b, cnt, tlist, wlist, jobs, njobs, ypart);
    hipLaunchKernelGGL(k4_reduce, dim3(2048), dim3(256), 0, stream, ypart,
                       out);
  } else {
    // fp32 fallback (compact layout, ~2.2 MB)
    float* pwT2 = ws;                         // 512*256
    float* embT2 = pwT2 + 131072;             // 256*64
    float* enT2 = embT2 + 16384;              // 512*64
    float* coef2 = enT2 + 32768;              // 64
    int* cnt2 = (int*)(coef2 + 64);           // 64
    int* tk_idx = cnt2 + 64;                  // 2048*8
    float* tk_w = (float*)(tk_idx + 16384);   // 2048*8
    int* tlist2 = (int*)(tk_w + 16384);       // 64*2048
    float* wlist2 = (float*)(tlist2 + 131072);
    float* Gpack = wlist2 + 131072;           // 512*64*2
    float* gbias2 = Gpack + 65536;            // 64
    hipLaunchKernelGGL(k_prep, dim3(576), dim3(256), 0, stream, proj_w,
                       expert_emb, expert_features, trust, dt, features, fst_w,
                       pwT2, embT2, enT2, coef2, cnt2, (_Float16*)Gpack,
                       (_Float16*)Gpack, Gpack, (_Float16*)Gpack);
    hipLaunchKernelGGL(k0g, dim3(513), dim3(64), 0, stream, pwT2, proj_b,
                       embT2, enT2, Gpack, gbias2);
    hipLaunchKernelGGL(k1_score, dim3(1024), dim3(256), 0, stream, features,
                       Gpack, gbias2, coef2, cnt2, tk_idx, tk_w, tlist2,
                       wlist2);
    hipLaunchKernelGGL(k2_bias, dim3(2048), dim3(256), 0, stream, tk_idx,
                       tk_w, fst_b, out);
    hipLaunchKernelGGL(k3_fst, dim3(4096), dim3(256), 0, stream, features,
                       fst_w, cnt2, tlist2, wlist2, out);
  }
}

// Round 11
// 101.459 us; speedup vs baseline: 2.7467x; 1.2291x over previous
//
#include <hip/hip_runtime.h>
#include <hip/hip_fp16.h>
#include <math.h>

#define B_N 2048
#define F_N 512
#define H_N 256
#define E_N 64

typedef __attribute__((ext_vector_type(8))) _Float16 half8;
typedef __attribute__((ext_vector_type(4))) float f32x4;

// ================= MAIN PATH (8 kernels) ====================================

// ---- k_prep: fused input transforms. grid 2112 (new) or 576 (fallback).
__global__ __launch_bounds__(256) void k_prep(
    const float* __restrict__ proj_w, const float* __restrict__ expert_emb,
    const float* __restrict__ expert_features, const float* __restrict__ trust,
    const float* __restrict__ dt, const float* __restrict__ features,
    const float* __restrict__ fst_w, float* __restrict__ pwT,
    float* __restrict__ embT, float* __restrict__ enT,
    float* __restrict__ coef, int* __restrict__ cnt, _Float16* __restrict__ Fh,
    _Float16* __restrict__ Fl, float* __restrict__ fnorm,
    _Float16* __restrict__ WhT, int* __restrict__ njobs) {
  __shared__ float tile[16704];  // convW staging (65 KB)
  __shared__ float parts[4];
  int bid = blockIdx.x, tid = threadIdx.x;
  if (bid < 512) {
    int idx = bid * 256 + tid;
    int f = idx >> 8, h = idx & 255;
    pwT[idx] = proj_w[h * 512 + f];
    if (bid == 0 && tid < E_N) cnt[tid] = 0;
    if (bid == 0 && tid == 64) njobs[0] = 0;
  } else if (bid < 576) {
    int e = bid - 512;  // 0..63
    float v0 = expert_features[e * 512 + tid];
    float v1 = expert_features[e * 512 + tid + 256];
    float ss = v0 * v0 + v1 * v1;
    #pragma unroll
    for (int off = 32; off; off >>= 1) ss += __shfl_xor(ss, off);
    if ((tid & 63) == 0) parts[tid >> 6] = ss;
    __syncthreads();
    float tot = parts[0] + parts[1] + parts[2] + parts[3];
    float inv = 1.0f / fmaxf(sqrtf(tot), 1e-8f);
    enT[tid * 64 + e] = v0 * inv;
    enT[(tid + 256) * 64 + e] = v1 * inv;
    embT[tid * 64 + e] = expert_emb[e * 256 + tid];
    if (tid == 0) {
      float st = fmaxf(0.1f, expf(-0.005f * dt[e]));
      coef[e] = trust[e] * st;
    }
  } else if (bid < 1088) {
    // convF: fp16 hi + scaled lo + row norms
    int gid = (bid - 576) * 256 + tid;
    int i = gid * 8;
    float4 v0 = *(const float4*)(features + i);
    float4 v1 = *(const float4*)(features + i + 4);
    float xs[8] = {v0.x, v0.y, v0.z, v0.w, v1.x, v1.y, v1.z, v1.w};
    half8 h, l;
    float ss = 0.0f;
    #pragma unroll
    for (int j = 0; j < 8; ++j) {
      h[j] = (_Float16)xs[j];
      l[j] = (_Float16)((xs[j] - (float)h[j]) * 2048.0f);
      ss = fmaf(xs[j], xs[j], ss);
    }
    *(half8*)(Fh + i) = h;
    *(half8*)(Fl + i) = l;
    #pragma unroll
    for (int off = 32; off; off >>= 1) ss += __shfl_xor(ss, off);
    if ((tid & 63) == 0) fnorm[gid >> 6] = ss;
  } else {
    // convW: fst_w -> transposed fp16 [e][col][k]
    int b2 = bid - 1088;  // 1024 = 64e x 8kb x 2cb
    int e = b2 >> 4;
    int kb = (b2 >> 1) & 7;
    int cb = b2 & 1;
    const float* src = fst_w + ((size_t)e << 18) + (size_t)(kb * 64) * 512 +
                       cb * 256;
    int kr = tid >> 6;
    int c4 = (tid & 63) * 4;
    #pragma unroll
    for (int r = 0; r < 16; ++r) {
      int k = r * 4 + kr;
      *(float4*)&tile[k * 260 + ((k >> 3) << 2) + c4] =
          *(const float4*)&src[(size_t)k * 512 + c4];
    }
    __syncthreads();
    int co = tid >> 3;
    int ko = (tid & 7) * 8;
    #pragma unroll
    for (int g = 0; g < 8; ++g) {
      int c = g * 32 + co;
      half8 vh;
      #pragma unroll
      for (int i = 0; i < 8; ++i) {
        int k = ko + i;
        vh[i] = (_Float16)tile[k * 260 + ((k >> 3) << 2) + c];
      }
      size_t dbase =
          ((size_t)e << 18) + (size_t)(cb * 256 + c) * 512 + kb * 64 + ko;
      *(half8*)(WhT + dbase) = vh;
    }
  }
}

// ---- k0gs: gate matrix + enT -> fp16 2-term GhT/GlT [128 col][512 k]; gbias
__global__ __launch_bounds__(64) void k0gs(
    const float* __restrict__ pwT, const float* __restrict__ proj_b,
    const float* __restrict__ embT, const float* __restrict__ enT,
    _Float16* __restrict__ GhT, _Float16* __restrict__ GlT,
    float* __restrict__ gbias) {
  __shared__ float row[256];
  int f = blockIdx.x;
  int e = threadIdx.x;
  const float* src = (f < 512) ? (pwT + f * 256) : proj_b;
  *(float4*)&row[e * 4] = *(const float4*)&src[e * 4];
  __syncthreads();
  float g = 0.0f;
  #pragma unroll 8
  for (int h = 0; h < 256; ++h) g = fmaf(row[h], embT[h * 64 + e], g);
  if (f < 512) {
    _Float16 h0 = (_Float16)g;
    GhT[e * 512 + f] = h0;
    GlT[e * 512 + f] = (_Float16)((g - (float)h0) * 2048.0f);
    float en = enT[f * 64 + e];
    _Float16 h1 = (_Float16)en;
    GhT[(64 + e) * 512 + f] = h1;
    GlT[(64 + e) * 512 + f] = (_Float16)((en - (float)h1) * 2048.0f);
  } else {
    gbias[e] = g;
  }
}

// ---- k1a: scoring GEMM via MFMA, fp16 2-term, K-split 4 (r9 structure) -----
__global__ __launch_bounds__(256, 2) void k1a_mfma(
    const _Float16* __restrict__ Fh, const _Float16* __restrict__ Fl,
    const _Float16* __restrict__ GhT, const _Float16* __restrict__ GlT,
    float* __restrict__ scores4) {
  __shared__ _Float16 Bh[2][128 * 64];  // 32 KB
  __shared__ _Float16 Bl[2][128 * 64];  // 32 KB
  __shared__ _Float16 Ah[2][32 * 64];   // 8 KB
  __shared__ _Float16 Al[2][32 * 64];   // 8 KB

  int tid = threadIdx.x;
  int kc = blockIdx.x & 3;
  int tt = blockIdx.x >> 2;   // 0..63
  int b0 = tt * 32;
  int k0 = kc * 128;
  int wave = tid >> 6, lane = tid & 63;

  size_t bsrc[4];
  int bdst[4];
  #pragma unroll
  for (int i = 0; i < 4; ++i) {
    int cw = wave * 32 + i * 8;
    int cl = cw + (lane >> 3);
    int g = (lane & 7) ^ (cl & 7);
    bsrc[i] = (size_t)cl * 512 + k0 + g * 8;
    bdst[i] = cw * 64;
  }
  int tw = wave * 8;
  int tkl = tw + (lane >> 3);
  int ga = (lane & 7) ^ (tkl & 7);
  size_t asrc = (size_t)(b0 + tkl) * 512 + k0 + ga * 8;
  int adst = tw * 64;

  f32x4 accH[2][2], accM[2][2];
  #pragma unroll
  for (int mt = 0; mt < 2; ++mt)
    #pragma unroll
    for (int ct = 0; ct < 2; ++ct) {
      accH[mt][ct] = (f32x4){0.f, 0.f, 0.f, 0.f};
      accM[mt][ct] = (f32x4){0.f, 0.f, 0.f, 0.f};
    }
  int kg = lane >> 4;
  int mrow = lane & 15;

  #define STG(K0S, BUF)                                                       \
    do {                                                                      \
      _Pragma("unroll")                                                       \
      for (int i = 0; i < 4; ++i) {                                           \
        __builtin_amdgcn_global_load_lds(                                     \
            (const __attribute__((address_space(1))) void*)(GhT + bsrc[i] + (K0S)), \
            (__attribute__((address_space(3))) void*)(&Bh[BUF][0] + bdst[i]), 16, 0, 0);\
        __builtin_amdgcn_global_load_lds(                                     \
            (const __attribute__((address_space(1))) void*)(GlT + bsrc[i] + (K0S)), \
            (__attribute__((address_space(3))) void*)(&Bl[BUF][0] + bdst[i]), 16, 0, 0);\
      }                                                                       \
      __builtin_amdgcn_global_load_lds(                                       \
          (const __attribute__((address_space(1))) void*)(Fh + asrc + (K0S)),  \
          (__attribute__((address_space(3))) void*)(&Ah[BUF][0] + adst), 16, 0, 0);\
      __builtin_amdgcn_global_load_lds(                                       \
          (const __attribute__((address_space(1))) void*)(Fl + asrc + (K0S)),  \
          (__attribute__((address_space(3))) void*)(&Al[BUF][0] + adst), 16, 0, 0);\
    } while (0)

  STG(0, 0);
  __syncthreads();
  int buf = 0;
  #pragma unroll
  for (int s = 0; s < 2; ++s) {
    if (s < 1) STG(64, 1);
    #pragma unroll
    for (int kh = 0; kh < 2; ++kh) {
      int gq = kh * 4 + kg;
      half8 afh[2], afl[2], bfh[2], bfl[2];
      #pragma unroll
      for (int mt = 0; mt < 2; ++mt) {
        int tr = mt * 16 + mrow;
        int off = tr * 64 + ((gq ^ (tr & 7)) * 8);
        afh[mt] = *(const half8*)(&Ah[buf][0] + off);
        afl[mt] = *(const half8*)(&Al[buf][0] + off);
      }
      #pragma unroll
      for (int ct = 0; ct < 2; ++ct) {
        int cl = wave * 32 + ct * 16 + mrow;
        int off = cl * 64 + ((gq ^ (cl & 7)) * 8);
        bfh[ct] = *(const half8*)(&Bh[buf][0] + off);
        bfl[ct] = *(const half8*)(&Bl[buf][0] + off);
      }
      #pragma unroll
      for (int mt = 0; mt < 2; ++mt)
        #pragma unroll
        for (int ct = 0; ct < 2; ++ct) {
          accH[mt][ct] = __builtin_amdgcn_mfma_f32_16x16x32_f16(
              afh[mt], bfh[ct], accH[mt][ct], 0, 0, 0);
          accM[mt][ct] = __builtin_amdgcn_mfma_f32_16x16x32_f16(
              afh[mt], bfl[ct], accM[mt][ct], 0, 0, 0);
          accM[mt][ct] = __builtin_amdgcn_mfma_f32_16x16x32_f16(
              afl[mt], bfh[ct], accM[mt][ct], 0, 0, 0);
        }
    }
    __syncthreads();
    buf ^= 1;
  }
  #undef STG

  int rbase = (lane >> 4) * 4;
  #pragma unroll
  for (int mt = 0; mt < 2; ++mt)
    #pragma unroll
    for (int ct = 0; ct < 2; ++ct)
      #pragma unroll
      for (int r = 0; r < 4; ++r) {
        int tok = b0 + mt * 16 + rbase + r;
        int col = wave * 32 + ct * 16 + mrow;
        scores4[((size_t)(kc * 2048 + tok) << 7) + col] =
            accH[mt][ct][r] + accM[mt][ct][r] * (1.0f / 2048.0f);
      }
}

// ---- k1b: rank-based top-8 (no butterfly, no global atomics) ---------------
// 512 blocks x 4 tokens; wave = one token, lane = expert.
// rank_e = #{j: s_j > s_e or (s_j==s_e and j<e)}  == jax top_k order.
__global__ __launch_bounds__(256) void k1b_rank(
    const float* __restrict__ scores4, const float* __restrict__ fnorm,
    const float* __restrict__ coef, const float* __restrict__ gbias,
    int* __restrict__ sel, float* __restrict__ selw) {
  __shared__ float sc[4][64];
  __shared__ float ex8[4][8];
  int tid = threadIdx.x;
  int wave = tid >> 6, lane = tid & 63;
  int b = blockIdx.x * 4 + wave;

  float l = 0.f, s = 0.f;
  #pragma unroll
  for (int kc = 0; kc < 4; ++kc) {
    const float* row = scores4 + ((size_t)(kc * 2048 + b) << 7);
    l += row[lane];
    s += row[64 + lane];
  }
  float inv_n = 1.0f / fmaxf(sqrtf(fnorm[b]), 1e-8f);
  float gate = 1.0f / (1.0f + expf(-(l + gbias[lane]) * 0.0625f));
  float sim = fmaxf(s * inv_n, 0.0f);
  float score = gate * sim * coef[lane];
  sc[wave][lane] = score;

  // rank + max via 64 independent LDS-broadcast reads (no dependent chain)
  int rank = 0;
  float mx = score;
  #pragma unroll 8
  for (int j = 0; j < 64; ++j) {
    float sj = sc[wave][j];
    rank += (sj > score || (sj == score && j < lane)) ? 1 : 0;
    mx = fmaxf(mx, sj);
  }
  float ev = expf(score - mx);
  if (rank < 8) ex8[wave][rank] = ev;
  float sum = 0.f;
  #pragma unroll
  for (int r = 0; r < 8; ++r) sum += ex8[wave][r];
  if (rank < 8) {
    sel[b * 8 + rank] = lane;
    selw[b * 8 + rank] = ev / sum;
  }
}

// ---- k_gather: per-expert compaction (LDS atomics) + jobs (1 atomic/expert)
__global__ __launch_bounds__(256) void k_gather(
    const int* __restrict__ sel, const float* __restrict__ selw,
    int* __restrict__ cnt, int* __restrict__ tlist, float* __restrict__ wlist,
    int* __restrict__ jobs, int* __restrict__ njobs) {
  __shared__ int lcnt;
  int e = blockIdx.x;
  int tid = threadIdx.x;
  if (tid == 0) lcnt = 0;
  __syncthreads();
  // scan 16384 entries, 64 per thread, coalesced stride
  for (int q = 0; q < 64; ++q) {
    int i = q * 256 + tid;
    if (sel[i] == e) {
      int pos = atomicAdd(&lcnt, 1);
      tlist[e * B_N + pos] = (i >> 3) | ((i & 7) << 12);  // token | slot<<12
      wlist[e * B_N + pos] = selw[i];
    }
  }
  __syncthreads();
  if (tid == 0) {
    int c = lcnt;
    cnt[e] = c;
    int nt = (c + 63) >> 6;
    int base = atomicAdd(njobs, nt);  // 64 atomics total, uncontended-ish
    for (int t = 0; t < nt; ++t) jobs[base + t] = (e << 8) | t;
  }
}

// ---- k3_mfma: gathered FST GEMM; plain stores (bias fused) to ypart --------
__global__ __launch_bounds__(256, 3) void k3_mfma(
    const _Float16* __restrict__ Fh, const _Float16* __restrict__ WhT,
    const float* __restrict__ fst_b, const int* __restrict__ cnt,
    const int* __restrict__ tlist, const float* __restrict__ wlist,
    const int* __restrict__ jobs, const int* __restrict__ njobs,
    float* __restrict__ ypart) {
  __shared__ _Float16 Bh[2][128 * 64];  // 32 KB
  __shared__ _Float16 Ah[2][64 * 64];   // 16 KB
  __shared__ int tl[64];
  __shared__ float wl[64];

  int tid = threadIdx.x;
  int job = blockIdx.x >> 2;
  int chunk = blockIdx.x & 3;
  if (job >= njobs[0]) return;
  int jb = jobs[job];
  int e = jb >> 8;
  int tile = jb & 255;
  int c0 = chunk * 128;
  int c_e = cnt[e];
  int t0 = tile * 64;

  if (tid < 64) {
    int t = t0 + tid;
    tl[tid] = tlist[e * B_N + (t < c_e ? t : t0)];
    wl[tid] = (t < c_e) ? wlist[e * B_N + t] : 0.0f;
  }
  __syncthreads();

  int wave = tid >> 6, lane = tid & 63;
  const _Float16* WhT_e = WhT + ((size_t)e << 18);

  size_t bsrc[4];
  int bdst[4];
  #pragma unroll
  for (int i = 0; i < 4; ++i) {
    int cw = wave * 32 + i * 8;
    int cl = cw + (lane >> 3);
    int g = (lane & 7) ^ (cl & 7);
    bsrc[i] = (size_t)(c0 + cl) * 512 + g * 8;
    bdst[i] = cw * 64;
  }
  size_t asrc[2];
  int adst[2];
  #pragma unroll
  for (int j = 0; j < 2; ++j) {
    int tw = wave * 16 + j * 8;
    int tkl = tw + (lane >> 3);
    int g = (lane & 7) ^ (tkl & 7);
    asrc[j] = (size_t)(tl[tkl] & 4095) * 512 + g * 8;
    adst[j] = tw * 64;
  }

  f32x4 acc[4][2];
  #pragma unroll
  for (int mt = 0; mt < 4; ++mt)
    #pragma unroll
    for (int ct = 0; ct < 2; ++ct) acc[mt][ct] = (f32x4){0.f, 0.f, 0.f, 0.f};

  int kg = lane >> 4;
  int mrow = lane & 15;

  #define STAGE(K0S, BUF)                                                     \
    do {                                                                      \
      _Pragma("unroll")                                                       \
      for (int i = 0; i < 4; ++i) {                                           \
        __builtin_amdgcn_global_load_lds(                                     \
            (const __attribute__((address_space(1))) void*)(WhT_e + bsrc[i] + (K0S)), \
            (__attribute__((address_space(3))) void*)(&Bh[BUF][0] + bdst[i]), 16, 0, 0);\
      }                                                                       \
      _Pragma("unroll")                                                       \
      for (int j = 0; j < 2; ++j) {                                           \
        __builtin_amdgcn_global_load_lds(                                     \
            (const __attribute__((address_space(1))) void*)(Fh + asrc[j] + (K0S)), \
            (__attribute__((address_space(3))) void*)(&Ah[BUF][0] + adst[j]), 16, 0, 0);\
      }                                                                       \
    } while (0)

  STAGE(0, 0);
  __syncthreads();

  int buf = 0;
  for (int s = 0; s < 8; ++s) {
    if (s < 7) STAGE((s + 1) * 64, buf ^ 1);
    #pragma unroll
    for (int kh = 0; kh < 2; ++kh) {
      int gq = kh * 4 + kg;
      half8 af[4], bf[2];
      #pragma unroll
      for (int mt = 0; mt < 4; ++mt) {
        int tr = mt * 16 + mrow;
        af[mt] = *(const half8*)(&Ah[buf][0] + tr * 64 + ((gq ^ (tr & 7)) * 8));
      }
      #pragma unroll
      for (int ct = 0; ct < 2; ++ct) {
        int cl = wave * 32 + ct * 16 + mrow;
        bf[ct] = *(const half8*)(&Bh[buf][0] + cl * 64 + ((gq ^ (cl & 7)) * 8));
      }
      #pragma unroll
      for (int mt = 0; mt < 4; ++mt)
        #pragma unroll
        for (int ct = 0; ct < 2; ++ct)
          acc[mt][ct] = __builtin_amdgcn_mfma_f32_16x16x32_f16(
              af[mt], bf[ct], acc[mt][ct], 0, 0, 0);
    }
    __syncthreads();
    buf ^= 1;
  }
  #undef STAGE

  int rbase = (lane >> 4) * 4;
  int colbase = c0 + wave * 32 + mrow;
  float bia0 = fst_b[e * 512 + colbase];
  float bia1 = fst_b[e * 512 + colbase + 16];
  #pragma unroll
  for (int mt = 0; mt < 4; ++mt) {
    #pragma unroll
    for (int r = 0; r < 4; ++r) {
      int tloc = mt * 16 + rbase + r;
      float w = wl[tloc];
      if (w != 0.0f) {
        int v = tl[tloc];
        int tok = v & 4095;
        int slot = v >> 12;
        float* yp = ypart + (((size_t)tok * 8 + slot) << 9) + colbase;
        yp[0] = w * (acc[mt][0][r] + bia0);
        yp[16] = w * (acc[mt][1][r] + bia1);
      }
    }
  }
}

// ---- k4: out[b][f] = sum_s ypart[b][s][f] ----------------------------------
__global__ __launch_bounds__(256) void k4_reduce(const float* __restrict__ ypart,
                                                 float* __restrict__ out) {
  int b = blockIdx.x, tid = threadIdx.x;
  #pragma unroll
  for (int q = 0; q < 2; ++q) {
    int f = tid + q * 256;
    float a = 0.0f;
    #pragma unroll
    for (int s = 0; s < 8; ++s) a += ypart[(((size_t)b * 8 + s) << 9) + f];
    out[(size_t)b * 512 + f] = a;
  }
}

// ================= FP32 FALLBACK PATH (ws too small; never expected) ========
__global__ __launch_bounds__(64) void k0g(
    const float* __restrict__ pwT, const float* __restrict__ proj_b,
    const float* __restrict__ embT, const float* __restrict__ enT,
    float* __restrict__ Gpack, float* __restrict__ gbias) {
  __shared__ float row[256];
  int f = blockIdx.x;
  int e = threadIdx.x;
  const float* src = (f < 512) ? (pwT + f * 256) : proj_b;
  *(float4*)&row[e * 4] = *(const float4*)&src[e * 4];
  __syncthreads();
  float g = 0.0f;
  #pragma unroll 8
  for (int h = 0; h < 256; ++h) g = fmaf(row[h], embT[h * 64 + e], g);
  if (f < 512) {
    Gpack[(f * 64 + e) * 2 + 0] = g;
    Gpack[(f * 64 + e) * 2 + 1] = enT[f * 64 + e];
  } else {
    gbias[e] = g;
  }
}

__global__ __launch_bounds__(256) void k1_score(
    const float* __restrict__ features, const float* __restrict__ Gpack,
    const float* __restrict__ gbias, const float* __restrict__ coef,
    int* __restrict__ cnt, int* __restrict__ tk_idx, float* __restrict__ tk_w,
    int* __restrict__ tlist, float* __restrict__ wlist) {
  __shared__ float Ft[2][512];
  __shared__ float pl[4][64];
  __shared__ float ps[4][64];
  __shared__ float pn[4];
  int tid = threadIdx.x;
  int b0 = blockIdx.x * 2;
  {
    int t = tid >> 7;
    int fo = (tid & 127) * 4;
    *(float4*)&Ft[t][fo] =
        *(const float4*)&features[(size_t)(b0 + t) * 512 + fo];
  }
  __syncthreads();
  int wave = tid >> 6, e = tid & 63;
  int tok = wave & 1;
  int f0 = (wave >> 1) * 256;
  float la = 0.f, lb = 0.f, sa = 0.f, sb = 0.f;
  #pragma unroll 4
  for (int f = f0; f < f0 + 256; f += 2) {
    float2 g0 = *(const float2*)&Gpack[(f * 64 + e) * 2];
    float2 g1 = *(const float2*)&Gpack[((f + 1) * 64 + e) * 2];
    float x0 = Ft[tok][f];
    float x1 = Ft[tok][f + 1];
    la = fmaf(x0, g0.x, la);
    sa = fmaf(x0, g0.y, sa);
    lb = fmaf(x1, g1.x, lb);
    sb = fmaf(x1, g1.y, sb);
  }
  float nn = 0.f;
  #pragma unroll
  for (int j = 0; j < 4; ++j) {
    float v = Ft[tok][f0 + e + 64 * j];
    nn = fmaf(v, v, nn);
  }
  #pragma unroll
  for (int off = 32; off; off >>= 1) nn += __shfl_xor(nn, off);
  pl[wave][e] = la + lb;
  ps[wave][e] = sa + sb;
  if (e == 0) pn[wave] = nn;
  __syncthreads();
  if (wave < 2) {
    int b = b0 + wave;
    float l = pl[wave][e] + pl[wave + 2][e];
    float s = ps[wave][e] + ps[wave + 2][e];
    float ntot = pn[wave] + pn[wave + 2];
    float inv_n = 1.0f / fmaxf(sqrtf(ntot), 1e-8f);
    float gate = 1.0f / (1.0f + expf(-(l + gbias[e]) * 0.0625f));
    float sim = fmaxf(s * inv_n, 0.0f);
    float score = gate * sim * coef[e];
    float cur = score;
    float bv[8];
    int bi[8];
    #pragma unroll
    for (int r = 0; r < 8; ++r) {
      float mv = cur;
      int mi = e;
      #pragma unroll
      for (int off = 1; off < 64; off <<= 1) {
        float ov = __shfl_xor(mv, off);
        int oi = __shfl_xor(mi, off);
        if (ov > mv || (ov == mv && oi < mi)) { mv = ov; mi = oi; }
      }
      bv[r] = mv;
      bi[r] = mi;
      if (e == mi) cur = -1.0f;
    }
    float m0 = bv[0];
    float ex[8];
    float sum = 0.0f;
    #pragma unroll
    for (int r = 0; r < 8; ++r) { ex[r] = expf(bv[r] - m0); sum += ex[r]; }
    float isum = 1.0f / sum;
    if (e < 8) {
      int ir = 0; float er = 0.0f;
      switch (e) {
        case 0: ir = bi[0]; er = ex[0]; break;
        case 1: ir = bi[1]; er = ex[1]; break;
        case 2: ir = bi[2]; er = ex[2]; break;
        case 3: ir = bi[3]; er = ex[3]; break;
        case 4: ir = bi[4]; er = ex[4]; break;
        case 5: ir = bi[5]; er = ex[5]; break;
        case 6: ir = bi[6]; er = ex[6]; break;
        case 7: ir = bi[7]; er = ex[7]; break;
      }
      float wr = er * isum;
      int pos = atomicAdd(&cnt[ir], 1);
      tlist[ir * B_N + pos] = b;
      wlist[ir * B_N + pos] = wr;
      tk_idx[b * 8 + e] = ir;
      tk_w[b * 8 + e] = wr;
    }
  }
}

__global__ __launch_bounds__(256) void k2_bias(
    const int* __restrict__ tk_idx, const float* __restrict__ tk_w,
    const float* __restrict__ fst_b, float* __restrict__ out) {
  int b = blockIdx.x, tid = threadIdx.x;
  int ir[8];
  float wr[8];
  #pragma unroll
  for (int r = 0; r < 8; ++r) {
    ir[r] = tk_idx[b * 8 + r];
    wr[r] = tk_w[b * 8 + r];
  }
  #pragma unroll
  for (int q = 0; q < 2; ++q) {
    int f = tid + q * 256;
    float a = 0.0f;
    #pragma unroll
    for (int r = 0; r < 8; ++r) a = fmaf(wr[r], fst_b[ir[r] * 512 + f], a);
    out[(size_t)b * 512 + f] = a;
  }
}

#define TM 64
#define TN 256
#define KC 16
__global__ __launch_bounds__(256, 2) void k3_fst(
    const float* __restrict__ features, const float* __restrict__ fst_w,
    const int* __restrict__ cnt, const int* __restrict__ tlist,
    const float* __restrict__ wlist, float* __restrict__ out) {
  __shared__ float Ws[2][KC][TN];
  __shared__ float Ft[2][KC][TM];
  __shared__ int tl[TM];
  __shared__ float wl[TM];

  int tid = threadIdx.x;
  int e = blockIdx.x & 63;
  int rest = blockIdx.x >> 6;
  int tile = rest >> 1;
  int ch = rest & 1;
  int c0 = ch * TN;
  int c_e = cnt[e];
  int t0 = tile * TM;
  if (t0 >= c_e) return;

  if (tid < TM) {
    int t = t0 + tid;
    if (t < c_e) {
      tl[tid] = tlist[e * B_N + t] & 4095;
      wl[tid] = wlist[e * B_N + t];
    } else {
      tl[tid] = tlist[e * B_N + t0] & 4095;
      wl[tid] = 0.0f;
    }
  }
  __syncthreads();

  const float* fw_e = fst_w + (size_t)e * (512 * 512);
  int wave = tid >> 6, lane = tid & 63;
  int tg = wave * 2 + (lane >> 5);
  int cg = lane & 31;
  int ft_t = tid >> 2;
  int ft_fq = tid & 3;
  const float* ft_src_row = features + (size_t)tl[ft_t] * 512;

  auto stageWs = [&](int kc, int buf) {
    int f0 = kc * KC;
    #pragma unroll
    for (int r = 0; r < 4; ++r) {
      int f = wave * 4 + r;
      const float* src = fw_e + (size_t)(f0 + f) * 512 + c0 + lane * 4;
      __builtin_amdgcn_global_load_lds(
          (const __attribute__((address_space(1))) void*)src,
          (__attribute__((address_space(3))) void*)&Ws[buf][f][0], 16, 0, 0);
    }
  };
  auto loadFt = [&](int kc) -> float4 {
    return *(const float4*)&ft_src_row[kc * KC + ft_fq * 4];
  };
  auto writeFt = [&](float4 v, int buf) {
    Ft[buf][ft_fq * 4 + 0][ft_t] = v.x;
    Ft[buf][ft_fq * 4 + 1][ft_t] = v.y;
    Ft[buf][ft_fq * 4 + 2][ft_t] = v.z;
    Ft[buf][ft_fq * 4 + 3][ft_t] = v.w;
  };

  float acc[8][8];
  #pragma unroll
  for (int j = 0; j < 8; ++j)
    #pragma unroll
    for (int i = 0; i < 8; ++i) acc[j][i] = 0.0f;

  auto compute = [&](int buf) {
    #pragma unroll 4
    for (int f = 0; f < KC; ++f) {
      float4 a0 = *(const float4*)&Ft[buf][f][tg * 8];
      float4 a1 = *(const float4*)&Ft[buf][f][tg * 8 + 4];
      float4 w0 = *(const float4*)&Ws[buf][f][cg * 4];
      float4 w1 = *(const float4*)&Ws[buf][f][cg * 4 + 128];
      float av[8] = {a0.x, a0.y, a0.z, a0.w, a1.x, a1.y, a1.z, a1.w};
      float wv[8] = {w0.x, w0.y, w0.z, w0.w, w1.x, w1.y, w1.z, w1.w};
      #pragma unroll
      for (int j = 0; j < 8; ++j)
        #pragma unroll
        for (int i = 0; i < 8; ++i)
          acc[j][i] = fmaf(av[j], wv[i], acc[j][i]);
    }
  };

  stageWs(0, 0);
  float4 rf = loadFt(0);
  writeFt(rf, 0);
  __syncthreads();

  for (int kc = 0; kc < 32; ++kc) {
    int cb = kc & 1, nb = cb ^ 1;
    float4 rn = make_float4(0.f, 0.f, 0.f, 0.f);
    if (kc < 31) {
      stageWs(kc + 1, nb);
      rn = loadFt(kc + 1);
    }
    compute(cb);
    if (kc < 31) writeFt(rn, nb);
    __syncthreads();
  }

  #pragma unroll
  for (int j = 0; j < 8; ++j) {
    int lt = tg * 8 + j;
    float w = wl[lt];
    if (w != 0.0f) {
      size_t orow = (size_t)tl[lt] * 512 + c0 + cg * 4;
      #pragma unroll
      for (int i = 0; i < 4; ++i) atomicAdd(&out[orow + i], w * acc[j][i]);
      #pragma unroll
      for (int i = 0; i < 4; ++i)
        atomicAdd(&out[orow + 128 + i], w * acc[j][i + 4]);
    }
  }
}

// ---------------- launch ----------------------------------------------------
extern "C" void kernel_launch(void* const* d_in, const int* in_sizes, int n_in,
                              void* d_out, int out_size, void* d_ws,
                              size_t ws_size, hipStream_t stream) {
  const float* features = (const float*)d_in[0];
  const float* proj_w = (const float*)d_in[1];
  const float* proj_b = (const float*)d_in[2];
  const float* expert_emb = (const float*)d_in[3];
  const float* expert_features = (const float*)d_in[4];
  const float* trust = (const float*)d_in[5];
  const float* dt = (const float*)d_in[6];
  const float* fst_w = (const float*)d_in[7];
  const float* fst_b = (const float*)d_in[8];
  float* out = (float*)d_out;
  float* ws = (float*)d_ws;

  // ---- main-path layout (unioned; 70,263,808 B total, same as r10) ----
  float* coef = ws;                          // 64
  int* cnt = (int*)(ws + 64);                // 64
  float* gbias = ws + 128;                   // 64
  int* njobs = (int*)(ws + 192);             // 64
  int* jobs = (int*)(ws + 256);              // 2048
  int* tlist = (int*)(ws + 2304);            // 64*2048
  float* wlist = ws + 133376;                // 64*2048
  _Float16* Fh = (_Float16*)(ws + 264448);   // 2048*512 halfs
  _Float16* WhT = (_Float16*)(ws + 788736);  // 64*512*512 halfs
  float* U = ws + 9177344;                   // union region
  float* pwT = U;                            // 512*256 (pre-k3 only)
  float* embT = U + 131072;                  // 256*64
  float* enT = U + 147456;                   // 512*64
  _Float16* Fl = (_Float16*)(U + 180224);    // 2048*512 halfs
  _Float16* GhT = (_Float16*)(U + 704512);   // 128*512 halfs
  _Float16* GlT = (_Float16*)(U + 737280);   // 128*512 halfs
  float* fnorm = U + 770048;                 // 2048
  float* scores4 = U + 772096;               // 4*2048*128 = 1M floats
  int* sel = (int*)(U + 1820672);            // 2048*8
  float* selw = U + 1837056;                 // 2048*8
  float* ypart = U;                          // 2048*8*512 (k3/k4, clobbers U)
  size_t need3 = (size_t)(9177344 + 8388608) * 4;

  if (ws_size >= need3) {
    hipLaunchKernelGGL(k_prep, dim3(2112), dim3(256), 0, stream, proj_w,
                       expert_emb, expert_features, trust, dt, features, fst_w,
                       pwT, embT, enT, coef, cnt, Fh, Fl, fnorm, WhT, njobs);
    hipLaunchKernelGGL(k0gs, dim3(513), dim3(64), 0, stream, pwT, proj_b,
                       embT, enT, GhT, GlT, gbias);
    hipLaunchKernelGGL(k1a_mfma, dim3(256), dim3(256), 0, stream, Fh, Fl, GhT,
                       GlT, scores4);
    hipLaunchKernelGGL(k1b_rank, dim3(512), dim3(256), 0, stream, scores4,
                       fnorm, coef, gbias, sel, selw);
    hipLaunchKernelGGL(k_gather, dim3(64), dim3(256), 0, stream, sel, selw,
                       cnt, tlist, wlist, jobs, njobs);
    hipLaunchKernelGGL(k3_mfma, dim3(2048), dim3(256), 0, stream, Fh, WhT,
                       fst_b, cnt, tlist, wlist, jobs, njobs, ypart);
    hipLaunchKernelGGL(k4_reduce, dim3(2048), dim3(256), 0, stream, ypart,
                       out);
  } else {
    // fp32 fallback (compact layout, ~2.2 MB)
    float* pwT2 = ws;                         // 512*256
    float* embT2 = pwT2 + 131072;             // 256*64
    float* enT2 = embT2 + 16384;              // 512*64
    float* coef2 = enT2 + 32768;              // 64
    int* cnt2 = (int*)(coef2 + 64);           // 64
    int* tk_idx = cnt2 + 64;                  // 2048*8
    float* tk_w = (float*)(tk_idx + 16384);   // 2048*8
    int* tlist2 = (int*)(tk_w + 16384);       // 64*2048
    float* wlist2 = (float*)(tlist2 + 131072);
    float* Gpack = wlist2 + 131072;           // 512*64*2
    float* gbias2 = Gpack + 65536;            // 64
    hipLaunchKernelGGL(k_prep, dim3(576), dim3(256), 0, stream, proj_w,
                       expert_emb, expert_features, trust, dt, features, fst_w,
                       pwT2, embT2, enT2, coef2, cnt2, (_Float16*)Gpack,
                       (_Float16*)Gpack, Gpack, (_Float16*)Gpack,
                       (int*)(gbias2 + 64));
    hipLaunchKernelGGL(k0g, dim3(513), dim3(64), 0, stream, pwT2, proj_b,
                       embT2, enT2, Gpack, gbias2);
    hipLaunchKernelGGL(k1_score, dim3(1024), dim3(256), 0, stream, features,
                       Gpack, gbias2, coef2, cnt2, tk_idx, tk_w, tlist2,
                       wlist2);
    hipLaunchKernelGGL(k2_bias, dim3(2048), dim3(256), 0, stream, tk_idx,
                       tk_w, fst_b, out);
    hipLaunchKernelGGL(k3_fst, dim3(4096), dim3(256), 0, stream, features,
                       fst_w, cnt2, tlist2, wlist2, out);
  }
}